// Round 2
// baseline (1256.005 us; speedup 1.0000x reference)
//
#include <hip/hip_runtime.h>
#include <math.h>

#define NNODES 40000
#define NEDGES 640000
#define NPB 8             // nodes per edge-block
#define LROW 257          // padded LDS accumulator row stride (floats)

typedef __attribute__((ext_vector_type(8))) short short8_t;
typedef __attribute__((ext_vector_type(4))) float float4_t;
typedef __attribute__((ext_vector_type(2))) float float2_t;
typedef __attribute__((ext_vector_type(2))) int   int2_t;

__device__ __forceinline__ float4 ld4(const float* p) { return *(const float4*)p; }

__device__ __forceinline__ unsigned short bf16r(float x) {
  union { float f; unsigned u; } v; v.f = x;
  unsigned u = v.u;
  u += 0x7FFFu + ((u >> 16) & 1u);   // RNE
  return (unsigned short)(u >> 16);
}

__device__ __forceinline__ void lds_fadd(float* p, float v) {
  __hip_atomic_fetch_add(p, v, __ATOMIC_RELAXED, __HIP_MEMORY_SCOPE_WORKGROUP);
}

#define INV_SQRT3_C 0.57735026918962576f

// 8 LDS atomics for one (edge-row, u) pair.
__device__ __forceinline__ void accum_half(float* lrow, int u,
    float w0, float w1, float w2, float w3,
    float se, float vx, float vy, float vz,
    float esc, float ev0, float ev1, float ev2) {
  lds_fadd(lrow + u, w0 * se * esc);
  float dv = vx * ev0 + vy * ev1 + vz * ev2;
  lds_fadd(lrow + 32 + u, w3 * dv * INV_SQRT3_C);
  float b1v = w1 * se;
  lds_fadd(lrow + 64 + u * 3 + 0, b1v * ev0);
  lds_fadd(lrow + 64 + u * 3 + 1, b1v * ev1);
  lds_fadd(lrow + 64 + u * 3 + 2, b1v * ev2);
  float b2v = w2 * esc;
  lds_fadd(lrow + 160 + u * 3 + 0, b2v * vx);
  lds_fadd(lrow + 160 + u * 3 + 1, b2v * vy);
  lds_fadd(lrow + 160 + u * 3 + 2, b2v * vz);
}

struct RowData { float se0, se1, vx0, vy0, vz0, vx1, vy1, vz1; };

__device__ __forceinline__ RowData load_row(const float* ab, int m) {
  RowData d;
  d.se0 = ab[m];            d.se1 = ab[m + 16];
  d.vx0 = ab[32 + 3 * m];   d.vy0 = ab[33 + 3 * m];   d.vz0 = ab[34 + 3 * m];
  d.vx1 = ab[80 + 3 * m];   d.vy1 = ab[81 + 3 * m];   d.vz1 = ab[82 + 3 * m];
  return d;
}

// ---------------- Stage 1 ----------------
__global__ void k1_stage1(const float* __restrict__ node_input,
                          const float* __restrict__ w1s,
                          const float* __restrict__ w1v,
                          float* __restrict__ A) {
  const float scale = 0.17677669529663687f; // 1/sqrt(32)
  int stride = gridDim.x * blockDim.x;
  for (int idx = blockIdx.x * blockDim.x + threadIdx.x; idx < NNODES * 128; idx += stride) {
    int n = idx >> 7;
    int c = idx & 127;
    const float* row = node_input + n * 128;
    float acc = 0.f;
    if (c < 32) {
      #pragma unroll
      for (int u = 0; u < 32; ++u)
        acc = fmaf(row[u], w1s[u * 32 + c], acc);
    } else {
      int cc = c - 32;
      int w = cc / 3;
      int i = cc - w * 3;
      #pragma unroll
      for (int u = 0; u < 32; ++u)
        acc = fmaf(row[32 + u * 3 + i], w1v[u * 32 + w], acc);
    }
    A[idx] = acc * scale;
  }
}

// ---------------- CSR build ----------------
__global__ void k_hist(const int* __restrict__ edge_dst, int* __restrict__ counts) {
  int e = blockIdx.x * blockDim.x + threadIdx.x;
  if (e < NEDGES) atomicAdd(&counts[edge_dst[e]], 1);
}

__global__ void k_scanA(const int* __restrict__ counts, int* __restrict__ bsum) {
  __shared__ int ws[4];
  int t = blockIdx.x * 256 + threadIdx.x;
  int v = (t < NNODES) ? counts[t] : 0;
  for (int d = 32; d; d >>= 1) v += __shfl_down(v, d, 64);
  if ((threadIdx.x & 63) == 0) ws[threadIdx.x >> 6] = v;
  __syncthreads();
  if (threadIdx.x == 0) bsum[blockIdx.x] = ws[0] + ws[1] + ws[2] + ws[3];
}

__global__ __launch_bounds__(256) void k_scanB(const int* __restrict__ bsum,
                                               int* __restrict__ boff,
                                               int* __restrict__ offsets) {
  __shared__ int s[256];
  int tid = threadIdx.x;
  int v = (tid < 157) ? bsum[tid] : 0;
  s[tid] = v;
  __syncthreads();
  for (int d = 1; d < 256; d <<= 1) {
    int x = (tid >= d) ? s[tid - d] : 0;
    __syncthreads();
    s[tid] += x;
    __syncthreads();
  }
  if (tid < 157) boff[tid] = s[tid] - v;
  if (tid == 0) offsets[NNODES] = NEDGES;
}

__global__ __launch_bounds__(256) void k_scanC(const int* __restrict__ counts,
                                               const int* __restrict__ boff,
                                               int* __restrict__ offsets,
                                               int* __restrict__ cursor) {
  __shared__ int s[256];
  int tid = threadIdx.x;
  int t = blockIdx.x * 256 + tid;
  int v = (t < NNODES) ? counts[t] : 0;
  s[tid] = v;
  __syncthreads();
  for (int d = 1; d < 256; d <<= 1) {
    int x = (tid >= d) ? s[tid - d] : 0;
    __syncthreads();
    s[tid] += x;
    __syncthreads();
  }
  int off = boff[blockIdx.x] + s[tid] - v;
  if (t < NNODES) { offsets[t] = off; cursor[t] = off; }
}

// fallback scatter (slots only)
__global__ void k_scatter(const int* __restrict__ edge_dst,
                          int* __restrict__ cursor, int* __restrict__ slots) {
  int e = blockIdx.x * blockDim.x + threadIdx.x;
  if (e < NEDGES) {
    int d = edge_dst[e];
    int p = atomicAdd(&cursor[d], 1);
    slots[p] = e;
  }
}

// R5 scatter: pack all per-edge payload in sorted order. Reads coalesced by e,
// writes scattered (fire-and-forget). Removes ALL random e-gathers from k_edge.
__global__ void k_scatter_pack(const int* __restrict__ edge_src,
                               const int* __restrict__ edge_dst,
                               const float* __restrict__ edge_attr,
                               const float* __restrict__ edge_scalars,
                               int* __restrict__ cursor,
                               int2_t* __restrict__ PSD,
                               float4_t* __restrict__ PEA,
                               float4_t* __restrict__ PES) {
  int e = blockIdx.x * blockDim.x + threadIdx.x;
  if (e < NEDGES) {
    int d = edge_dst[e];
    int p = atomicAdd(&cursor[d], 1);
    int2_t sd; sd.x = edge_src[e]; sd.y = d;
    PSD[p] = sd;
    PEA[p] = *(const float4_t*)(edge_attr + (long)e * 4);
    PES[2 * p]     = *(const float4_t*)(edge_scalars + (long)e * 8);
    PES[2 * p + 1] = *(const float4_t*)(edge_scalars + (long)e * 8 + 4);
  }
}

// ---------------- Fused edge kernel — R5: forced memory-level parallelism ----
// R4 post-mortem: removing barriers/batching in SOURCE changed nothing; VGPR=60
// shows the compiler sinks every gather to just-before-use -> ~30 SERIAL round
// trips per chunk per wave (~2.4k cy each). Fix:
// (1) packed sorted edge streams (PSD/PEA/PES) -> the 3-level random chain
//     slots->e->{src,attr,scalars} becomes 1 contiguous stream read.
// (2) ALL in-loop global loads via inline-asm global_load_* issued back-to-back
//     (24 A-row loads + 4 next-chunk stream loads in flight), ONE counted
//     s_waitcnt vmcnt(4) after MFMA (A done, next stream still flying), and
//     vmcnt(0) at loop end. sched_barrier(0) after each waitcnt (rule #18:
//     compiler may hoist consumers past asm waitcnt).
// (3) launch_bounds(256,3): asm outputs force ~120 VGPR live; avoid spills.
// Edge->lane map, h-compute, MFMA frags, atomics identical to R4 (proven).
__global__ __launch_bounds__(256, 3) void k_edge2(
    const float* __restrict__ A,
    const int2_t* __restrict__ PSD,
    const float4_t* __restrict__ PEA,
    const float4_t* __restrict__ PES,
    const float* __restrict__ fc_w1,
    const float* __restrict__ fc_w2,
    const int* __restrict__ offsets,
    float* __restrict__ ACC) {
  const float INV_SQRT8 = 0.35355339059327373f;
  const float H_SCALE   = 1.6791767923989418f / 8.0f;

  __shared__ float    lacc[NPB * LROW];
  __shared__ short8_t w2frag[16 * 64];
  __shared__ float4   w1f[144];

  int tid = threadIdx.x;
  int n0 = blockIdx.x * NPB;
  int ebase = offsets[n0];
  int eend  = offsets[n0 + NPB];

  for (int i = tid; i < NPB * LROW; i += 256) lacc[i] = 0.f;
  if (tid < 128) {
    int j = tid >> 1, hf = tid & 1;
    float4 wv4;
    wv4.x = fc_w1[(hf * 4 + 0) * 64 + j] * INV_SQRT8;
    wv4.y = fc_w1[(hf * 4 + 1) * 64 + j] * INV_SQRT8;
    wv4.z = fc_w1[(hf * 4 + 2) * 64 + j] * INV_SQRT8;
    wv4.w = fc_w1[(hf * 4 + 3) * 64 + j] * INV_SQRT8;
    w1f[(j >> 3) * 18 + (j & 7) * 2 + hf] = wv4;
  }
  for (int fi = tid; fi < 16 * 64; fi += 256) {
    int f = fi >> 6, ll = fi & 63;
    int ct = f >> 1, kh = f & 1, mm = ll & 15, qq = ll >> 4;
    short8_t v;
    #pragma unroll
    for (int j = 0; j < 8; ++j)
      v[j] = (short)bf16r(fc_w2[(kh * 32 + qq * 8 + j) * 128 + ct * 16 + mm]);
    w2frag[fi] = v;
  }
  __syncthreads();

  int wv = tid >> 6;
  int l  = tid & 63;
  int m  = l & 15;
  int q  = l >> 4;

  // ---- preload stream for chunk 0 (clamped; harmless if block empty)
  int2_t  csd;  float4_t cea, cesA, cesB;
  {
    int ce = ebase + 4 * m + wv;
    ce = (ce < eend) ? ce : (eend - 1);
    const int2_t*  p0 = PSD + ce;
    const float4_t* p1 = PEA + ce;
    const float4_t* p2 = PES + 2 * (long)ce;
    asm volatile("global_load_dwordx2 %0, %1, off" : "=v"(csd) : "v"(p0));
    asm volatile("global_load_dwordx4 %0, %1, off" : "=v"(cea) : "v"(p1));
    asm volatile("global_load_dwordx4 %0, %1, off" : "=v"(cesA) : "v"(p2));
    asm volatile("global_load_dwordx4 %0, %1, off offset:16" : "=v"(cesB) : "v"(p2));
  }
  asm volatile("s_waitcnt vmcnt(0)" ::: "memory");
  __builtin_amdgcn_sched_barrier(0);

  for (int k0 = ebase; k0 < eend; k0 += 64) {
    // ---- shfl metadata from cur regs (edge 4m+wv per lane)
    int lnm = csd.y - n0;
    int sl0 = q * 4, sl1 = sl0 + 1, sl2 = sl0 + 2, sl3 = sl0 + 3;
    int src0 = __shfl(csd.x, sl0, 64), src1 = __shfl(csd.x, sl1, 64);
    int src2 = __shfl(csd.x, sl2, 64), src3 = __shfl(csd.x, sl3, 64);
    int ln0 = __shfl(lnm, sl0, 64), ln1 = __shfl(lnm, sl1, 64);
    int ln2 = __shfl(lnm, sl2, 64), ln3 = __shfl(lnm, sl3, 64);
    float ea0x = __shfl(cea.x, sl0, 64), ea0y = __shfl(cea.y, sl0, 64),
          ea0z = __shfl(cea.z, sl0, 64), ea0w = __shfl(cea.w, sl0, 64);
    float ea1x = __shfl(cea.x, sl1, 64), ea1y = __shfl(cea.y, sl1, 64),
          ea1z = __shfl(cea.z, sl1, 64), ea1w = __shfl(cea.w, sl1, 64);
    float ea2x = __shfl(cea.x, sl2, 64), ea2y = __shfl(cea.y, sl2, 64),
          ea2z = __shfl(cea.z, sl2, 64), ea2w = __shfl(cea.w, sl2, 64);
    float ea3x = __shfl(cea.x, sl3, 64), ea3y = __shfl(cea.y, sl3, 64),
          ea3z = __shfl(cea.z, sl3, 64), ea3w = __shfl(cea.w, sl3, 64);

    // ---- issue ALL A-row gathers (24 loads, pinned issue order)
#define ALOAD(E, SRC)                                                              \
    float se0_##E, se1_##E, v0z_##E, v1z_##E; float2_t v0_##E, v1_##E;             \
    {                                                                              \
      const float* ps = A + (long)(SRC) * 128 + m;                                 \
      const float* pv = A + (long)(SRC) * 128 + 3 * m;                             \
      asm volatile("global_load_dword %0, %1, off"             : "=v"(se0_##E) : "v"(ps)); \
      asm volatile("global_load_dword %0, %1, off offset:64"   : "=v"(se1_##E) : "v"(ps)); \
      asm volatile("global_load_dwordx2 %0, %1, off offset:128": "=v"(v0_##E)  : "v"(pv)); \
      asm volatile("global_load_dword %0, %1, off offset:136"  : "=v"(v0z_##E) : "v"(pv)); \
      asm volatile("global_load_dwordx2 %0, %1, off offset:320": "=v"(v1_##E)  : "v"(pv)); \
      asm volatile("global_load_dword %0, %1, off offset:328"  : "=v"(v1z_##E) : "v"(pv)); \
    }
    ALOAD(0, src0)
    ALOAD(1, src1)
    ALOAD(2, src2)
    ALOAD(3, src3)
#undef ALOAD

    // ---- issue next-chunk stream loads (4 loads; consumed next iteration)
    int2_t  nsd;  float4_t nea, nesA, nesB;
    {
      int cen = k0 + 64 + 4 * m + wv;
      cen = (cen < eend) ? cen : (eend - 1);
      const int2_t*  p0 = PSD + cen;
      const float4_t* p1 = PEA + cen;
      const float4_t* p2 = PES + 2 * (long)cen;
      asm volatile("global_load_dwordx2 %0, %1, off" : "=v"(nsd) : "v"(p0));
      asm volatile("global_load_dwordx4 %0, %1, off" : "=v"(nea) : "v"(p1));
      asm volatile("global_load_dwordx4 %0, %1, off" : "=v"(nesA) : "v"(p2));
      asm volatile("global_load_dwordx4 %0, %1, off offset:16" : "=v"(nesB) : "v"(p2));
    }
    __builtin_amdgcn_sched_barrier(0);  // keep h-compute below the issue block

    // ---- h-compute (VALU, covers A-load latency)
    bool vld = (k0 + 4 * m + wv) < eend;
    float es0 = cesA.x, es1 = cesA.y, es2 = cesA.z, es3 = cesA.w;
    float es4 = cesB.x, es5 = cesB.y, es6 = cesB.z, es7 = cesB.w;
    short8_t a0, a1;
    #pragma unroll
    for (int jj = 0; jj < 8; ++jj) {
      float4 wA = w1f[q * 18 + jj * 2 + 0];
      float4 wB = w1f[q * 18 + jj * 2 + 1];
      float x = es0 * wA.x + es1 * wA.y + es2 * wA.z + es3 * wA.w
              + es4 * wB.x + es5 * wB.y + es6 * wB.z + es7 * wB.w;
      float hv = vld ? (x * H_SCALE) / (1.f + __expf(-x)) : 0.f;
      a0[jj] = (short)bf16r(hv);
      float4 wC = w1f[(4 + q) * 18 + jj * 2 + 0];
      float4 wD = w1f[(4 + q) * 18 + jj * 2 + 1];
      float x2 = es0 * wC.x + es1 * wC.y + es2 * wC.z + es3 * wC.w
               + es4 * wD.x + es5 * wD.y + es6 * wD.z + es7 * wD.w;
      float hv2 = vld ? (x2 * H_SCALE) / (1.f + __expf(-x2)) : 0.f;
      a1[jj] = (short)bf16r(hv2);
    }

    // ---- MFMA: w = h @ w2
    float4_t acc[8];
    #pragma unroll
    for (int t = 0; t < 8; ++t) {
      short8_t b0 = w2frag[(t * 2 + 0) * 64 + l];
      short8_t b1 = w2frag[(t * 2 + 1) * 64 + l];
      float4_t z = (float4_t){0.f, 0.f, 0.f, 0.f};
      z = __builtin_amdgcn_mfma_f32_16x16x32_bf16(a0, b0, z, 0, 0, 0);
      z = __builtin_amdgcn_mfma_f32_16x16x32_bf16(a1, b1, z, 0, 0, 0);
      acc[t] = z;
    }

    // ---- wait A-loads (the 4 newest = next-chunk stream keep flying)
    asm volatile("s_waitcnt vmcnt(4)" ::: "memory");
    __builtin_amdgcn_sched_barrier(0);

#define ACCUM_ROW2(RR, LN, EAX, EAY, EAZ, EAW, E) do {                           \
      float* lrow = lacc + (LN) * LROW;                                          \
      accum_half(lrow, m,      acc[0][RR], acc[2][RR], acc[4][RR], acc[6][RR],   \
                 se0_##E, v0_##E.x, v0_##E.y, v0z_##E, EAX, EAY, EAZ, EAW);      \
      accum_half(lrow, m + 16, acc[1][RR], acc[3][RR], acc[5][RR], acc[7][RR],   \
                 se1_##E, v1_##E.x, v1_##E.y, v1z_##E, EAX, EAY, EAZ, EAW);      \
    } while (0)

    if (k0 + 64 <= eend) {
      ACCUM_ROW2(0, ln0, ea0x, ea0y, ea0z, ea0w, 0);
      ACCUM_ROW2(1, ln1, ea1x, ea1y, ea1z, ea1w, 1);
      ACCUM_ROW2(2, ln2, ea2x, ea2y, ea2z, ea2w, 2);
      ACCUM_ROW2(3, ln3, ea3x, ea3y, ea3z, ea3w, 3);
    } else {
      int cb = k0 + 16 * q + wv;
      if (cb + 0  < eend) ACCUM_ROW2(0, ln0, ea0x, ea0y, ea0z, ea0w, 0);
      if (cb + 4  < eend) ACCUM_ROW2(1, ln1, ea1x, ea1y, ea1z, ea1w, 1);
      if (cb + 8  < eend) ACCUM_ROW2(2, ln2, ea2x, ea2y, ea2z, ea2w, 2);
      if (cb + 12 < eend) ACCUM_ROW2(3, ln3, ea3x, ea3y, ea3z, ea3w, 3);
    }
#undef ACCUM_ROW2

    // ---- next stream is (long since) arrived; swap
    asm volatile("s_waitcnt vmcnt(0)" ::: "memory");
    __builtin_amdgcn_sched_barrier(0);
    csd = nsd; cea = nea; cesA = nesA; cesB = nesB;
  }
  __syncthreads();

  for (int i = tid; i < NPB * 256; i += 256) {
    int node = i >> 8;
    int c = i & 255;
    ACC[(long)(n0 + node) * 256 + c] = lacc[node * LROW + c];
  }
}

// ---------------- R4 k_edge kept verbatim as ws-size fallback ----------------
__global__ __launch_bounds__(256, 4) void k_edge_fb(
    const float* __restrict__ A,
    const int* __restrict__ edge_src,
    const int* __restrict__ edge_dst,
    const float* __restrict__ edge_attr,
    const float* __restrict__ edge_scalars,
    const float* __restrict__ fc_w1,
    const float* __restrict__ fc_w2,
    const int* __restrict__ offsets,
    const int* __restrict__ slots,
    float* __restrict__ ACC) {
  const float INV_SQRT8 = 0.35355339059327373f;
  const float H_SCALE   = 1.6791767923989418f / 8.0f;

  __shared__ float    lacc[NPB * LROW];
  __shared__ short8_t w2frag[16 * 64];
  __shared__ float4   w1f[144];

  int tid = threadIdx.x;
  int n0 = blockIdx.x * NPB;
  int ebase = offsets[n0];
  int eend  = offsets[n0 + NPB];

  for (int i = tid; i < NPB * LROW; i += 256) lacc[i] = 0.f;
  if (tid < 128) {
    int j = tid >> 1, hf = tid & 1;
    float4 wv4;
    wv4.x = fc_w1[(hf * 4 + 0) * 64 + j] * INV_SQRT8;
    wv4.y = fc_w1[(hf * 4 + 1) * 64 + j] * INV_SQRT8;
    wv4.z = fc_w1[(hf * 4 + 2) * 64 + j] * INV_SQRT8;
    wv4.w = fc_w1[(hf * 4 + 3) * 64 + j] * INV_SQRT8;
    w1f[(j >> 3) * 18 + (j & 7) * 2 + hf] = wv4;
  }
  for (int fi = tid; fi < 16 * 64; fi += 256) {
    int f = fi >> 6, ll = fi & 63;
    int ct = f >> 1, kh = f & 1, mm = ll & 15, qq = ll >> 4;
    short8_t v;
    #pragma unroll
    for (int j = 0; j < 8; ++j)
      v[j] = (short)bf16r(fc_w2[(kh * 32 + qq * 8 + j) * 128 + ct * 16 + mm]);
    w2frag[fi] = v;
  }
  __syncthreads();

  int wv = tid >> 6;
  int l  = tid & 63;
  int m  = l & 15;
  int q  = l >> 4;

  for (int k0 = ebase; k0 < eend; k0 += 64) {
    int ce = k0 + 4 * m + wv;
    bool vld = ce < eend;
    int e = slots[vld ? ce : (eend - 1)];
    int srcm = edge_src[e];
    int lnm  = edge_dst[e] - n0;
    float4 eam = ld4(edge_attr + (long)e * 4);
    float4 sA = ld4(edge_scalars + (long)e * 8);
    float4 sB = ld4(edge_scalars + (long)e * 8 + 4);
    float es0 = sA.x, es1 = sA.y, es2 = sA.z, es3 = sA.w;
    float es4 = sB.x, es5 = sB.y, es6 = sB.z, es7 = sB.w;

    short8_t a0, a1;
    #pragma unroll
    for (int jj = 0; jj < 8; ++jj) {
      float4 wA = w1f[q * 18 + jj * 2 + 0];
      float4 wB = w1f[q * 18 + jj * 2 + 1];
      float x = es0 * wA.x + es1 * wA.y + es2 * wA.z + es3 * wA.w
              + es4 * wB.x + es5 * wB.y + es6 * wB.z + es7 * wB.w;
      float hv = vld ? (x * H_SCALE) / (1.f + __expf(-x)) : 0.f;
      a0[jj] = (short)bf16r(hv);
      float4 wC = w1f[(4 + q) * 18 + jj * 2 + 0];
      float4 wD = w1f[(4 + q) * 18 + jj * 2 + 1];
      float x2 = es0 * wC.x + es1 * wC.y + es2 * wC.z + es3 * wC.w
               + es4 * wD.x + es5 * wD.y + es6 * wD.z + es7 * wD.w;
      float hv2 = vld ? (x2 * H_SCALE) / (1.f + __expf(-x2)) : 0.f;
      a1[jj] = (short)bf16r(hv2);
    }

    int sl0 = q * 4, sl1 = sl0 + 1, sl2 = sl0 + 2, sl3 = sl0 + 3;
    int src0 = __shfl(srcm, sl0, 64), src1 = __shfl(srcm, sl1, 64);
    int src2 = __shfl(srcm, sl2, 64), src3 = __shfl(srcm, sl3, 64);
    int ln0 = __shfl(lnm, sl0, 64), ln1 = __shfl(lnm, sl1, 64);
    int ln2 = __shfl(lnm, sl2, 64), ln3 = __shfl(lnm, sl3, 64);
    float ea0x = __shfl(eam.x, sl0, 64), ea0y = __shfl(eam.y, sl0, 64),
          ea0z = __shfl(eam.z, sl0, 64), ea0w = __shfl(eam.w, sl0, 64);
    float ea1x = __shfl(eam.x, sl1, 64), ea1y = __shfl(eam.y, sl1, 64),
          ea1z = __shfl(eam.z, sl1, 64), ea1w = __shfl(eam.w, sl1, 64);
    float ea2x = __shfl(eam.x, sl2, 64), ea2y = __shfl(eam.y, sl2, 64),
          ea2z = __shfl(eam.z, sl2, 64), ea2w = __shfl(eam.w, sl2, 64);
    float ea3x = __shfl(eam.x, sl3, 64), ea3y = __shfl(eam.y, sl3, 64),
          ea3z = __shfl(eam.z, sl3, 64), ea3w = __shfl(eam.w, sl3, 64);

    const float* abA = A + (long)src0 * 128;
    const float* abB = A + (long)src1 * 128;
    RowData dA = load_row(abA, m);
    RowData dB = load_row(abB, m);

    float4_t acc[8];
    #pragma unroll
    for (int t = 0; t < 8; ++t) {
      short8_t b0 = w2frag[(t * 2 + 0) * 64 + l];
      short8_t b1 = w2frag[(t * 2 + 1) * 64 + l];
      float4_t z = (float4_t){0.f, 0.f, 0.f, 0.f};
      z = __builtin_amdgcn_mfma_f32_16x16x32_bf16(a0, b0, z, 0, 0, 0);
      z = __builtin_amdgcn_mfma_f32_16x16x32_bf16(a1, b1, z, 0, 0, 0);
      acc[t] = z;
    }

    const float* abC = A + (long)src2 * 128;
    const float* abD = A + (long)src3 * 128;
    RowData dC = load_row(abC, m);
    RowData dD = load_row(abD, m);

    #define ACCUM_ROW(RR, LN, EAX, EAY, EAZ, EAW, D) do {                        \
        float* lrow = lacc + (LN) * LROW;                                        \
        accum_half(lrow, m,      acc[0][RR], acc[2][RR], acc[4][RR], acc[6][RR], \
                   D.se0, D.vx0, D.vy0, D.vz0, EAX, EAY, EAZ, EAW);              \
        accum_half(lrow, m + 16, acc[1][RR], acc[3][RR], acc[5][RR], acc[7][RR], \
                   D.se1, D.vx1, D.vy1, D.vz1, EAX, EAY, EAZ, EAW);              \
      } while (0)

    if (k0 + 64 <= eend) {
      ACCUM_ROW(0, ln0, ea0x, ea0y, ea0z, ea0w, dA);
      ACCUM_ROW(1, ln1, ea1x, ea1y, ea1z, ea1w, dB);
      ACCUM_ROW(2, ln2, ea2x, ea2y, ea2z, ea2w, dC);
      ACCUM_ROW(3, ln3, ea3x, ea3y, ea3z, ea3w, dD);
    } else {
      int cb = k0 + 16 * q + wv;
      if (cb + 0  < eend) ACCUM_ROW(0, ln0, ea0x, ea0y, ea0z, ea0w, dA);
      if (cb + 4  < eend) ACCUM_ROW(1, ln1, ea1x, ea1y, ea1z, ea1w, dB);
      if (cb + 8  < eend) ACCUM_ROW(2, ln2, ea2x, ea2y, ea2z, ea2w, dC);
      if (cb + 12 < eend) ACCUM_ROW(3, ln3, ea3x, ea3y, ea3z, ea3w, dD);
    }
    #undef ACCUM_ROW
  }
  __syncthreads();

  for (int i = tid; i < NPB * 256; i += 256) {
    int node = i >> 8;
    int c = i & 255;
    ACC[(long)(n0 + node) * 256 + c] = lacc[node * LROW + c];
  }
}

// ---------------- Stage 2 ----------------
__global__ void k3_stage2(const float* __restrict__ ACC,
                          const float* __restrict__ w2s,
                          const float* __restrict__ w2v,
                          float* __restrict__ out) {
  const float scale = 0.03125f;
  int stride = gridDim.x * blockDim.x;
  for (int idx = blockIdx.x * blockDim.x + threadIdx.x; idx < NNODES * 128; idx += stride) {
    int n = idx >> 7;
    int c = idx & 127;
    const float* row = ACC + (long)n * 256;
    float acc = 0.f;
    if (c < 32) {
      #pragma unroll
      for (int qq = 0; qq < 64; ++qq)
        acc = fmaf(row[qq], w2s[qq * 32 + c], acc);
    } else {
      int cc = c - 32;
      int w = cc / 3;
      int i = cc - w * 3;
      #pragma unroll
      for (int qq = 0; qq < 64; ++qq)
        acc = fmaf(row[64 + qq * 3 + i], w2v[qq * 32 + w], acc);
    }
    out[idx] = acc * scale;
  }
}

extern "C" void kernel_launch(void* const* d_in, const int* in_sizes, int n_in,
                              void* d_out, int out_size, void* d_ws, size_t ws_size,
                              hipStream_t stream) {
  const float* node_input   = (const float*)d_in[0];
  const int*   edge_src     = (const int*)d_in[2];
  const int*   edge_dst     = (const int*)d_in[3];
  const float* edge_attr    = (const float*)d_in[4];
  const float* edge_scalars = (const float*)d_in[5];
  const float* w_lin1_s     = (const float*)d_in[6];
  const float* w_lin1_v     = (const float*)d_in[7];
  const float* fc_w1        = (const float*)d_in[8];
  const float* fc_w2        = (const float*)d_in[9];
  const float* w_lin2_s     = (const float*)d_in[10];
  const float* w_lin2_v     = (const float*)d_in[11];

  float* out = (float*)d_out;
  float* Abuf = out;  // stage-1 output lives in d_out; k3 overwrites it after edge kernel

  const size_t SZ_ACC = (size_t)NNODES * 256 * sizeof(float);   // 40.96 MB
  const size_t SZ_PES = (size_t)NEDGES * 32;                    // 20.48 MB
  const size_t SZ_PEA = (size_t)NEDGES * 16;                    // 10.24 MB
  const size_t SZ_PSD = (size_t)NEDGES * 8;                     //  5.12 MB
  const size_t SZ_CNT = (size_t)NNODES * sizeof(int);
  const size_t SZ_OFF = (size_t)(NNODES + 4) * sizeof(int);
  const size_t SZ_SLT = (size_t)NEDGES * sizeof(int);
  const size_t need_packed = SZ_ACC + SZ_PES + SZ_PEA + SZ_PSD + 3 * SZ_CNT + SZ_OFF + 2048;

  if (ws_size >= need_packed) {
    // ---- R5 packed-stream path
    char* p = (char*)d_ws;
    float*    ACC = (float*)p;    p += SZ_ACC;
    float4_t* PES = (float4_t*)p; p += SZ_PES;
    float4_t* PEA = (float4_t*)p; p += SZ_PEA;
    int2_t*   PSD = (int2_t*)p;   p += SZ_PSD;
    int* counts   = (int*)p;      p += SZ_CNT;
    int* offsets  = (int*)p;      p += SZ_OFF;
    int* cursor   = (int*)p;      p += SZ_CNT;
    int* bsum     = (int*)p;      p += 160 * sizeof(int);
    int* boff     = (int*)p;      p += 160 * sizeof(int);

    hipMemsetAsync(counts, 0, SZ_CNT, stream);
    k1_stage1<<<2048, 256, 0, stream>>>(node_input, w_lin1_s, w_lin1_v, Abuf);
    k_hist<<<NEDGES / 256, 256, 0, stream>>>(edge_dst, counts);
    k_scanA<<<157, 256, 0, stream>>>(counts, bsum);
    k_scanB<<<1, 256, 0, stream>>>(bsum, boff, offsets);
    k_scanC<<<157, 256, 0, stream>>>(counts, boff, offsets, cursor);
    k_scatter_pack<<<NEDGES / 256, 256, 0, stream>>>(edge_src, edge_dst, edge_attr,
                                                     edge_scalars, cursor, PSD, PEA, PES);
    k_edge2<<<NNODES / NPB, 256, 0, stream>>>(Abuf, PSD, PEA, PES, fc_w1, fc_w2,
                                              offsets, ACC);
    k3_stage2<<<2048, 256, 0, stream>>>(ACC, w_lin2_s, w_lin2_v, out);
  } else {
    // ---- proven R4 fallback
    char* p = (char*)d_ws;
    float* ACC    = (float*)p;  p += SZ_ACC;
    int* counts   = (int*)p;    p += SZ_CNT;
    int* offsets  = (int*)p;    p += SZ_OFF;
    int* cursor   = (int*)p;    p += SZ_CNT;
    int* slots    = (int*)p;    p += SZ_SLT;
    int* bsum     = (int*)p;    p += 160 * sizeof(int);
    int* boff     = (int*)p;    p += 160 * sizeof(int);

    hipMemsetAsync(counts, 0, SZ_CNT, stream);
    k1_stage1<<<2048, 256, 0, stream>>>(node_input, w_lin1_s, w_lin1_v, Abuf);
    k_hist<<<NEDGES / 256, 256, 0, stream>>>(edge_dst, counts);
    k_scanA<<<157, 256, 0, stream>>>(counts, bsum);
    k_scanB<<<1, 256, 0, stream>>>(bsum, boff, offsets);
    k_scanC<<<157, 256, 0, stream>>>(counts, boff, offsets, cursor);
    k_scatter<<<NEDGES / 256, 256, 0, stream>>>(edge_dst, cursor, slots);
    k_edge_fb<<<NNODES / NPB, 256, 0, stream>>>(Abuf, edge_src, edge_dst, edge_attr,
                                                edge_scalars, fc_w1, fc_w2,
                                                offsets, slots, ACC);
    k3_stage2<<<2048, 256, 0, stream>>>(ACC, w_lin2_s, w_lin2_v, out);
  }
}

// Round 3
// 527.429 us; speedup vs baseline: 2.3814x; 2.3814x over previous
//
#include <hip/hip_runtime.h>
#include <math.h>

#define NNODES 40000
#define NEDGES 640000
#define NPB 8             // nodes per edge-block
#define LROW 257          // fallback kernel: padded LDS accumulator row stride
#define CHUNK 32          // edges per chunk in k_edge3
#define MROW 260          // mid row stride (floats): 1040B = 16B-aligned, 4-bank row shift

typedef __attribute__((ext_vector_type(8))) short short8_t;
typedef __attribute__((ext_vector_type(4))) float float4_t;

__device__ __forceinline__ float4 ld4(const float* p) { return *(const float4*)p; }

__device__ __forceinline__ unsigned short bf16r(float x) {
  union { float f; unsigned u; } v; v.f = x;
  unsigned u = v.u;
  u += 0x7FFFu + ((u >> 16) & 1u);   // RNE
  return (unsigned short)(u >> 16);
}

__device__ __forceinline__ void lds_fadd(float* p, float v) {
  __hip_atomic_fetch_add(p, v, __ATOMIC_RELAXED, __HIP_MEMORY_SCOPE_WORKGROUP);
}

#define INV_SQRT3_C 0.57735026918962576f

// fallback-kernel helper (R4, proven)
__device__ __forceinline__ void accum_half(float* lrow, int u,
    float w0, float w1, float w2, float w3,
    float se, float vx, float vy, float vz,
    float esc, float ev0, float ev1, float ev2) {
  lds_fadd(lrow + u, w0 * se * esc);
  float dv = vx * ev0 + vy * ev1 + vz * ev2;
  lds_fadd(lrow + 32 + u, w3 * dv * INV_SQRT3_C);
  float b1v = w1 * se;
  lds_fadd(lrow + 64 + u * 3 + 0, b1v * ev0);
  lds_fadd(lrow + 64 + u * 3 + 1, b1v * ev1);
  lds_fadd(lrow + 64 + u * 3 + 2, b1v * ev2);
  float b2v = w2 * esc;
  lds_fadd(lrow + 160 + u * 3 + 0, b2v * vx);
  lds_fadd(lrow + 160 + u * 3 + 1, b2v * vy);
  lds_fadd(lrow + 160 + u * 3 + 2, b2v * vz);
}

struct RowData { float se0, se1, vx0, vy0, vz0, vx1, vy1, vz1; };

__device__ __forceinline__ RowData load_row(const float* ab, int m) {
  RowData d;
  d.se0 = ab[m];            d.se1 = ab[m + 16];
  d.vx0 = ab[32 + 3 * m];   d.vy0 = ab[33 + 3 * m];   d.vz0 = ab[34 + 3 * m];
  d.vx1 = ab[80 + 3 * m];   d.vy1 = ab[81 + 3 * m];   d.vz1 = ab[82 + 3 * m];
  return d;
}

// ---------------- Stage 1 ----------------
__global__ void k1_stage1(const float* __restrict__ node_input,
                          const float* __restrict__ w1s,
                          const float* __restrict__ w1v,
                          float* __restrict__ A) {
  const float scale = 0.17677669529663687f; // 1/sqrt(32)
  int stride = gridDim.x * blockDim.x;
  for (int idx = blockIdx.x * blockDim.x + threadIdx.x; idx < NNODES * 128; idx += stride) {
    int n = idx >> 7;
    int c = idx & 127;
    const float* row = node_input + n * 128;
    float acc = 0.f;
    if (c < 32) {
      #pragma unroll
      for (int u = 0; u < 32; ++u)
        acc = fmaf(row[u], w1s[u * 32 + c], acc);
    } else {
      int cc = c - 32;
      int w = cc / 3;
      int i = cc - w * 3;
      #pragma unroll
      for (int u = 0; u < 32; ++u)
        acc = fmaf(row[32 + u * 3 + i], w1v[u * 32 + w], acc);
    }
    A[idx] = acc * scale;
  }
}

// ---------------- CSR build ----------------
__global__ void k_hist(const int* __restrict__ edge_dst, int* __restrict__ counts) {
  int e = blockIdx.x * blockDim.x + threadIdx.x;
  if (e < NEDGES) atomicAdd(&counts[edge_dst[e]], 1);
}

__global__ void k_scanA(const int* __restrict__ counts, int* __restrict__ bsum) {
  __shared__ int ws[4];
  int t = blockIdx.x * 256 + threadIdx.x;
  int v = (t < NNODES) ? counts[t] : 0;
  for (int d = 32; d; d >>= 1) v += __shfl_down(v, d, 64);
  if ((threadIdx.x & 63) == 0) ws[threadIdx.x >> 6] = v;
  __syncthreads();
  if (threadIdx.x == 0) bsum[blockIdx.x] = ws[0] + ws[1] + ws[2] + ws[3];
}

__global__ __launch_bounds__(256) void k_scanB(const int* __restrict__ bsum,
                                               int* __restrict__ boff,
                                               int* __restrict__ offsets) {
  __shared__ int s[256];
  int tid = threadIdx.x;
  int v = (tid < 157) ? bsum[tid] : 0;
  s[tid] = v;
  __syncthreads();
  for (int d = 1; d < 256; d <<= 1) {
    int x = (tid >= d) ? s[tid - d] : 0;
    __syncthreads();
    s[tid] += x;
    __syncthreads();
  }
  if (tid < 157) boff[tid] = s[tid] - v;
  if (tid == 0) offsets[NNODES] = NEDGES;
}

__global__ __launch_bounds__(256) void k_scanC(const int* __restrict__ counts,
                                               const int* __restrict__ boff,
                                               int* __restrict__ offsets,
                                               int* __restrict__ cursor) {
  __shared__ int s[256];
  int tid = threadIdx.x;
  int t = blockIdx.x * 256 + tid;
  int v = (t < NNODES) ? counts[t] : 0;
  s[tid] = v;
  __syncthreads();
  for (int d = 1; d < 256; d <<= 1) {
    int x = (tid >= d) ? s[tid - d] : 0;
    __syncthreads();
    s[tid] += x;
    __syncthreads();
  }
  int off = boff[blockIdx.x] + s[tid] - v;
  if (t < NNODES) { offsets[t] = off; cursor[t] = off; }
}

// fallback scatter (slots only)
__global__ void k_scatter(const int* __restrict__ edge_dst,
                          int* __restrict__ cursor, int* __restrict__ slots) {
  int e = blockIdx.x * blockDim.x + threadIdx.x;
  if (e < NEDGES) {
    int d = edge_dst[e];
    int p = atomicAdd(&cursor[d], 1);
    slots[p] = e;
  }
}

// R6 scatter: pack per-edge payload in sorted order (dst no longer needed
// downstream — per-edge mid rows make the writer dst-free).
__global__ void k_scatter_pack2(const int* __restrict__ edge_src,
                                const int* __restrict__ edge_dst,
                                const float* __restrict__ edge_attr,
                                const float* __restrict__ edge_scalars,
                                int* __restrict__ cursor,
                                int* __restrict__ PSRC,
                                float4_t* __restrict__ PEA,
                                float4_t* __restrict__ PES) {
  int e = blockIdx.x * blockDim.x + threadIdx.x;
  if (e < NEDGES) {
    int d = edge_dst[e];
    int p = atomicAdd(&cursor[d], 1);
    PSRC[p] = edge_src[e];
    PEA[p] = *(const float4_t*)(edge_attr + (long)e * 4);
    PES[2 * p]     = *(const float4_t*)(edge_scalars + (long)e * 8);
    PES[2 * p + 1] = *(const float4_t*)(edge_scalars + (long)e * 8 + 4);
  }
}

// ---------------- Fused edge kernel — R6: ZERO LDS atomics -------------------
// R3/R4/R5 all pinned at ~930us with every pipe idle; the invariant was the 64
// ds_add_f32 per wave-chunk. Arithmetic: 2.56M ds_adds / 256 CUs * ~190cy RMW
// occupancy = 1.9M cycles = the observed 2.23M-cycle wall. Theory: k_edge is
// bound by LDS-atomic pipe throughput (~3cy/lane RMW).
// Fix: per-edge private mid rows written with PLAIN ds_write_b32 (race-free by
// construction: distinct row per edge, distinct col per lane), then the
// segment-sum runs as a register accumulation over each node's contiguous
// sorted edge range via conflict-free ds_read_b128. No atomics anywhere.
// Structure: CHUNK=32 edges; waves split as (et=edge-tile, ch=col-half):
//   ch=0: MFMA tiles {0,1,4,5} (w0,w2) -> writes cols u (s0) and 160+3u (v1)
//   ch=1: MFMA tiles {2,3,6,7} (w1,w3) -> writes cols 32+u (s1) and 64+3u (v0)
// mid row stride 260 floats: 16B-aligned rows (b128 reader), 4-bank row shift
// (writer q-groups 16 banks apart -> worst 2-way = free).
// LDS: 33.3K mid + 16.4K w2frag + 2.3K w1f = 52KB -> 3 blocks/CU.
__global__ __launch_bounds__(256, 3) void k_edge3(
    const float* __restrict__ A,
    const int* __restrict__ PSRC,
    const float4_t* __restrict__ PEA,
    const float4_t* __restrict__ PES,
    const float* __restrict__ fc_w1,
    const float* __restrict__ fc_w2,
    const int* __restrict__ offsets,
    float* __restrict__ ACC) {
  const float INV_SQRT8 = 0.35355339059327373f;
  const float H_SCALE   = 1.6791767923989418f / 8.0f; // SILU_NORM / sqrt(64)

  __shared__ float    mid[CHUNK * MROW];   // 33,280 B
  __shared__ short8_t w2frag[16 * 64];     // 16,384 B
  __shared__ float4   w1f[144];            //  2,304 B

  int tid = threadIdx.x;
  int n0 = blockIdx.x * NPB;
  int ebase = offsets[n0];
  int eend  = offsets[n0 + NPB];

  if (tid < 128) {
    int j = tid >> 1, hf = tid & 1;
    float4 wv4;
    wv4.x = fc_w1[(hf * 4 + 0) * 64 + j] * INV_SQRT8;
    wv4.y = fc_w1[(hf * 4 + 1) * 64 + j] * INV_SQRT8;
    wv4.z = fc_w1[(hf * 4 + 2) * 64 + j] * INV_SQRT8;
    wv4.w = fc_w1[(hf * 4 + 3) * 64 + j] * INV_SQRT8;
    w1f[(j >> 3) * 18 + (j & 7) * 2 + hf] = wv4;
  }
  // B-frag layout (proven): frag f=(ct*2+kh), lane l holds
  // elem j = w2[k = kh*32 + (l>>4)*8 + j][c = ct*16 + (l&15)]
  for (int fi = tid; fi < 16 * 64; fi += 256) {
    int f = fi >> 6, ll = fi & 63;
    int ct = f >> 1, kh = f & 1, mm = ll & 15, qq = ll >> 4;
    short8_t v;
    #pragma unroll
    for (int j = 0; j < 8; ++j)
      v[j] = (short)bf16r(fc_w2[(kh * 32 + qq * 8 + j) * 128 + ct * 16 + mm]);
    w2frag[fi] = v;
  }
  __syncthreads();

  int wv = tid >> 6;       // wave id 0..3
  int l  = tid & 63;
  int m  = l & 15;
  int q  = l >> 4;
  int et = wv & 1;         // edge-tile of this wave (chunk edges et*16..et*16+15)
  int ch = wv >> 1;        // col-half class

  // reduction ownership: wave wv owns nodes {2wv, 2wv+1}; lane l owns cols 4l..4l+3
  int nA = 2 * wv;
  int offA0 = offsets[n0 + nA];
  int offA1 = offsets[n0 + nA + 1];
  int offB1 = offsets[n0 + nA + 2];
  float4_t racA = {0.f, 0.f, 0.f, 0.f};
  float4_t racB = {0.f, 0.f, 0.f, 0.f};

  for (int k0 = ebase; k0 < eend; k0 += CHUNK) {
    // ================= writer phase (no atomics, no tail branches) ==========
    {
      // this lane's edge (duplicated across q; clamped tail rows are never read)
      int ecs = k0 + et * 16 + m;
      int ecc = (ecs < eend) ? ecs : (eend - 1);
      int srcm = PSRC[ecc];
      float4 eam = *(const float4*)(PEA + ecc);
      float4 sA  = *(const float4*)(PES + 2 * (long)ecc);
      float4 sB  = *(const float4*)(PES + 2 * (long)ecc + 1);
      float es0 = sA.x, es1 = sA.y, es2 = sA.z, es3 = sA.w;
      float es4 = sB.x, es5 = sB.y, es6 = sB.z, es7 = sB.w;

      // h-compute: lane (m,q) supplies A-frag row m, k = q*8+j (a0) / 32+q*8+j (a1)
      short8_t a0, a1;
      #pragma unroll
      for (int jj = 0; jj < 8; ++jj) {
        float4 wA = w1f[q * 18 + jj * 2 + 0];
        float4 wB = w1f[q * 18 + jj * 2 + 1];
        float x = es0 * wA.x + es1 * wA.y + es2 * wA.z + es3 * wA.w
                + es4 * wB.x + es5 * wB.y + es6 * wB.z + es7 * wB.w;
        float hv = (x * H_SCALE) / (1.f + __expf(-x));
        a0[jj] = (short)bf16r(hv);
        float4 wC = w1f[(4 + q) * 18 + jj * 2 + 0];
        float4 wD = w1f[(4 + q) * 18 + jj * 2 + 1];
        float x2 = es0 * wC.x + es1 * wC.y + es2 * wC.z + es3 * wC.w
                 + es4 * wD.x + es5 * wD.y + es6 * wD.z + es7 * wD.w;
        float hv2 = (x2 * H_SCALE) / (1.f + __expf(-x2));
        a1[jj] = (short)bf16r(hv2);
      }

      // epilogue metadata: row r held by lane (m = q*4+r, q'' = 0)
      int sl0 = q * 4, sl1 = sl0 + 1, sl2 = sl0 + 2, sl3 = sl0 + 3;
      int src0 = __shfl(srcm, sl0, 64), src1 = __shfl(srcm, sl1, 64);
      int src2 = __shfl(srcm, sl2, 64), src3 = __shfl(srcm, sl3, 64);
      float ea0x = __shfl(eam.x, sl0, 64), ea0y = __shfl(eam.y, sl0, 64),
            ea0z = __shfl(eam.z, sl0, 64), ea0w = __shfl(eam.w, sl0, 64);
      float ea1x = __shfl(eam.x, sl1, 64), ea1y = __shfl(eam.y, sl1, 64),
            ea1z = __shfl(eam.z, sl1, 64), ea1w = __shfl(eam.w, sl1, 64);
      float ea2x = __shfl(eam.x, sl2, 64), ea2y = __shfl(eam.y, sl2, 64),
            ea2z = __shfl(eam.z, sl2, 64), ea2w = __shfl(eam.w, sl2, 64);
      float ea3x = __shfl(eam.x, sl3, 64), ea3y = __shfl(eam.y, sl3, 64),
            ea3z = __shfl(eam.z, sl3, 64), ea3w = __shfl(eam.w, sl3, 64);

      // A-row gathers (issue before MFMA; latency hidden under it)
      RowData d0 = load_row(A + (long)src0 * 128, m);
      RowData d1 = load_row(A + (long)src1 * 128, m);
      RowData d2 = load_row(A + (long)src2 * 128, m);
      RowData d3 = load_row(A + (long)src3 * 128, m);

      // MFMA: 4 col-tiles for this wave's class
      // acL[uo] = tile (ch*2+uo):   ch0 -> w0[u],  ch1 -> w1[u]   (u = uo*16+m)
      // acH[uo] = tile (4+ch*2+uo): ch0 -> w2[u],  ch1 -> w3[u]
      float4_t acL[2], acH[2];
      #pragma unroll
      for (int uo = 0; uo < 2; ++uo) {
        int tl = ch * 2 + uo;
        short8_t bl0 = w2frag[(tl * 2 + 0) * 64 + l];
        short8_t bl1 = w2frag[(tl * 2 + 1) * 64 + l];
        float4_t zl = (float4_t){0.f, 0.f, 0.f, 0.f};
        zl = __builtin_amdgcn_mfma_f32_16x16x32_bf16(a0, bl0, zl, 0, 0, 0);
        zl = __builtin_amdgcn_mfma_f32_16x16x32_bf16(a1, bl1, zl, 0, 0, 0);
        acL[uo] = zl;
        int th = 4 + ch * 2 + uo;
        short8_t bh0 = w2frag[(th * 2 + 0) * 64 + l];
        short8_t bh1 = w2frag[(th * 2 + 1) * 64 + l];
        float4_t zh = (float4_t){0.f, 0.f, 0.f, 0.f};
        zh = __builtin_amdgcn_mfma_f32_16x16x32_bf16(a0, bh0, zh, 0, 0, 0);
        zh = __builtin_amdgcn_mfma_f32_16x16x32_bf16(a1, bh1, zh, 0, 0, 0);
        acH[uo] = zh;
      }

      // plain-store epilogue: C reg (q,r) -> chunk-edge et*16 + q*4 + r
#define EPI(R, D, EAX, EAY, EAZ, EAW) do {                                       \
        float* mrow = mid + (et * 16 + q * 4 + (R)) * MROW;                      \
        { float wAa = acL[0][R], wBb = acH[0][R];                                \
          if (ch == 0) {                                                         \
            mrow[m] = wAa * D.se0 * EAX;                                         \
            float b = wBb * EAX;                                                 \
            mrow[160 + 3 * m + 0] = b * D.vx0;                                   \
            mrow[160 + 3 * m + 1] = b * D.vy0;                                   \
            mrow[160 + 3 * m + 2] = b * D.vz0;                                   \
          } else {                                                               \
            float dv = D.vx0 * EAY + D.vy0 * EAZ + D.vz0 * EAW;                  \
            mrow[32 + m] = wBb * dv * INV_SQRT3_C;                               \
            float b = wAa * D.se0;                                               \
            mrow[64 + 3 * m + 0] = b * EAY;                                      \
            mrow[64 + 3 * m + 1] = b * EAZ;                                      \
            mrow[64 + 3 * m + 2] = b * EAW;                                      \
          } }                                                                    \
        { float wAa = acL[1][R], wBb = acH[1][R];                                \
          int u = 16 + m;                                                        \
          if (ch == 0) {                                                         \
            mrow[u] = wAa * D.se1 * EAX;                                         \
            float b = wBb * EAX;                                                 \
            mrow[160 + 3 * u + 0] = b * D.vx1;                                   \
            mrow[160 + 3 * u + 1] = b * D.vy1;                                   \
            mrow[160 + 3 * u + 2] = b * D.vz1;                                   \
          } else {                                                               \
            float dv = D.vx1 * EAY + D.vy1 * EAZ + D.vz1 * EAW;                  \
            mrow[32 + u] = wBb * dv * INV_SQRT3_C;                               \
            float b = wAa * D.se1;                                               \
            mrow[64 + 3 * u + 0] = b * EAY;                                      \
            mrow[64 + 3 * u + 1] = b * EAZ;                                      \
            mrow[64 + 3 * u + 2] = b * EAW;                                      \
          } }                                                                    \
      } while (0)

      EPI(0, d0, ea0x, ea0y, ea0z, ea0w);
      EPI(1, d1, ea1x, ea1y, ea1z, ea1w);
      EPI(2, d2, ea2x, ea2y, ea2z, ea2w);
      EPI(3, d3, ea3x, ea3y, ea3z, ea3w);
#undef EPI
    }
    __syncthreads();

    // ================= reader phase: register segment-sum ===================
    {
      int lo = (offA0 > k0) ? offA0 : k0;
      int hiA = offA1 < (k0 + CHUNK) ? offA1 : (k0 + CHUNK);
      for (int e = lo; e < hiA; ++e) {
        float4_t v = *(const float4_t*)(mid + (e - k0) * MROW + 4 * l);
        racA.x += v.x; racA.y += v.y; racA.z += v.z; racA.w += v.w;
      }
      int lo2 = (offA1 > k0) ? offA1 : k0;
      int hiB = offB1 < (k0 + CHUNK) ? offB1 : (k0 + CHUNK);
      for (int e = lo2; e < hiB; ++e) {
        float4_t v = *(const float4_t*)(mid + (e - k0) * MROW + 4 * l);
        racB.x += v.x; racB.y += v.y; racB.z += v.z; racB.w += v.w;
      }
    }
    __syncthreads();
  }

  // final coalesced output: wave wv writes node rows 2wv, 2wv+1
  *(float4_t*)(ACC + (long)(n0 + nA) * 256 + 4 * l)     = racA;
  *(float4_t*)(ACC + (long)(n0 + nA + 1) * 256 + 4 * l) = racB;
}

// ---------------- R4 k_edge kept verbatim as ws-size fallback ----------------
__global__ __launch_bounds__(256, 4) void k_edge_fb(
    const float* __restrict__ A,
    const int* __restrict__ edge_src,
    const int* __restrict__ edge_dst,
    const float* __restrict__ edge_attr,
    const float* __restrict__ edge_scalars,
    const float* __restrict__ fc_w1,
    const float* __restrict__ fc_w2,
    const int* __restrict__ offsets,
    const int* __restrict__ slots,
    float* __restrict__ ACC) {
  const float INV_SQRT8 = 0.35355339059327373f;
  const float H_SCALE   = 1.6791767923989418f / 8.0f;

  __shared__ float    lacc[NPB * LROW];
  __shared__ short8_t w2frag[16 * 64];
  __shared__ float4   w1f[144];

  int tid = threadIdx.x;
  int n0 = blockIdx.x * NPB;
  int ebase = offsets[n0];
  int eend  = offsets[n0 + NPB];

  for (int i = tid; i < NPB * LROW; i += 256) lacc[i] = 0.f;
  if (tid < 128) {
    int j = tid >> 1, hf = tid & 1;
    float4 wv4;
    wv4.x = fc_w1[(hf * 4 + 0) * 64 + j] * INV_SQRT8;
    wv4.y = fc_w1[(hf * 4 + 1) * 64 + j] * INV_SQRT8;
    wv4.z = fc_w1[(hf * 4 + 2) * 64 + j] * INV_SQRT8;
    wv4.w = fc_w1[(hf * 4 + 3) * 64 + j] * INV_SQRT8;
    w1f[(j >> 3) * 18 + (j & 7) * 2 + hf] = wv4;
  }
  for (int fi = tid; fi < 16 * 64; fi += 256) {
    int f = fi >> 6, ll = fi & 63;
    int ct = f >> 1, kh = f & 1, mm = ll & 15, qq = ll >> 4;
    short8_t v;
    #pragma unroll
    for (int j = 0; j < 8; ++j)
      v[j] = (short)bf16r(fc_w2[(kh * 32 + qq * 8 + j) * 128 + ct * 16 + mm]);
    w2frag[fi] = v;
  }
  __syncthreads();

  int wv = tid >> 6;
  int l  = tid & 63;
  int m  = l & 15;
  int q  = l >> 4;

  for (int k0 = ebase; k0 < eend; k0 += 64) {
    int ce = k0 + 4 * m + wv;
    bool vld = ce < eend;
    int e = slots[vld ? ce : (eend - 1)];
    int srcm = edge_src[e];
    int lnm  = edge_dst[e] - n0;
    float4 eam = ld4(edge_attr + (long)e * 4);
    float4 sA = ld4(edge_scalars + (long)e * 8);
    float4 sB = ld4(edge_scalars + (long)e * 8 + 4);
    float es0 = sA.x, es1 = sA.y, es2 = sA.z, es3 = sA.w;
    float es4 = sB.x, es5 = sB.y, es6 = sB.z, es7 = sB.w;

    short8_t a0, a1;
    #pragma unroll
    for (int jj = 0; jj < 8; ++jj) {
      float4 wA = w1f[q * 18 + jj * 2 + 0];
      float4 wB = w1f[q * 18 + jj * 2 + 1];
      float x = es0 * wA.x + es1 * wA.y + es2 * wA.z + es3 * wA.w
              + es4 * wB.x + es5 * wB.y + es6 * wB.z + es7 * wB.w;
      float hv = vld ? (x * H_SCALE) / (1.f + __expf(-x)) : 0.f;
      a0[jj] = (short)bf16r(hv);
      float4 wC = w1f[(4 + q) * 18 + jj * 2 + 0];
      float4 wD = w1f[(4 + q) * 18 + jj * 2 + 1];
      float x2 = es0 * wC.x + es1 * wC.y + es2 * wC.z + es3 * wC.w
               + es4 * wD.x + es5 * wD.y + es6 * wD.z + es7 * wD.w;
      float hv2 = vld ? (x2 * H_SCALE) / (1.f + __expf(-x2)) : 0.f;
      a1[jj] = (short)bf16r(hv2);
    }

    int sl0 = q * 4, sl1 = sl0 + 1, sl2 = sl0 + 2, sl3 = sl0 + 3;
    int src0 = __shfl(srcm, sl0, 64), src1 = __shfl(srcm, sl1, 64);
    int src2 = __shfl(srcm, sl2, 64), src3 = __shfl(srcm, sl3, 64);
    int ln0 = __shfl(lnm, sl0, 64), ln1 = __shfl(lnm, sl1, 64);
    int ln2 = __shfl(lnm, sl2, 64), ln3 = __shfl(lnm, sl3, 64);
    float ea0x = __shfl(eam.x, sl0, 64), ea0y = __shfl(eam.y, sl0, 64),
          ea0z = __shfl(eam.z, sl0, 64), ea0w = __shfl(eam.w, sl0, 64);
    float ea1x = __shfl(eam.x, sl1, 64), ea1y = __shfl(eam.y, sl1, 64),
          ea1z = __shfl(eam.z, sl1, 64), ea1w = __shfl(eam.w, sl1, 64);
    float ea2x = __shfl(eam.x, sl2, 64), ea2y = __shfl(eam.y, sl2, 64),
          ea2z = __shfl(eam.z, sl2, 64), ea2w = __shfl(eam.w, sl2, 64);
    float ea3x = __shfl(eam.x, sl3, 64), ea3y = __shfl(eam.y, sl3, 64),
          ea3z = __shfl(eam.z, sl3, 64), ea3w = __shfl(eam.w, sl3, 64);

    const float* abA = A + (long)src0 * 128;
    const float* abB = A + (long)src1 * 128;
    RowData dA = load_row(abA, m);
    RowData dB = load_row(abB, m);

    float4_t acc[8];
    #pragma unroll
    for (int t = 0; t < 8; ++t) {
      short8_t b0 = w2frag[(t * 2 + 0) * 64 + l];
      short8_t b1 = w2frag[(t * 2 + 1) * 64 + l];
      float4_t z = (float4_t){0.f, 0.f, 0.f, 0.f};
      z = __builtin_amdgcn_mfma_f32_16x16x32_bf16(a0, b0, z, 0, 0, 0);
      z = __builtin_amdgcn_mfma_f32_16x16x32_bf16(a1, b1, z, 0, 0, 0);
      acc[t] = z;
    }

    const float* abC = A + (long)src2 * 128;
    const float* abD = A + (long)src3 * 128;
    RowData dC = load_row(abC, m);
    RowData dD = load_row(abD, m);

    #define ACCUM_ROW(RR, LN, EAX, EAY, EAZ, EAW, D) do {                        \
        float* lrow = lacc + (LN) * LROW;                                        \
        accum_half(lrow, m,      acc[0][RR], acc[2][RR], acc[4][RR], acc[6][RR], \
                   D.se0, D.vx0, D.vy0, D.vz0, EAX, EAY, EAZ, EAW);              \
        accum_half(lrow, m + 16, acc[1][RR], acc[3][RR], acc[5][RR], acc[7][RR], \
                   D.se1, D.vx1, D.vy1, D.vz1, EAX, EAY, EAZ, EAW);              \
      } while (0)

    if (k0 + 64 <= eend) {
      ACCUM_ROW(0, ln0, ea0x, ea0y, ea0z, ea0w, dA);
      ACCUM_ROW(1, ln1, ea1x, ea1y, ea1z, ea1w, dB);
      ACCUM_ROW(2, ln2, ea2x, ea2y, ea2z, ea2w, dC);
      ACCUM_ROW(3, ln3, ea3x, ea3y, ea3z, ea3w, dD);
    } else {
      int cb = k0 + 16 * q + wv;
      if (cb + 0  < eend) ACCUM_ROW(0, ln0, ea0x, ea0y, ea0z, ea0w, dA);
      if (cb + 4  < eend) ACCUM_ROW(1, ln1, ea1x, ea1y, ea1z, ea1w, dB);
      if (cb + 8  < eend) ACCUM_ROW(2, ln2, ea2x, ea2y, ea2z, ea2w, dC);
      if (cb + 12 < eend) ACCUM_ROW(3, ln3, ea3x, ea3y, ea3z, ea3w, dD);
    }
    #undef ACCUM_ROW
  }
  __syncthreads();

  for (int i = tid; i < NPB * 256; i += 256) {
    int node = i >> 8;
    int c = i & 255;
    ACC[(long)(n0 + node) * 256 + c] = lacc[node * LROW + c];
  }
}

// ---------------- Stage 2 ----------------
__global__ void k3_stage2(const float* __restrict__ ACC,
                          const float* __restrict__ w2s,
                          const float* __restrict__ w2v,
                          float* __restrict__ out) {
  const float scale = 0.03125f; // (1/sqrt(16)) / sqrt(64)
  int stride = gridDim.x * blockDim.x;
  for (int idx = blockIdx.x * blockDim.x + threadIdx.x; idx < NNODES * 128; idx += stride) {
    int n = idx >> 7;
    int c = idx & 127;
    const float* row = ACC + (long)n * 256;
    float acc = 0.f;
    if (c < 32) {
      #pragma unroll
      for (int qq = 0; qq < 64; ++qq)
        acc = fmaf(row[qq], w2s[qq * 32 + c], acc);
    } else {
      int cc = c - 32;
      int w = cc / 3;
      int i = cc - w * 3;
      #pragma unroll
      for (int qq = 0; qq < 64; ++qq)
        acc = fmaf(row[64 + qq * 3 + i], w2v[qq * 32 + w], acc);
    }
    out[idx] = acc * scale;
  }
}

extern "C" void kernel_launch(void* const* d_in, const int* in_sizes, int n_in,
                              void* d_out, int out_size, void* d_ws, size_t ws_size,
                              hipStream_t stream) {
  const float* node_input   = (const float*)d_in[0];
  const int*   edge_src     = (const int*)d_in[2];
  const int*   edge_dst     = (const int*)d_in[3];
  const float* edge_attr    = (const float*)d_in[4];
  const float* edge_scalars = (const float*)d_in[5];
  const float* w_lin1_s     = (const float*)d_in[6];
  const float* w_lin1_v     = (const float*)d_in[7];
  const float* fc_w1        = (const float*)d_in[8];
  const float* fc_w2        = (const float*)d_in[9];
  const float* w_lin2_s     = (const float*)d_in[10];
  const float* w_lin2_v     = (const float*)d_in[11];

  float* out = (float*)d_out;
  float* Abuf = out;  // stage-1 output lives in d_out; k3 overwrites it after edge kernel

  const size_t SZ_ACC = (size_t)NNODES * 256 * sizeof(float);   // 40.96 MB
  const size_t SZ_PES = (size_t)NEDGES * 32;                    // 20.48 MB
  const size_t SZ_PEA = (size_t)NEDGES * 16;                    // 10.24 MB
  const size_t SZ_PSR = (size_t)NEDGES * 4;                     //  2.56 MB
  const size_t SZ_CNT = (size_t)NNODES * sizeof(int);
  const size_t SZ_OFF = (size_t)(NNODES + 4) * sizeof(int);
  const size_t SZ_SLT = (size_t)NEDGES * sizeof(int);
  const size_t need_packed = SZ_ACC + SZ_PES + SZ_PEA + SZ_PSR + 3 * SZ_CNT + SZ_OFF + 2048;

  if (ws_size >= need_packed) {
    // ---- R6 packed-stream + atomic-free path
    char* p = (char*)d_ws;
    float*    ACC = (float*)p;    p += SZ_ACC;
    float4_t* PES = (float4_t*)p; p += SZ_PES;
    float4_t* PEA = (float4_t*)p; p += SZ_PEA;
    int*      PSRC = (int*)p;     p += SZ_PSR;
    int* counts   = (int*)p;      p += SZ_CNT;
    int* offsets  = (int*)p;      p += SZ_OFF;
    int* cursor   = (int*)p;      p += SZ_CNT;
    int* bsum     = (int*)p;      p += 160 * sizeof(int);
    int* boff     = (int*)p;      p += 160 * sizeof(int);

    hipMemsetAsync(counts, 0, SZ_CNT, stream);
    k1_stage1<<<2048, 256, 0, stream>>>(node_input, w_lin1_s, w_lin1_v, Abuf);
    k_hist<<<NEDGES / 256, 256, 0, stream>>>(edge_dst, counts);
    k_scanA<<<157, 256, 0, stream>>>(counts, bsum);
    k_scanB<<<1, 256, 0, stream>>>(bsum, boff, offsets);
    k_scanC<<<157, 256, 0, stream>>>(counts, boff, offsets, cursor);
    k_scatter_pack2<<<NEDGES / 256, 256, 0, stream>>>(edge_src, edge_dst, edge_attr,
                                                      edge_scalars, cursor, PSRC, PEA, PES);
    k_edge3<<<NNODES / NPB, 256, 0, stream>>>(Abuf, PSRC, PEA, PES, fc_w1, fc_w2,
                                              offsets, ACC);
    k3_stage2<<<2048, 256, 0, stream>>>(ACC, w_lin2_s, w_lin2_v, out);
  } else {
    // ---- proven R4 fallback
    char* p = (char*)d_ws;
    float* ACC    = (float*)p;  p += SZ_ACC;
    int* counts   = (int*)p;    p += SZ_CNT;
    int* offsets  = (int*)p;    p += SZ_OFF;
    int* cursor   = (int*)p;    p += SZ_CNT;
    int* slots    = (int*)p;    p += SZ_SLT;
    int* bsum     = (int*)p;    p += 160 * sizeof(int);
    int* boff     = (int*)p;    p += 160 * sizeof(int);

    hipMemsetAsync(counts, 0, SZ_CNT, stream);
    k1_stage1<<<2048, 256, 0, stream>>>(node_input, w_lin1_s, w_lin1_v, Abuf);
    k_hist<<<NEDGES / 256, 256, 0, stream>>>(edge_dst, counts);
    k_scanA<<<157, 256, 0, stream>>>(counts, bsum);
    k_scanB<<<1, 256, 0, stream>>>(bsum, boff, offsets);
    k_scanC<<<157, 256, 0, stream>>>(counts, boff, offsets, cursor);
    k_scatter<<<NEDGES / 256, 256, 0, stream>>>(edge_dst, cursor, slots);
    k_edge_fb<<<NNODES / NPB, 256, 0, stream>>>(Abuf, edge_src, edge_dst, edge_attr,
                                                edge_scalars, fc_w1, fc_w2,
                                                offsets, slots, ACC);
    k3_stage2<<<2048, 256, 0, stream>>>(ACC, w_lin2_s, w_lin2_v, out);
  }
}

// Round 4
// 466.870 us; speedup vs baseline: 2.6903x; 1.1297x over previous
//
#include <hip/hip_runtime.h>
#include <math.h>

#define NNODES 40000
#define NEDGES 640000
#define NPB 8             // nodes per edge-block
#define LROW 257          // fallback kernels: padded LDS accumulator row stride
#define CHUNK 32          // edges per chunk in k_edge3 (tier2)
#define CHUNK4 16         // edges per chunk in k_edge4 (tier1)
#define MROW 260          // mid row stride (floats): 16B-aligned, 4-bank row shift

typedef __attribute__((ext_vector_type(8))) short short8_t;
typedef __attribute__((ext_vector_type(4))) short short4_t;
typedef __attribute__((ext_vector_type(4))) float float4_t;

__device__ __forceinline__ float4 ld4(const float* p) { return *(const float4*)p; }

__device__ __forceinline__ unsigned short bf16r(float x) {
  union { float f; unsigned u; } v; v.f = x;
  unsigned u = v.u;
  u += 0x7FFFu + ((u >> 16) & 1u);   // RNE
  return (unsigned short)(u >> 16);
}

__device__ __forceinline__ void lds_fadd(float* p, float v) {
  __hip_atomic_fetch_add(p, v, __ATOMIC_RELAXED, __HIP_MEMORY_SCOPE_WORKGROUP);
}

#define INV_SQRT3_C 0.57735026918962576f

// tier3-kernel helper (R4, proven)
__device__ __forceinline__ void accum_half(float* lrow, int u,
    float w0, float w1, float w2, float w3,
    float se, float vx, float vy, float vz,
    float esc, float ev0, float ev1, float ev2) {
  lds_fadd(lrow + u, w0 * se * esc);
  float dv = vx * ev0 + vy * ev1 + vz * ev2;
  lds_fadd(lrow + 32 + u, w3 * dv * INV_SQRT3_C);
  float b1v = w1 * se;
  lds_fadd(lrow + 64 + u * 3 + 0, b1v * ev0);
  lds_fadd(lrow + 64 + u * 3 + 1, b1v * ev1);
  lds_fadd(lrow + 64 + u * 3 + 2, b1v * ev2);
  float b2v = w2 * esc;
  lds_fadd(lrow + 160 + u * 3 + 0, b2v * vx);
  lds_fadd(lrow + 160 + u * 3 + 1, b2v * vy);
  lds_fadd(lrow + 160 + u * 3 + 2, b2v * vz);
}

struct RowData { float se0, se1, vx0, vy0, vz0, vx1, vy1, vz1; };

__device__ __forceinline__ RowData load_row(const float* ab, int m) {
  RowData d;
  d.se0 = ab[m];            d.se1 = ab[m + 16];
  d.vx0 = ab[32 + 3 * m];   d.vy0 = ab[33 + 3 * m];   d.vz0 = ab[34 + 3 * m];
  d.vx1 = ab[80 + 3 * m];   d.vy1 = ab[81 + 3 * m];   d.vz1 = ab[82 + 3 * m];
  return d;
}

// ---------------- Stage 1 ----------------
__global__ void k1_stage1(const float* __restrict__ node_input,
                          const float* __restrict__ w1s,
                          const float* __restrict__ w1v,
                          float* __restrict__ A) {
  const float scale = 0.17677669529663687f; // 1/sqrt(32)
  int stride = gridDim.x * blockDim.x;
  for (int idx = blockIdx.x * blockDim.x + threadIdx.x; idx < NNODES * 128; idx += stride) {
    int n = idx >> 7;
    int c = idx & 127;
    const float* row = node_input + n * 128;
    float acc = 0.f;
    if (c < 32) {
      #pragma unroll
      for (int u = 0; u < 32; ++u)
        acc = fmaf(row[u], w1s[u * 32 + c], acc);
    } else {
      int cc = c - 32;
      int w = cc / 3;
      int i = cc - w * 3;
      #pragma unroll
      for (int u = 0; u < 32; ++u)
        acc = fmaf(row[32 + u * 3 + i], w1v[u * 32 + w], acc);
    }
    A[idx] = acc * scale;
  }
}

// ---------------- CSR build ----------------
__global__ void k_hist(const int* __restrict__ edge_dst, int* __restrict__ counts) {
  int e = blockIdx.x * blockDim.x + threadIdx.x;
  if (e < NEDGES) atomicAdd(&counts[edge_dst[e]], 1);
}

__global__ void k_scanA(const int* __restrict__ counts, int* __restrict__ bsum) {
  __shared__ int ws[4];
  int t = blockIdx.x * 256 + threadIdx.x;
  int v = (t < NNODES) ? counts[t] : 0;
  for (int d = 32; d; d >>= 1) v += __shfl_down(v, d, 64);
  if ((threadIdx.x & 63) == 0) ws[threadIdx.x >> 6] = v;
  __syncthreads();
  if (threadIdx.x == 0) bsum[blockIdx.x] = ws[0] + ws[1] + ws[2] + ws[3];
}

__global__ __launch_bounds__(256) void k_scanB(const int* __restrict__ bsum,
                                               int* __restrict__ boff,
                                               int* __restrict__ offsets) {
  __shared__ int s[256];
  int tid = threadIdx.x;
  int v = (tid < 157) ? bsum[tid] : 0;
  s[tid] = v;
  __syncthreads();
  for (int d = 1; d < 256; d <<= 1) {
    int x = (tid >= d) ? s[tid - d] : 0;
    __syncthreads();
    s[tid] += x;
    __syncthreads();
  }
  if (tid < 157) boff[tid] = s[tid] - v;
  if (tid == 0) offsets[NNODES] = NEDGES;
}

__global__ __launch_bounds__(256) void k_scanC(const int* __restrict__ counts,
                                               const int* __restrict__ boff,
                                               int* __restrict__ offsets,
                                               int* __restrict__ cursor) {
  __shared__ int s[256];
  int tid = threadIdx.x;
  int t = blockIdx.x * 256 + tid;
  int v = (t < NNODES) ? counts[t] : 0;
  s[tid] = v;
  __syncthreads();
  for (int d = 1; d < 256; d <<= 1) {
    int x = (tid >= d) ? s[tid - d] : 0;
    __syncthreads();
    s[tid] += x;
    __syncthreads();
  }
  int off = boff[blockIdx.x] + s[tid] - v;
  if (t < NNODES) { offsets[t] = off; cursor[t] = off; }
}

// tier3 scatter (slots only)
__global__ void k_scatter(const int* __restrict__ edge_dst,
                          int* __restrict__ cursor, int* __restrict__ slots) {
  int e = blockIdx.x * blockDim.x + threadIdx.x;
  if (e < NEDGES) {
    int d = edge_dst[e];
    int p = atomicAdd(&cursor[d], 1);
    slots[p] = e;
  }
}

// tier2 scatter (R6, proven): 3 separate packed arrays
__global__ void k_scatter_pack2(const int* __restrict__ edge_src,
                                const int* __restrict__ edge_dst,
                                const float* __restrict__ edge_attr,
                                const float* __restrict__ edge_scalars,
                                int* __restrict__ cursor,
                                int* __restrict__ PSRC,
                                float4_t* __restrict__ PEA,
                                float4_t* __restrict__ PES) {
  int e = blockIdx.x * blockDim.x + threadIdx.x;
  if (e < NEDGES) {
    int d = edge_dst[e];
    int p = atomicAdd(&cursor[d], 1);
    PSRC[p] = edge_src[e];
    PEA[p] = *(const float4_t*)(edge_attr + (long)e * 4);
    PES[2 * p]     = *(const float4_t*)(edge_scalars + (long)e * 8);
    PES[2 * p + 1] = *(const float4_t*)(edge_scalars + (long)e * 8 + 4);
  }
}

// R7 scatter: ONE aligned 64B record per edge -> single cache line per edge
// (R6 wrote 3 random lines/edge: 4B+16B+32B write-allocate). Layout:
//   [0..16)  ea (float4)
//   [16..32) es[0..4)
//   [32..48) es[4..8)
//   [48..64) {src-as-float-bits, pad, pad, pad}
__global__ void k_scatter_pack3(const int* __restrict__ edge_src,
                                const int* __restrict__ edge_dst,
                                const float* __restrict__ edge_attr,
                                const float* __restrict__ edge_scalars,
                                int* __restrict__ cursor,
                                float4_t* __restrict__ PE) {
  int e = blockIdx.x * blockDim.x + threadIdx.x;
  if (e < NEDGES) {
    int d = edge_dst[e];
    int p = atomicAdd(&cursor[d], 1);
    float4_t* b = PE + (long)p * 4;
    b[0] = *(const float4_t*)(edge_attr + (long)e * 4);
    b[1] = *(const float4_t*)(edge_scalars + (long)e * 8);
    b[2] = *(const float4_t*)(edge_scalars + (long)e * 8 + 4);
    float4_t s;
    s.x = __int_as_float(edge_src[e]); s.y = 0.f; s.z = 0.f; s.w = 0.f;
    b[3] = s;
  }
}

// ---------------- Fused edge kernel — R7: dedup + occupancy ------------------
// R6 post-mortem: atomic-free writer confirmed (933->175us). Remaining waste:
// (a) h-compute + A-gathers duplicated 2x across ch-wave classes (VALU 55%);
// (b) LDS 52.2KB -> only 3 blocks/CU (occupancy 30%).
// k_edge4 changes:
// (1) CHUNK 16: each wave computes a k-QUARTER of h for all 16 edges
//     (k = wv*16 + q*4 + j; zero duplication) and publishes 8B to a padded
//     h_lds (16 rows x 72 shorts; stride 144B -> even bank spread). All waves
//     read their MFMA A-frags from it: a0/a1 = 16B-aligned b128 reads.
// (2) B-frags built ONCE from global into 4 short8 registers (tiles are fixed
//     per wave: tL = cl*2+uh, tH = 4+cl*2+uh) -> w2frag LDS (16.4KB) gone.
//     LDS total 21.2KB -> 4-5 blocks/CU.
// (3) 2 barriers/chunk: [publish h_i]->bar->[frags+MFMA+epilogue->mid]->bar->
//     [reader(mid_i) || publish h_{i+1} + prefetch A-rows for i+1] -- the
//     A-gather latency spans a barrier + full MFMA phase.
// Epilogue/reader formulas identical to proven R6 (uo -> fixed uh per wave).
// Wave roles: uh = wv&1 (u-half), cl = wv>>1 (class: 0 -> w0/w2 -> s0/v1 cols,
// 1 -> w1/w3 -> s1/v0 cols). Reduction: wave wv owns nodes {2wv,2wv+1}.
__global__ __launch_bounds__(256, 4) void k_edge4(
    const float* __restrict__ A,
    const float4_t* __restrict__ PE,
    const float* __restrict__ fc_w1,
    const float* __restrict__ fc_w2,
    const int* __restrict__ offsets,
    float* __restrict__ ACC) {
  const float INV_SQRT8 = 0.35355339059327373f;
  const float H_SCALE   = 1.6791767923989418f / 8.0f; // SILU_NORM / sqrt(64)

  __shared__ float  mid[CHUNK4 * MROW];   // 16,640 B
  __shared__ short  h_lds[CHUNK4 * 72];   //  2,304 B (144B row stride)
  __shared__ float4 w1f[144];             //  2,304 B

  int tid = threadIdx.x;
  int n0 = blockIdx.x * NPB;
  int ebase = offsets[n0];
  int eend  = offsets[n0 + NPB];

  if (tid < 128) {
    int j = tid >> 1, hf = tid & 1;
    float4 wv4;
    wv4.x = fc_w1[(hf * 4 + 0) * 64 + j] * INV_SQRT8;
    wv4.y = fc_w1[(hf * 4 + 1) * 64 + j] * INV_SQRT8;
    wv4.z = fc_w1[(hf * 4 + 2) * 64 + j] * INV_SQRT8;
    wv4.w = fc_w1[(hf * 4 + 3) * 64 + j] * INV_SQRT8;
    w1f[(j >> 3) * 18 + (j & 7) * 2 + hf] = wv4;
  }

  int wv = tid >> 6;       // wave id 0..3
  int l  = tid & 63;
  int m  = l & 15;
  int q  = l >> 4;
  int uh = wv & 1;         // u-half: u in [uh*16, uh*16+16)
  int cl = wv >> 1;        // column class
  int tL = cl * 2 + uh;    // w-tile for {w0|w1}
  int tH = 4 + cl * 2 + uh;// w-tile for {w2|w3}
  int u  = uh * 16 + m;

  // B-frags direct from global (fc_w2 is 32KB, L2-resident). Same element map
  // as the proven w2frag: frag (t,kh), lane l -> fc_w2[(kh*32+q*8+j)*128 + t*16+m]
  short8_t bL0, bL1, bH0, bH1;
  #pragma unroll
  for (int j = 0; j < 8; ++j) {
    bL0[j] = (short)bf16r(fc_w2[(q * 8 + j) * 128      + tL * 16 + m]);
    bL1[j] = (short)bf16r(fc_w2[(32 + q * 8 + j) * 128 + tL * 16 + m]);
    bH0[j] = (short)bf16r(fc_w2[(q * 8 + j) * 128      + tH * 16 + m]);
    bH1[j] = (short)bf16r(fc_w2[(32 + q * 8 + j) * 128 + tH * 16 + m]);
  }

  int nA = 2 * wv;
  int offA0 = offsets[n0 + nA];
  int offA1 = offsets[n0 + nA + 1];
  int offB1 = offsets[n0 + nA + 2];
  float4_t racA = {0.f, 0.f, 0.f, 0.f};
  float4_t racB = {0.f, 0.f, 0.f, 0.f};

  // per-chunk metadata registers (assigned by loadmeta, consumed after barrier)
  float ea0x, ea0y, ea0z, ea0w, ea1x, ea1y, ea1z, ea1w,
        ea2x, ea2y, ea2z, ea2w, ea3x, ea3y, ea3z, ea3w;
  float se0, se1, se2, se3, vx0, vx1, vx2, vx3,
        vy0, vy1, vy2, vy3, vz0, vz1, vz2, vz3;

  auto loadmeta = [&](int kb) {
    int ecs = kb + m;                      // lane's edge = chunk row m
    int ecc = (ecs < eend) ? ecs : (eend - 1);
    const float4_t* pb = PE + (long)ecc * 4;
    float4_t eam = pb[0];
    float4_t sA  = pb[1];
    float4_t sB  = pb[2];
    int srcm = __float_as_int(pb[3].x);
    // h quarter: k = wv*16 + q*4 + j  (all (wv,q,j) cover k 0..63 exactly once)
    int g  = wv * 2 + (q >> 1);
    int ob = (q & 1) * 4;
    short4_t hq;
    #pragma unroll
    for (int j = 0; j < 4; ++j) {
      float4 wA = w1f[g * 18 + (ob + j) * 2 + 0];
      float4 wB = w1f[g * 18 + (ob + j) * 2 + 1];
      float x = sA.x * wA.x + sA.y * wA.y + sA.z * wA.z + sA.w * wA.w
              + sB.x * wB.x + sB.y * wB.y + sB.z * wB.z + sB.w * wB.w;
      float hv = (x * H_SCALE) / (1.f + __expf(-x));
      hq[j] = (short)bf16r(hv);
    }
    *(short4_t*)((char*)h_lds + m * 144 + wv * 32 + q * 8) = hq;
    // metadata for this wave's 4 epilogue rows R = q*4+r (lane R holds edge R)
    int sl0 = q * 4, sl1 = sl0 + 1, sl2 = sl0 + 2, sl3 = sl0 + 3;
    int src0 = __shfl(srcm, sl0, 64), src1 = __shfl(srcm, sl1, 64);
    int src2 = __shfl(srcm, sl2, 64), src3 = __shfl(srcm, sl3, 64);
    ea0x = __shfl(eam.x, sl0, 64); ea0y = __shfl(eam.y, sl0, 64);
    ea0z = __shfl(eam.z, sl0, 64); ea0w = __shfl(eam.w, sl0, 64);
    ea1x = __shfl(eam.x, sl1, 64); ea1y = __shfl(eam.y, sl1, 64);
    ea1z = __shfl(eam.z, sl1, 64); ea1w = __shfl(eam.w, sl1, 64);
    ea2x = __shfl(eam.x, sl2, 64); ea2y = __shfl(eam.y, sl2, 64);
    ea2z = __shfl(eam.z, sl2, 64); ea2w = __shfl(eam.w, sl2, 64);
    ea3x = __shfl(eam.x, sl3, 64); ea3y = __shfl(eam.y, sl3, 64);
    ea3z = __shfl(eam.z, sl3, 64); ea3w = __shfl(eam.w, sl3, 64);
    // A-row gathers for col u only (this wave's half) — latency spans a
    // barrier + MFMA phase before first use.
    const float* r0 = A + (long)src0 * 128;
    const float* r1 = A + (long)src1 * 128;
    const float* r2 = A + (long)src2 * 128;
    const float* r3 = A + (long)src3 * 128;
    se0 = r0[u]; vx0 = r0[32 + 3 * u]; vy0 = r0[33 + 3 * u]; vz0 = r0[34 + 3 * u];
    se1 = r1[u]; vx1 = r1[32 + 3 * u]; vy1 = r1[33 + 3 * u]; vz1 = r1[34 + 3 * u];
    se2 = r2[u]; vx2 = r2[32 + 3 * u]; vy2 = r2[33 + 3 * u]; vz2 = r2[34 + 3 * u];
    se3 = r3[u]; vx3 = r3[32 + 3 * u]; vy3 = r3[33 + 3 * u]; vz3 = r3[34 + 3 * u];
  };

  __syncthreads();    // w1f ready

  if (ebase < eend) {
    loadmeta(ebase);
    for (int k0 = ebase; k0 < eend; k0 += CHUNK4) {
      __syncthreads();  // h_lds published by all waves; prev-chunk mid reads done
      // ---- frags + MFMA + plain-store epilogue
      short8_t a0 = *(const short8_t*)((const char*)h_lds + m * 144 + q * 16);
      short8_t a1 = *(const short8_t*)((const char*)h_lds + m * 144 + 64 + q * 16);
      float4_t acL = {0.f, 0.f, 0.f, 0.f};
      float4_t acH = {0.f, 0.f, 0.f, 0.f};
      acL = __builtin_amdgcn_mfma_f32_16x16x32_bf16(a0, bL0, acL, 0, 0, 0);
      acL = __builtin_amdgcn_mfma_f32_16x16x32_bf16(a1, bL1, acL, 0, 0, 0);
      acH = __builtin_amdgcn_mfma_f32_16x16x32_bf16(a0, bH0, acH, 0, 0, 0);
      acH = __builtin_amdgcn_mfma_f32_16x16x32_bf16(a1, bH1, acH, 0, 0, 0);
      // C reg (q,r) -> chunk-edge q*4+r. cl decides column set (R6 formulas).
#define EPI4(R, SE, VX, VY, VZ, EAX, EAY, EAZ, EAW) do {            \
        float* mrow = mid + (q * 4 + (R)) * MROW;                   \
        if (cl == 0) {                                              \
          mrow[u] = acL[R] * (SE) * (EAX);                          \
          float b = acH[R] * (EAX);                                 \
          mrow[160 + 3 * u + 0] = b * (VX);                         \
          mrow[160 + 3 * u + 1] = b * (VY);                         \
          mrow[160 + 3 * u + 2] = b * (VZ);                         \
        } else {                                                    \
          float dv = (VX) * (EAY) + (VY) * (EAZ) + (VZ) * (EAW);    \
          mrow[32 + u] = acH[R] * dv * INV_SQRT3_C;                 \
          float b = acL[R] * (SE);                                  \
          mrow[64 + 3 * u + 0] = b * (EAY);                         \
          mrow[64 + 3 * u + 1] = b * (EAZ);                         \
          mrow[64 + 3 * u + 2] = b * (EAW);                         \
        }                                                           \
      } while (0)
      EPI4(0, se0, vx0, vy0, vz0, ea0x, ea0y, ea0z, ea0w);
      EPI4(1, se1, vx1, vy1, vz1, ea1x, ea1y, ea1z, ea1w);
      EPI4(2, se2, vx2, vy2, vz2, ea2x, ea2y, ea2z, ea2w);
      EPI4(3, se3, vx3, vy3, vz3, ea3x, ea3y, ea3z, ea3w);
#undef EPI4
      __syncthreads();  // mid ready
      // ---- reader (register segment-sum) || next-chunk h publish + A prefetch
      {
        int lo = (offA0 > k0) ? offA0 : k0;
        int hi = offA1 < (k0 + CHUNK4) ? offA1 : (k0 + CHUNK4);
        for (int e = lo; e < hi; ++e) {
          float4_t v = *(const float4_t*)(mid + (e - k0) * MROW + 4 * l);
          racA.x += v.x; racA.y += v.y; racA.z += v.z; racA.w += v.w;
        }
        int lo2 = (offA1 > k0) ? offA1 : k0;
        int hi2 = offB1 < (k0 + CHUNK4) ? offB1 : (k0 + CHUNK4);
        for (int e = lo2; e < hi2; ++e) {
          float4_t v = *(const float4_t*)(mid + (e - k0) * MROW + 4 * l);
          racB.x += v.x; racB.y += v.y; racB.z += v.z; racB.w += v.w;
        }
      }
      if (k0 + CHUNK4 < eend) loadmeta(k0 + CHUNK4);
    }
  }

  // final coalesced output: wave wv writes node rows 2wv, 2wv+1
  *(float4_t*)(ACC + (long)(n0 + nA) * 256 + 4 * l)     = racA;
  *(float4_t*)(ACC + (long)(n0 + nA + 1) * 256 + 4 * l) = racB;
}

// ---------------- tier2: R6 k_edge3 kept verbatim ----------------------------
__global__ __launch_bounds__(256, 3) void k_edge3(
    const float* __restrict__ A,
    const int* __restrict__ PSRC,
    const float4_t* __restrict__ PEA,
    const float4_t* __restrict__ PES,
    const float* __restrict__ fc_w1,
    const float* __restrict__ fc_w2,
    const int* __restrict__ offsets,
    float* __restrict__ ACC) {
  const float INV_SQRT8 = 0.35355339059327373f;
  const float H_SCALE   = 1.6791767923989418f / 8.0f;

  __shared__ float    mid[CHUNK * MROW];
  __shared__ short8_t w2frag[16 * 64];
  __shared__ float4   w1f[144];

  int tid = threadIdx.x;
  int n0 = blockIdx.x * NPB;
  int ebase = offsets[n0];
  int eend  = offsets[n0 + NPB];

  if (tid < 128) {
    int j = tid >> 1, hf = tid & 1;
    float4 wv4;
    wv4.x = fc_w1[(hf * 4 + 0) * 64 + j] * INV_SQRT8;
    wv4.y = fc_w1[(hf * 4 + 1) * 64 + j] * INV_SQRT8;
    wv4.z = fc_w1[(hf * 4 + 2) * 64 + j] * INV_SQRT8;
    wv4.w = fc_w1[(hf * 4 + 3) * 64 + j] * INV_SQRT8;
    w1f[(j >> 3) * 18 + (j & 7) * 2 + hf] = wv4;
  }
  for (int fi = tid; fi < 16 * 64; fi += 256) {
    int f = fi >> 6, ll = fi & 63;
    int ct = f >> 1, kh = f & 1, mm = ll & 15, qq = ll >> 4;
    short8_t v;
    #pragma unroll
    for (int j = 0; j < 8; ++j)
      v[j] = (short)bf16r(fc_w2[(kh * 32 + qq * 8 + j) * 128 + ct * 16 + mm]);
    w2frag[fi] = v;
  }
  __syncthreads();

  int wv = tid >> 6;
  int l  = tid & 63;
  int m  = l & 15;
  int q  = l >> 4;
  int et = wv & 1;
  int ch = wv >> 1;

  int nA = 2 * wv;
  int offA0 = offsets[n0 + nA];
  int offA1 = offsets[n0 + nA + 1];
  int offB1 = offsets[n0 + nA + 2];
  float4_t racA = {0.f, 0.f, 0.f, 0.f};
  float4_t racB = {0.f, 0.f, 0.f, 0.f};

  for (int k0 = ebase; k0 < eend; k0 += CHUNK) {
    {
      int ecs = k0 + et * 16 + m;
      int ecc = (ecs < eend) ? ecs : (eend - 1);
      int srcm = PSRC[ecc];
      float4 eam = *(const float4*)(PEA + ecc);
      float4 sA  = *(const float4*)(PES + 2 * (long)ecc);
      float4 sB  = *(const float4*)(PES + 2 * (long)ecc + 1);
      float es0 = sA.x, es1 = sA.y, es2 = sA.z, es3 = sA.w;
      float es4 = sB.x, es5 = sB.y, es6 = sB.z, es7 = sB.w;

      short8_t a0, a1;
      #pragma unroll
      for (int jj = 0; jj < 8; ++jj) {
        float4 wA = w1f[q * 18 + jj * 2 + 0];
        float4 wB = w1f[q * 18 + jj * 2 + 1];
        float x = es0 * wA.x + es1 * wA.y + es2 * wA.z + es3 * wA.w
                + es4 * wB.x + es5 * wB.y + es6 * wB.z + es7 * wB.w;
        float hv = (x * H_SCALE) / (1.f + __expf(-x));
        a0[jj] = (short)bf16r(hv);
        float4 wC = w1f[(4 + q) * 18 + jj * 2 + 0];
        float4 wD = w1f[(4 + q) * 18 + jj * 2 + 1];
        float x2 = es0 * wC.x + es1 * wC.y + es2 * wC.z + es3 * wC.w
                 + es4 * wD.x + es5 * wD.y + es6 * wD.z + es7 * wD.w;
        float hv2 = (x2 * H_SCALE) / (1.f + __expf(-x2));
        a1[jj] = (short)bf16r(hv2);
      }

      int sl0 = q * 4, sl1 = sl0 + 1, sl2 = sl0 + 2, sl3 = sl0 + 3;
      int src0 = __shfl(srcm, sl0, 64), src1 = __shfl(srcm, sl1, 64);
      int src2 = __shfl(srcm, sl2, 64), src3 = __shfl(srcm, sl3, 64);
      float ea0x = __shfl(eam.x, sl0, 64), ea0y = __shfl(eam.y, sl0, 64),
            ea0z = __shfl(eam.z, sl0, 64), ea0w = __shfl(eam.w, sl0, 64);
      float ea1x = __shfl(eam.x, sl1, 64), ea1y = __shfl(eam.y, sl1, 64),
            ea1z = __shfl(eam.z, sl1, 64), ea1w = __shfl(eam.w, sl1, 64);
      float ea2x = __shfl(eam.x, sl2, 64), ea2y = __shfl(eam.y, sl2, 64),
            ea2z = __shfl(eam.z, sl2, 64), ea2w = __shfl(eam.w, sl2, 64);
      float ea3x = __shfl(eam.x, sl3, 64), ea3y = __shfl(eam.y, sl3, 64),
            ea3z = __shfl(eam.z, sl3, 64), ea3w = __shfl(eam.w, sl3, 64);

      RowData d0 = load_row(A + (long)src0 * 128, m);
      RowData d1 = load_row(A + (long)src1 * 128, m);
      RowData d2 = load_row(A + (long)src2 * 128, m);
      RowData d3 = load_row(A + (long)src3 * 128, m);

      float4_t acL[2], acH[2];
      #pragma unroll
      for (int uo = 0; uo < 2; ++uo) {
        int tl = ch * 2 + uo;
        short8_t bl0 = w2frag[(tl * 2 + 0) * 64 + l];
        short8_t bl1 = w2frag[(tl * 2 + 1) * 64 + l];
        float4_t zl = (float4_t){0.f, 0.f, 0.f, 0.f};
        zl = __builtin_amdgcn_mfma_f32_16x16x32_bf16(a0, bl0, zl, 0, 0, 0);
        zl = __builtin_amdgcn_mfma_f32_16x16x32_bf16(a1, bl1, zl, 0, 0, 0);
        acL[uo] = zl;
        int th = 4 + ch * 2 + uo;
        short8_t bh0 = w2frag[(th * 2 + 0) * 64 + l];
        short8_t bh1 = w2frag[(th * 2 + 1) * 64 + l];
        float4_t zh = (float4_t){0.f, 0.f, 0.f, 0.f};
        zh = __builtin_amdgcn_mfma_f32_16x16x32_bf16(a0, bh0, zh, 0, 0, 0);
        zh = __builtin_amdgcn_mfma_f32_16x16x32_bf16(a1, bh1, zh, 0, 0, 0);
        acH[uo] = zh;
      }

#define EPI(R, D, EAX, EAY, EAZ, EAW) do {                                       \
        float* mrow = mid + (et * 16 + q * 4 + (R)) * MROW;                      \
        { float wAa = acL[0][R], wBb = acH[0][R];                                \
          if (ch == 0) {                                                         \
            mrow[m] = wAa * D.se0 * EAX;                                         \
            float b = wBb * EAX;                                                 \
            mrow[160 + 3 * m + 0] = b * D.vx0;                                   \
            mrow[160 + 3 * m + 1] = b * D.vy0;                                   \
            mrow[160 + 3 * m + 2] = b * D.vz0;                                   \
          } else {                                                               \
            float dv = D.vx0 * EAY + D.vy0 * EAZ + D.vz0 * EAW;                  \
            mrow[32 + m] = wBb * dv * INV_SQRT3_C;                               \
            float b = wAa * D.se0;                                               \
            mrow[64 + 3 * m + 0] = b * EAY;                                      \
            mrow[64 + 3 * m + 1] = b * EAZ;                                      \
            mrow[64 + 3 * m + 2] = b * EAW;                                      \
          } }                                                                    \
        { float wAa = acL[1][R], wBb = acH[1][R];                                \
          int uu = 16 + m;                                                       \
          if (ch == 0) {                                                         \
            mrow[uu] = wAa * D.se1 * EAX;                                        \
            float b = wBb * EAX;                                                 \
            mrow[160 + 3 * uu + 0] = b * D.vx1;                                  \
            mrow[160 + 3 * uu + 1] = b * D.vy1;                                  \
            mrow[160 + 3 * uu + 2] = b * D.vz1;                                  \
          } else {                                                               \
            float dv = D.vx1 * EAY + D.vy1 * EAZ + D.vz1 * EAW;                  \
            mrow[32 + uu] = wBb * dv * INV_SQRT3_C;                              \
            float b = wAa * D.se1;                                               \
            mrow[64 + 3 * uu + 0] = b * EAY;                                     \
            mrow[64 + 3 * uu + 1] = b * EAZ;                                     \
            mrow[64 + 3 * uu + 2] = b * EAW;                                     \
          } }                                                                    \
      } while (0)

      EPI(0, d0, ea0x, ea0y, ea0z, ea0w);
      EPI(1, d1, ea1x, ea1y, ea1z, ea1w);
      EPI(2, d2, ea2x, ea2y, ea2z, ea2w);
      EPI(3, d3, ea3x, ea3y, ea3z, ea3w);
#undef EPI
    }
    __syncthreads();

    {
      int lo = (offA0 > k0) ? offA0 : k0;
      int hiA = offA1 < (k0 + CHUNK) ? offA1 : (k0 + CHUNK);
      for (int e = lo; e < hiA; ++e) {
        float4_t v = *(const float4_t*)(mid + (e - k0) * MROW + 4 * l);
        racA.x += v.x; racA.y += v.y; racA.z += v.z; racA.w += v.w;
      }
      int lo2 = (offA1 > k0) ? offA1 : k0;
      int hiB = offB1 < (k0 + CHUNK) ? offB1 : (k0 + CHUNK);
      for (int e = lo2; e < hiB; ++e) {
        float4_t v = *(const float4_t*)(mid + (e - k0) * MROW + 4 * l);
        racB.x += v.x; racB.y += v.y; racB.z += v.z; racB.w += v.w;
      }
    }
    __syncthreads();
  }

  *(float4_t*)(ACC + (long)(n0 + nA) * 256 + 4 * l)     = racA;
  *(float4_t*)(ACC + (long)(n0 + nA + 1) * 256 + 4 * l) = racB;
}

// ---------------- tier3: R4 k_edge kept verbatim -----------------------------
__global__ __launch_bounds__(256, 4) void k_edge_fb(
    const float* __restrict__ A,
    const int* __restrict__ edge_src,
    const int* __restrict__ edge_dst,
    const float* __restrict__ edge_attr,
    const float* __restrict__ edge_scalars,
    const float* __restrict__ fc_w1,
    const float* __restrict__ fc_w2,
    const int* __restrict__ offsets,
    const int* __restrict__ slots,
    float* __restrict__ ACC) {
  const float INV_SQRT8 = 0.35355339059327373f;
  const float H_SCALE   = 1.6791767923989418f / 8.0f;

  __shared__ float    lacc[NPB * LROW];
  __shared__ short8_t w2frag[16 * 64];
  __shared__ float4   w1f[144];

  int tid = threadIdx.x;
  int n0 = blockIdx.x * NPB;
  int ebase = offsets[n0];
  int eend  = offsets[n0 + NPB];

  for (int i = tid; i < NPB * LROW; i += 256) lacc[i] = 0.f;
  if (tid < 128) {
    int j = tid >> 1, hf = tid & 1;
    float4 wv4;
    wv4.x = fc_w1[(hf * 4 + 0) * 64 + j] * INV_SQRT8;
    wv4.y = fc_w1[(hf * 4 + 1) * 64 + j] * INV_SQRT8;
    wv4.z = fc_w1[(hf * 4 + 2) * 64 + j] * INV_SQRT8;
    wv4.w = fc_w1[(hf * 4 + 3) * 64 + j] * INV_SQRT8;
    w1f[(j >> 3) * 18 + (j & 7) * 2 + hf] = wv4;
  }
  for (int fi = tid; fi < 16 * 64; fi += 256) {
    int f = fi >> 6, ll = fi & 63;
    int ct = f >> 1, kh = f & 1, mm = ll & 15, qq = ll >> 4;
    short8_t v;
    #pragma unroll
    for (int j = 0; j < 8; ++j)
      v[j] = (short)bf16r(fc_w2[(kh * 32 + qq * 8 + j) * 128 + ct * 16 + mm]);
    w2frag[fi] = v;
  }
  __syncthreads();

  int wv = tid >> 6;
  int l  = tid & 63;
  int m  = l & 15;
  int q  = l >> 4;

  for (int k0 = ebase; k0 < eend; k0 += 64) {
    int ce = k0 + 4 * m + wv;
    bool vld = ce < eend;
    int e = slots[vld ? ce : (eend - 1)];
    int srcm = edge_src[e];
    int lnm  = edge_dst[e] - n0;
    float4 eam = ld4(edge_attr + (long)e * 4);
    float4 sA = ld4(edge_scalars + (long)e * 8);
    float4 sB = ld4(edge_scalars + (long)e * 8 + 4);
    float es0 = sA.x, es1 = sA.y, es2 = sA.z, es3 = sA.w;
    float es4 = sB.x, es5 = sB.y, es6 = sB.z, es7 = sB.w;

    short8_t a0, a1;
    #pragma unroll
    for (int jj = 0; jj < 8; ++jj) {
      float4 wA = w1f[q * 18 + jj * 2 + 0];
      float4 wB = w1f[q * 18 + jj * 2 + 1];
      float x = es0 * wA.x + es1 * wA.y + es2 * wA.z + es3 * wA.w
              + es4 * wB.x + es5 * wB.y + es6 * wB.z + es7 * wB.w;
      float hv = vld ? (x * H_SCALE) / (1.f + __expf(-x)) : 0.f;
      a0[jj] = (short)bf16r(hv);
      float4 wC = w1f[(4 + q) * 18 + jj * 2 + 0];
      float4 wD = w1f[(4 + q) * 18 + jj * 2 + 1];
      float x2 = es0 * wC.x + es1 * wC.y + es2 * wC.z + es3 * wC.w
               + es4 * wD.x + es5 * wD.y + es6 * wD.z + es7 * wD.w;
      float hv2 = vld ? (x2 * H_SCALE) / (1.f + __expf(-x2)) : 0.f;
      a1[jj] = (short)bf16r(hv2);
    }

    int sl0 = q * 4, sl1 = sl0 + 1, sl2 = sl0 + 2, sl3 = sl0 + 3;
    int src0 = __shfl(srcm, sl0, 64), src1 = __shfl(srcm, sl1, 64);
    int src2 = __shfl(srcm, sl2, 64), src3 = __shfl(srcm, sl3, 64);
    int ln0 = __shfl(lnm, sl0, 64), ln1 = __shfl(lnm, sl1, 64);
    int ln2 = __shfl(lnm, sl2, 64), ln3 = __shfl(lnm, sl3, 64);
    float ea0x = __shfl(eam.x, sl0, 64), ea0y = __shfl(eam.y, sl0, 64),
          ea0z = __shfl(eam.z, sl0, 64), ea0w = __shfl(eam.w, sl0, 64);
    float ea1x = __shfl(eam.x, sl1, 64), ea1y = __shfl(eam.y, sl1, 64),
          ea1z = __shfl(eam.z, sl1, 64), ea1w = __shfl(eam.w, sl1, 64);
    float ea2x = __shfl(eam.x, sl2, 64), ea2y = __shfl(eam.y, sl2, 64),
          ea2z = __shfl(eam.z, sl2, 64), ea2w = __shfl(eam.w, sl2, 64);
    float ea3x = __shfl(eam.x, sl3, 64), ea3y = __shfl(eam.y, sl3, 64),
          ea3z = __shfl(eam.z, sl3, 64), ea3w = __shfl(eam.w, sl3, 64);

    const float* abA = A + (long)src0 * 128;
    const float* abB = A + (long)src1 * 128;
    RowData dA = load_row(abA, m);
    RowData dB = load_row(abB, m);

    float4_t acc[8];
    #pragma unroll
    for (int t = 0; t < 8; ++t) {
      short8_t b0 = w2frag[(t * 2 + 0) * 64 + l];
      short8_t b1 = w2frag[(t * 2 + 1) * 64 + l];
      float4_t z = (float4_t){0.f, 0.f, 0.f, 0.f};
      z = __builtin_amdgcn_mfma_f32_16x16x32_bf16(a0, b0, z, 0, 0, 0);
      z = __builtin_amdgcn_mfma_f32_16x16x32_bf16(a1, b1, z, 0, 0, 0);
      acc[t] = z;
    }

    const float* abC = A + (long)src2 * 128;
    const float* abD = A + (long)src3 * 128;
    RowData dC = load_row(abC, m);
    RowData dD = load_row(abD, m);

    #define ACCUM_ROW(RR, LN, EAX, EAY, EAZ, EAW, D) do {                        \
        float* lrow = lacc + (LN) * LROW;                                        \
        accum_half(lrow, m,      acc[0][RR], acc[2][RR], acc[4][RR], acc[6][RR], \
                   D.se0, D.vx0, D.vy0, D.vz0, EAX, EAY, EAZ, EAW);              \
        accum_half(lrow, m + 16, acc[1][RR], acc[3][RR], acc[5][RR], acc[7][RR], \
                   D.se1, D.vx1, D.vy1, D.vz1, EAX, EAY, EAZ, EAW);              \
      } while (0)

    if (k0 + 64 <= eend) {
      ACCUM_ROW(0, ln0, ea0x, ea0y, ea0z, ea0w, dA);
      ACCUM_ROW(1, ln1, ea1x, ea1y, ea1z, ea1w, dB);
      ACCUM_ROW(2, ln2, ea2x, ea2y, ea2z, ea2w, dC);
      ACCUM_ROW(3, ln3, ea3x, ea3y, ea3z, ea3w, dD);
    } else {
      int cb = k0 + 16 * q + wv;
      if (cb + 0  < eend) ACCUM_ROW(0, ln0, ea0x, ea0y, ea0z, ea0w, dA);
      if (cb + 4  < eend) ACCUM_ROW(1, ln1, ea1x, ea1y, ea1z, ea1w, dB);
      if (cb + 8  < eend) ACCUM_ROW(2, ln2, ea2x, ea2y, ea2z, ea2w, dC);
      if (cb + 12 < eend) ACCUM_ROW(3, ln3, ea3x, ea3y, ea3z, ea3w, dD);
    }
    #undef ACCUM_ROW
  }
  __syncthreads();

  for (int i = tid; i < NPB * 256; i += 256) {
    int node = i >> 8;
    int c = i & 255;
    ACC[(long)(n0 + node) * 256 + c] = lacc[node * LROW + c];
  }
}

// ---------------- Stage 2 ----------------
__global__ void k3_stage2(const float* __restrict__ ACC,
                          const float* __restrict__ w2s,
                          const float* __restrict__ w2v,
                          float* __restrict__ out) {
  const float scale = 0.03125f; // (1/sqrt(16)) / sqrt(64)
  int stride = gridDim.x * blockDim.x;
  for (int idx = blockIdx.x * blockDim.x + threadIdx.x; idx < NNODES * 128; idx += stride) {
    int n = idx >> 7;
    int c = idx & 127;
    const float* row = ACC + (long)n * 256;
    float acc = 0.f;
    if (c < 32) {
      #pragma unroll
      for (int qq = 0; qq < 64; ++qq)
        acc = fmaf(row[qq], w2s[qq * 32 + c], acc);
    } else {
      int cc = c - 32;
      int w = cc / 3;
      int i = cc - w * 3;
      #pragma unroll
      for (int qq = 0; qq < 64; ++qq)
        acc = fmaf(row[64 + qq * 3 + i], w2v[qq * 32 + w], acc);
    }
    out[idx] = acc * scale;
  }
}

extern "C" void kernel_launch(void* const* d_in, const int* in_sizes, int n_in,
                              void* d_out, int out_size, void* d_ws, size_t ws_size,
                              hipStream_t stream) {
  const float* node_input   = (const float*)d_in[0];
  const int*   edge_src     = (const int*)d_in[2];
  const int*   edge_dst     = (const int*)d_in[3];
  const float* edge_attr    = (const float*)d_in[4];
  const float* edge_scalars = (const float*)d_in[5];
  const float* fc_w1        = (const float*)d_in[8];
  const float* fc_w2        = (const float*)d_in[9];
  const float* w_lin1_s     = (const float*)d_in[6];
  const float* w_lin1_v     = (const float*)d_in[7];
  const float* w_lin2_s     = (const float*)d_in[10];
  const float* w_lin2_v     = (const float*)d_in[11];

  float* out = (float*)d_out;
  float* Abuf = out;  // stage-1 output lives in d_out; k3 overwrites it after edge kernel

  const size_t SZ_ACC = (size_t)NNODES * 256 * sizeof(float);   // 40.96 MB
  const size_t SZ_PE  = (size_t)NEDGES * 64;                    // 40.96 MB (tier1)
  const size_t SZ_PES = (size_t)NEDGES * 32;                    // 20.48 MB (tier2)
  const size_t SZ_PEA = (size_t)NEDGES * 16;                    // 10.24 MB (tier2)
  const size_t SZ_PSR = (size_t)NEDGES * 4;                     //  2.56 MB (tier2)
  const size_t SZ_CNT = (size_t)NNODES * sizeof(int);
  const size_t SZ_OFF = (size_t)(NNODES + 4) * sizeof(int);
  const size_t SZ_SLT = (size_t)NEDGES * sizeof(int);
  const size_t need1 = SZ_ACC + SZ_PE + 3 * SZ_CNT + SZ_OFF + 2048;
  const size_t need2 = SZ_ACC + SZ_PES + SZ_PEA + SZ_PSR + 3 * SZ_CNT + SZ_OFF + 2048;

  if (ws_size >= need1) {
    // ---- tier1: R7 64B-record + dedup/occupancy edge kernel
    char* p = (char*)d_ws;
    float*    ACC = (float*)p;    p += SZ_ACC;
    float4_t* PE  = (float4_t*)p; p += SZ_PE;
    int* counts   = (int*)p;      p += SZ_CNT;
    int* offsets  = (int*)p;      p += SZ_OFF;
    int* cursor   = (int*)p;      p += SZ_CNT;
    int* bsum     = (int*)p;      p += 160 * sizeof(int);
    int* boff     = (int*)p;      p += 160 * sizeof(int);

    hipMemsetAsync(counts, 0, SZ_CNT, stream);
    k1_stage1<<<2048, 256, 0, stream>>>(node_input, w_lin1_s, w_lin1_v, Abuf);
    k_hist<<<NEDGES / 256, 256, 0, stream>>>(edge_dst, counts);
    k_scanA<<<157, 256, 0, stream>>>(counts, bsum);
    k_scanB<<<1, 256, 0, stream>>>(bsum, boff, offsets);
    k_scanC<<<157, 256, 0, stream>>>(counts, boff, offsets, cursor);
    k_scatter_pack3<<<NEDGES / 256, 256, 0, stream>>>(edge_src, edge_dst, edge_attr,
                                                      edge_scalars, cursor, PE);
    k_edge4<<<NNODES / NPB, 256, 0, stream>>>(Abuf, PE, fc_w1, fc_w2, offsets, ACC);
    k3_stage2<<<2048, 256, 0, stream>>>(ACC, w_lin2_s, w_lin2_v, out);
  } else if (ws_size >= need2) {
    // ---- tier2: proven R6 path
    char* p = (char*)d_ws;
    float*    ACC = (float*)p;    p += SZ_ACC;
    float4_t* PES = (float4_t*)p; p += SZ_PES;
    float4_t* PEA = (float4_t*)p; p += SZ_PEA;
    int*      PSRC = (int*)p;     p += SZ_PSR;
    int* counts   = (int*)p;      p += SZ_CNT;
    int* offsets  = (int*)p;      p += SZ_OFF;
    int* cursor   = (int*)p;      p += SZ_CNT;
    int* bsum     = (int*)p;      p += 160 * sizeof(int);
    int* boff     = (int*)p;      p += 160 * sizeof(int);

    hipMemsetAsync(counts, 0, SZ_CNT, stream);
    k1_stage1<<<2048, 256, 0, stream>>>(node_input, w_lin1_s, w_lin1_v, Abuf);
    k_hist<<<NEDGES / 256, 256, 0, stream>>>(edge_dst, counts);
    k_scanA<<<157, 256, 0, stream>>>(counts, bsum);
    k_scanB<<<1, 256, 0, stream>>>(bsum, boff, offsets);
    k_scanC<<<157, 256, 0, stream>>>(counts, boff, offsets, cursor);
    k_scatter_pack2<<<NEDGES / 256, 256, 0, stream>>>(edge_src, edge_dst, edge_attr,
                                                      edge_scalars, cursor, PSRC, PEA, PES);
    k_edge3<<<NNODES / NPB, 256, 0, stream>>>(Abuf, PSRC, PEA, PES, fc_w1, fc_w2,
                                              offsets, ACC);
    k3_stage2<<<2048, 256, 0, stream>>>(ACC, w_lin2_s, w_lin2_v, out);
  } else {
    // ---- tier3: proven R4 fallback
    char* p = (char*)d_ws;
    float* ACC    = (float*)p;  p += SZ_ACC;
    int* counts   = (int*)p;    p += SZ_CNT;
    int* offsets  = (int*)p;    p += SZ_OFF;
    int* cursor   = (int*)p;    p += SZ_CNT;
    int* slots    = (int*)p;    p += SZ_SLT;
    int* bsum     = (int*)p;    p += 160 * sizeof(int);
    int* boff     = (int*)p;    p += 160 * sizeof(int);

    hipMemsetAsync(counts, 0, SZ_CNT, stream);
    k1_stage1<<<2048, 256, 0, stream>>>(node_input, w_lin1_s, w_lin1_v, Abuf);
    k_hist<<<NEDGES / 256, 256, 0, stream>>>(edge_dst, counts);
    k_scanA<<<157, 256, 0, stream>>>(counts, bsum);
    k_scanB<<<1, 256, 0, stream>>>(bsum, boff, offsets);
    k_scanC<<<157, 256, 0, stream>>>(counts, boff, offsets, cursor);
    k_scatter<<<NEDGES / 256, 256, 0, stream>>>(edge_dst, cursor, slots);
    k_edge_fb<<<NNODES / NPB, 256, 0, stream>>>(Abuf, edge_src, edge_dst, edge_attr,
                                                edge_scalars, fc_w1, fc_w2,
                                                offsets, slots, ACC);
    k3_stage2<<<2048, 256, 0, stream>>>(ACC, w_lin2_s, w_lin2_v, out);
  }
}

// Round 5
// 337.113 us; speedup vs baseline: 3.7258x; 1.3849x over previous
//
#include <hip/hip_runtime.h>
#include <math.h>

#define NNODES 40000
#define NEDGES 640000
#define NPB 8             // nodes per edge-block
#define LROW 257          // fallback kernels: padded LDS accumulator row stride
#define CHUNK 32          // edges per chunk in k_edge3 (tier2)
#define CHUNK4 16         // edges per chunk in k_edge4b (tier1)
#define MROW 260          // mid row stride (floats): 16B-aligned, 4-bank row shift
#define NB1 8             // nodes per block, k1_stage1b
#define NB3 8             // nodes per block, k3_stage2b

typedef __attribute__((ext_vector_type(8))) short short8_t;
typedef __attribute__((ext_vector_type(4))) short short4_t;
typedef __attribute__((ext_vector_type(4))) float float4_t;

__device__ __forceinline__ float4 ld4(const float* p) { return *(const float4*)p; }

__device__ __forceinline__ unsigned short bf16r(float x) {
  union { float f; unsigned u; } v; v.f = x;
  unsigned u = v.u;
  u += 0x7FFFu + ((u >> 16) & 1u);   // RNE
  return (unsigned short)(u >> 16);
}

__device__ __forceinline__ void lds_fadd(float* p, float v) {
  __hip_atomic_fetch_add(p, v, __ATOMIC_RELAXED, __HIP_MEMORY_SCOPE_WORKGROUP);
}

#define INV_SQRT3_C 0.57735026918962576f

// tier3-kernel helper (R4, proven)
__device__ __forceinline__ void accum_half(float* lrow, int u,
    float w0, float w1, float w2, float w3,
    float se, float vx, float vy, float vz,
    float esc, float ev0, float ev1, float ev2) {
  lds_fadd(lrow + u, w0 * se * esc);
  float dv = vx * ev0 + vy * ev1 + vz * ev2;
  lds_fadd(lrow + 32 + u, w3 * dv * INV_SQRT3_C);
  float b1v = w1 * se;
  lds_fadd(lrow + 64 + u * 3 + 0, b1v * ev0);
  lds_fadd(lrow + 64 + u * 3 + 1, b1v * ev1);
  lds_fadd(lrow + 64 + u * 3 + 2, b1v * ev2);
  float b2v = w2 * esc;
  lds_fadd(lrow + 160 + u * 3 + 0, b2v * vx);
  lds_fadd(lrow + 160 + u * 3 + 1, b2v * vy);
  lds_fadd(lrow + 160 + u * 3 + 2, b2v * vz);
}

struct RowData { float se0, se1, vx0, vy0, vz0, vx1, vy1, vz1; };

__device__ __forceinline__ RowData load_row(const float* ab, int m) {
  RowData d;
  d.se0 = ab[m];            d.se1 = ab[m + 16];
  d.vx0 = ab[32 + 3 * m];   d.vy0 = ab[33 + 3 * m];   d.vz0 = ab[34 + 3 * m];
  d.vx1 = ab[80 + 3 * m];   d.vy1 = ab[81 + 3 * m];   d.vz1 = ab[82 + 3 * m];
  return d;
}

// ---------------- Stage 1 (old SoA layout; tiers 2/3) ----------------
__global__ void k1_stage1(const float* __restrict__ node_input,
                          const float* __restrict__ w1s,
                          const float* __restrict__ w1v,
                          float* __restrict__ A) {
  const float scale = 0.17677669529663687f; // 1/sqrt(32)
  int stride = gridDim.x * blockDim.x;
  for (int idx = blockIdx.x * blockDim.x + threadIdx.x; idx < NNODES * 128; idx += stride) {
    int n = idx >> 7;
    int c = idx & 127;
    const float* row = node_input + n * 128;
    float acc = 0.f;
    if (c < 32) {
      #pragma unroll
      for (int u = 0; u < 32; ++u)
        acc = fmaf(row[u], w1s[u * 32 + c], acc);
    } else {
      int cc = c - 32;
      int w = cc / 3;
      int i = cc - w * 3;
      #pragma unroll
      for (int u = 0; u < 32; ++u)
        acc = fmaf(row[32 + u * 3 + i], w1v[u * 32 + w], acc);
    }
    A[idx] = acc * scale;
  }
}

// ---------------- Stage 1b — R8: divergence-free, LDS-staged, AoS output ----
// Old k1: wave lanes 0-31 take the s-branch, 32-63 the v-branch -> BOTH bodies
// execute serially under exec-mask (2x), all loads scalar (2-2.5x more).
// New: block = 8 nodes staged in LDS (float4 coalesced), weights prescaled in
// LDS; thread (g=t>>5, j=t&31) computes node g, u=j: {s'[u], v'[u][0..2]} and
// stores ONE float4 -> A2[n][u] AoS. k_edge4b then gathers each (src,u) as a
// single aligned dwordx4 instead of 4 scalar loads at 2 scattered granules.
__global__ __launch_bounds__(256) void k1_stage1b(
    const float* __restrict__ node_input,
    const float* __restrict__ w1s,
    const float* __restrict__ w1v,
    float* __restrict__ A2) {
  __shared__ float rows[NB1 * 128];   // 4 KB
  __shared__ float ws[32 * 32];       // 4 KB (prescaled)
  __shared__ float wvv[32 * 32];      // 4 KB (prescaled)
  const float scale = 0.17677669529663687f; // 1/sqrt(32)
  int tid = threadIdx.x;
  int n0 = blockIdx.x * NB1;

  float4 a = ((const float4*)w1s)[tid];          // 256 float4 = full 32x32
  a.x *= scale; a.y *= scale; a.z *= scale; a.w *= scale;
  ((float4*)ws)[tid] = a;
  float4 b = ((const float4*)w1v)[tid];
  b.x *= scale; b.y *= scale; b.z *= scale; b.w *= scale;
  ((float4*)wvv)[tid] = b;
  ((float4*)rows)[tid] = ((const float4*)(node_input + (long)n0 * 128))[tid];
  __syncthreads();

  int j = tid & 31, g = tid >> 5;
  const float* lr = rows + g * 128;
  float ac0 = 0.f, ac1 = 0.f, ac2 = 0.f, ac3 = 0.f;
  #pragma unroll
  for (int t = 0; t < 32; ++t) {
    float wsj = ws[t * 32 + j];
    float wvj = wvv[t * 32 + j];
    ac0 = fmaf(lr[t],            wsj, ac0);
    ac1 = fmaf(lr[32 + 3 * t],     wvj, ac1);
    ac2 = fmaf(lr[32 + 3 * t + 1], wvj, ac2);
    ac3 = fmaf(lr[32 + 3 * t + 2], wvj, ac3);
  }
  float4 o; o.x = ac0; o.y = ac1; o.z = ac2; o.w = ac3;
  ((float4*)(A2 + (long)n0 * 128))[tid] = o;   // tid = g*32+j -> n0+g, u=j
}

// ---------------- CSR build ----------------
__global__ void k_hist(const int* __restrict__ edge_dst, int* __restrict__ counts) {
  int e = blockIdx.x * blockDim.x + threadIdx.x;
  if (e < NEDGES) atomicAdd(&counts[edge_dst[e]], 1);
}

__global__ void k_scanA(const int* __restrict__ counts, int* __restrict__ bsum) {
  __shared__ int ws[4];
  int t = blockIdx.x * 256 + threadIdx.x;
  int v = (t < NNODES) ? counts[t] : 0;
  for (int d = 32; d; d >>= 1) v += __shfl_down(v, d, 64);
  if ((threadIdx.x & 63) == 0) ws[threadIdx.x >> 6] = v;
  __syncthreads();
  if (threadIdx.x == 0) bsum[blockIdx.x] = ws[0] + ws[1] + ws[2] + ws[3];
}

__global__ __launch_bounds__(256) void k_scanB(const int* __restrict__ bsum,
                                               int* __restrict__ boff,
                                               int* __restrict__ offsets) {
  __shared__ int s[256];
  int tid = threadIdx.x;
  int v = (tid < 157) ? bsum[tid] : 0;
  s[tid] = v;
  __syncthreads();
  for (int d = 1; d < 256; d <<= 1) {
    int x = (tid >= d) ? s[tid - d] : 0;
    __syncthreads();
    s[tid] += x;
    __syncthreads();
  }
  if (tid < 157) boff[tid] = s[tid] - v;
  if (tid == 0) offsets[NNODES] = NEDGES;
}

__global__ __launch_bounds__(256) void k_scanC(const int* __restrict__ counts,
                                               const int* __restrict__ boff,
                                               int* __restrict__ offsets,
                                               int* __restrict__ cursor) {
  __shared__ int s[256];
  int tid = threadIdx.x;
  int t = blockIdx.x * 256 + tid;
  int v = (t < NNODES) ? counts[t] : 0;
  s[tid] = v;
  __syncthreads();
  for (int d = 1; d < 256; d <<= 1) {
    int x = (tid >= d) ? s[tid - d] : 0;
    __syncthreads();
    s[tid] += x;
    __syncthreads();
  }
  int off = boff[blockIdx.x] + s[tid] - v;
  if (t < NNODES) { offsets[t] = off; cursor[t] = off; }
}

// tier3 scatter (slots only)
__global__ void k_scatter(const int* __restrict__ edge_dst,
                          int* __restrict__ cursor, int* __restrict__ slots) {
  int e = blockIdx.x * blockDim.x + threadIdx.x;
  if (e < NEDGES) {
    int d = edge_dst[e];
    int p = atomicAdd(&cursor[d], 1);
    slots[p] = e;
  }
}

// tier2 scatter (R6, proven)
__global__ void k_scatter_pack2(const int* __restrict__ edge_src,
                                const int* __restrict__ edge_dst,
                                const float* __restrict__ edge_attr,
                                const float* __restrict__ edge_scalars,
                                int* __restrict__ cursor,
                                int* __restrict__ PSRC,
                                float4_t* __restrict__ PEA,
                                float4_t* __restrict__ PES) {
  int e = blockIdx.x * blockDim.x + threadIdx.x;
  if (e < NEDGES) {
    int d = edge_dst[e];
    int p = atomicAdd(&cursor[d], 1);
    PSRC[p] = edge_src[e];
    PEA[p] = *(const float4_t*)(edge_attr + (long)e * 4);
    PES[2 * p]     = *(const float4_t*)(edge_scalars + (long)e * 8);
    PES[2 * p + 1] = *(const float4_t*)(edge_scalars + (long)e * 8 + 4);
  }
}

// tier1 scatter (R7, proven): one aligned 64B record per edge
__global__ void k_scatter_pack3(const int* __restrict__ edge_src,
                                const int* __restrict__ edge_dst,
                                const float* __restrict__ edge_attr,
                                const float* __restrict__ edge_scalars,
                                int* __restrict__ cursor,
                                float4_t* __restrict__ PE) {
  int e = blockIdx.x * blockDim.x + threadIdx.x;
  if (e < NEDGES) {
    int d = edge_dst[e];
    int p = atomicAdd(&cursor[d], 1);
    float4_t* b = PE + (long)p * 4;
    b[0] = *(const float4_t*)(edge_attr + (long)e * 4);
    b[1] = *(const float4_t*)(edge_scalars + (long)e * 8);
    b[2] = *(const float4_t*)(edge_scalars + (long)e * 8 + 4);
    float4_t s;
    s.x = __int_as_float(edge_src[e]); s.y = 0.f; s.z = 0.f; s.w = 0.f;
    b[3] = s;
  }
}

// ---------------- Fused edge kernel — R8: AoS float4 A-gather ----------------
// Identical to proven R7 k_edge4 except the A-row gather: A2 is AoS
// ({s',vx,vy,vz} per (n,u)) so each of the 4 rows needs ONE dwordx4 instead of
// 4 scalar loads at 2 scattered granules. 16 -> 4 gather instrs/lane/chunk.
__global__ __launch_bounds__(256, 4) void k_edge4b(
    const float* __restrict__ A2,
    const float4_t* __restrict__ PE,
    const float* __restrict__ fc_w1,
    const float* __restrict__ fc_w2,
    const int* __restrict__ offsets,
    float* __restrict__ ACC) {
  const float INV_SQRT8 = 0.35355339059327373f;
  const float H_SCALE   = 1.6791767923989418f / 8.0f; // SILU_NORM / sqrt(64)

  __shared__ float  mid[CHUNK4 * MROW];   // 16,640 B
  __shared__ short  h_lds[CHUNK4 * 72];   //  2,304 B (144B row stride)
  __shared__ float4 w1f[144];             //  2,304 B

  int tid = threadIdx.x;
  int n0 = blockIdx.x * NPB;
  int ebase = offsets[n0];
  int eend  = offsets[n0 + NPB];

  if (tid < 128) {
    int j = tid >> 1, hf = tid & 1;
    float4 wv4;
    wv4.x = fc_w1[(hf * 4 + 0) * 64 + j] * INV_SQRT8;
    wv4.y = fc_w1[(hf * 4 + 1) * 64 + j] * INV_SQRT8;
    wv4.z = fc_w1[(hf * 4 + 2) * 64 + j] * INV_SQRT8;
    wv4.w = fc_w1[(hf * 4 + 3) * 64 + j] * INV_SQRT8;
    w1f[(j >> 3) * 18 + (j & 7) * 2 + hf] = wv4;
  }

  int wv = tid >> 6;       // wave id 0..3
  int l  = tid & 63;
  int m  = l & 15;
  int q  = l >> 4;
  int uh = wv & 1;         // u-half: u in [uh*16, uh*16+16)
  int cl = wv >> 1;        // column class
  int tL = cl * 2 + uh;    // w-tile for {w0|w1}
  int tH = 4 + cl * 2 + uh;// w-tile for {w2|w3}
  int u  = uh * 16 + m;

  // B-frags direct from global (fc_w2 is 32KB, L2-resident)
  short8_t bL0, bL1, bH0, bH1;
  #pragma unroll
  for (int j = 0; j < 8; ++j) {
    bL0[j] = (short)bf16r(fc_w2[(q * 8 + j) * 128      + tL * 16 + m]);
    bL1[j] = (short)bf16r(fc_w2[(32 + q * 8 + j) * 128 + tL * 16 + m]);
    bH0[j] = (short)bf16r(fc_w2[(q * 8 + j) * 128      + tH * 16 + m]);
    bH1[j] = (short)bf16r(fc_w2[(32 + q * 8 + j) * 128 + tH * 16 + m]);
  }

  int nA = 2 * wv;
  int offA0 = offsets[n0 + nA];
  int offA1 = offsets[n0 + nA + 1];
  int offB1 = offsets[n0 + nA + 2];
  float4_t racA = {0.f, 0.f, 0.f, 0.f};
  float4_t racB = {0.f, 0.f, 0.f, 0.f};

  float ea0x, ea0y, ea0z, ea0w, ea1x, ea1y, ea1z, ea1w,
        ea2x, ea2y, ea2z, ea2w, ea3x, ea3y, ea3z, ea3w;
  float se0, se1, se2, se3, vx0, vx1, vx2, vx3,
        vy0, vy1, vy2, vy3, vz0, vz1, vz2, vz3;

  auto loadmeta = [&](int kb) {
    int ecs = kb + m;
    int ecc = (ecs < eend) ? ecs : (eend - 1);
    const float4_t* pb = PE + (long)ecc * 4;
    float4_t eam = pb[0];
    float4_t sA  = pb[1];
    float4_t sB  = pb[2];
    int srcm = __float_as_int(pb[3].x);
    // h quarter: k = wv*16 + q*4 + j
    int g  = wv * 2 + (q >> 1);
    int ob = (q & 1) * 4;
    short4_t hq;
    #pragma unroll
    for (int j = 0; j < 4; ++j) {
      float4 wA = w1f[g * 18 + (ob + j) * 2 + 0];
      float4 wB = w1f[g * 18 + (ob + j) * 2 + 1];
      float x = sA.x * wA.x + sA.y * wA.y + sA.z * wA.z + sA.w * wA.w
              + sB.x * wB.x + sB.y * wB.y + sB.z * wB.z + sB.w * wB.w;
      float hv = (x * H_SCALE) / (1.f + __expf(-x));
      hq[j] = (short)bf16r(hv);
    }
    *(short4_t*)((char*)h_lds + m * 144 + wv * 32 + q * 8) = hq;
    int sl0 = q * 4, sl1 = sl0 + 1, sl2 = sl0 + 2, sl3 = sl0 + 3;
    int src0 = __shfl(srcm, sl0, 64), src1 = __shfl(srcm, sl1, 64);
    int src2 = __shfl(srcm, sl2, 64), src3 = __shfl(srcm, sl3, 64);
    ea0x = __shfl(eam.x, sl0, 64); ea0y = __shfl(eam.y, sl0, 64);
    ea0z = __shfl(eam.z, sl0, 64); ea0w = __shfl(eam.w, sl0, 64);
    ea1x = __shfl(eam.x, sl1, 64); ea1y = __shfl(eam.y, sl1, 64);
    ea1z = __shfl(eam.z, sl1, 64); ea1w = __shfl(eam.w, sl1, 64);
    ea2x = __shfl(eam.x, sl2, 64); ea2y = __shfl(eam.y, sl2, 64);
    ea2z = __shfl(eam.z, sl2, 64); ea2w = __shfl(eam.w, sl2, 64);
    ea3x = __shfl(eam.x, sl3, 64); ea3y = __shfl(eam.y, sl3, 64);
    ea3z = __shfl(eam.z, sl3, 64); ea3w = __shfl(eam.w, sl3, 64);
    // AoS A2 gathers: one aligned dwordx4 per row
    float4 g0 = *(const float4*)(A2 + (long)src0 * 128 + 4 * u);
    float4 g1 = *(const float4*)(A2 + (long)src1 * 128 + 4 * u);
    float4 g2 = *(const float4*)(A2 + (long)src2 * 128 + 4 * u);
    float4 g3 = *(const float4*)(A2 + (long)src3 * 128 + 4 * u);
    se0 = g0.x; vx0 = g0.y; vy0 = g0.z; vz0 = g0.w;
    se1 = g1.x; vx1 = g1.y; vy1 = g1.z; vz1 = g1.w;
    se2 = g2.x; vx2 = g2.y; vy2 = g2.z; vz2 = g2.w;
    se3 = g3.x; vx3 = g3.y; vy3 = g3.z; vz3 = g3.w;
  };

  __syncthreads();    // w1f ready

  if (ebase < eend) {
    loadmeta(ebase);
    for (int k0 = ebase; k0 < eend; k0 += CHUNK4) {
      __syncthreads();  // h_lds published; prev-chunk mid reads done
      short8_t a0 = *(const short8_t*)((const char*)h_lds + m * 144 + q * 16);
      short8_t a1 = *(const short8_t*)((const char*)h_lds + m * 144 + 64 + q * 16);
      float4_t acL = {0.f, 0.f, 0.f, 0.f};
      float4_t acH = {0.f, 0.f, 0.f, 0.f};
      acL = __builtin_amdgcn_mfma_f32_16x16x32_bf16(a0, bL0, acL, 0, 0, 0);
      acL = __builtin_amdgcn_mfma_f32_16x16x32_bf16(a1, bL1, acL, 0, 0, 0);
      acH = __builtin_amdgcn_mfma_f32_16x16x32_bf16(a0, bH0, acH, 0, 0, 0);
      acH = __builtin_amdgcn_mfma_f32_16x16x32_bf16(a1, bH1, acH, 0, 0, 0);
#define EPI4(R, SE, VX, VY, VZ, EAX, EAY, EAZ, EAW) do {            \
        float* mrow = mid + (q * 4 + (R)) * MROW;                   \
        if (cl == 0) {                                              \
          mrow[u] = acL[R] * (SE) * (EAX);                          \
          float b = acH[R] * (EAX);                                 \
          mrow[160 + 3 * u + 0] = b * (VX);                         \
          mrow[160 + 3 * u + 1] = b * (VY);                         \
          mrow[160 + 3 * u + 2] = b * (VZ);                         \
        } else {                                                    \
          float dv = (VX) * (EAY) + (VY) * (EAZ) + (VZ) * (EAW);    \
          mrow[32 + u] = acH[R] * dv * INV_SQRT3_C;                 \
          float b = acL[R] * (SE);                                  \
          mrow[64 + 3 * u + 0] = b * (EAY);                         \
          mrow[64 + 3 * u + 1] = b * (EAZ);                         \
          mrow[64 + 3 * u + 2] = b * (EAW);                         \
        }                                                           \
      } while (0)
      EPI4(0, se0, vx0, vy0, vz0, ea0x, ea0y, ea0z, ea0w);
      EPI4(1, se1, vx1, vy1, vz1, ea1x, ea1y, ea1z, ea1w);
      EPI4(2, se2, vx2, vy2, vz2, ea2x, ea2y, ea2z, ea2w);
      EPI4(3, se3, vx3, vy3, vz3, ea3x, ea3y, ea3z, ea3w);
#undef EPI4
      __syncthreads();  // mid ready
      {
        int lo = (offA0 > k0) ? offA0 : k0;
        int hi = offA1 < (k0 + CHUNK4) ? offA1 : (k0 + CHUNK4);
        for (int e = lo; e < hi; ++e) {
          float4_t v = *(const float4_t*)(mid + (e - k0) * MROW + 4 * l);
          racA.x += v.x; racA.y += v.y; racA.z += v.z; racA.w += v.w;
        }
        int lo2 = (offA1 > k0) ? offA1 : k0;
        int hi2 = offB1 < (k0 + CHUNK4) ? offB1 : (k0 + CHUNK4);
        for (int e = lo2; e < hi2; ++e) {
          float4_t v = *(const float4_t*)(mid + (e - k0) * MROW + 4 * l);
          racB.x += v.x; racB.y += v.y; racB.z += v.z; racB.w += v.w;
        }
      }
      if (k0 + CHUNK4 < eend) loadmeta(k0 + CHUNK4);
    }
  }

  *(float4_t*)(ACC + (long)(n0 + nA) * 256 + 4 * l)     = racA;
  *(float4_t*)(ACC + (long)(n0 + nA + 1) * 256 + 4 * l) = racB;
}

// ---------------- tier2: R6 k_edge3 kept verbatim ----------------------------
__global__ __launch_bounds__(256, 3) void k_edge3(
    const float* __restrict__ A,
    const int* __restrict__ PSRC,
    const float4_t* __restrict__ PEA,
    const float4_t* __restrict__ PES,
    const float* __restrict__ fc_w1,
    const float* __restrict__ fc_w2,
    const int* __restrict__ offsets,
    float* __restrict__ ACC) {
  const float INV_SQRT8 = 0.35355339059327373f;
  const float H_SCALE   = 1.6791767923989418f / 8.0f;

  __shared__ float    mid[CHUNK * MROW];
  __shared__ short8_t w2frag[16 * 64];
  __shared__ float4   w1f[144];

  int tid = threadIdx.x;
  int n0 = blockIdx.x * NPB;
  int ebase = offsets[n0];
  int eend  = offsets[n0 + NPB];

  if (tid < 128) {
    int j = tid >> 1, hf = tid & 1;
    float4 wv4;
    wv4.x = fc_w1[(hf * 4 + 0) * 64 + j] * INV_SQRT8;
    wv4.y = fc_w1[(hf * 4 + 1) * 64 + j] * INV_SQRT8;
    wv4.z = fc_w1[(hf * 4 + 2) * 64 + j] * INV_SQRT8;
    wv4.w = fc_w1[(hf * 4 + 3) * 64 + j] * INV_SQRT8;
    w1f[(j >> 3) * 18 + (j & 7) * 2 + hf] = wv4;
  }
  for (int fi = tid; fi < 16 * 64; fi += 256) {
    int f = fi >> 6, ll = fi & 63;
    int ct = f >> 1, kh = f & 1, mm = ll & 15, qq = ll >> 4;
    short8_t v;
    #pragma unroll
    for (int j = 0; j < 8; ++j)
      v[j] = (short)bf16r(fc_w2[(kh * 32 + qq * 8 + j) * 128 + ct * 16 + mm]);
    w2frag[fi] = v;
  }
  __syncthreads();

  int wv = tid >> 6;
  int l  = tid & 63;
  int m  = l & 15;
  int q  = l >> 4;
  int et = wv & 1;
  int ch = wv >> 1;

  int nA = 2 * wv;
  int offA0 = offsets[n0 + nA];
  int offA1 = offsets[n0 + nA + 1];
  int offB1 = offsets[n0 + nA + 2];
  float4_t racA = {0.f, 0.f, 0.f, 0.f};
  float4_t racB = {0.f, 0.f, 0.f, 0.f};

  for (int k0 = ebase; k0 < eend; k0 += CHUNK) {
    {
      int ecs = k0 + et * 16 + m;
      int ecc = (ecs < eend) ? ecs : (eend - 1);
      int srcm = PSRC[ecc];
      float4 eam = *(const float4*)(PEA + ecc);
      float4 sA  = *(const float4*)(PES + 2 * (long)ecc);
      float4 sB  = *(const float4*)(PES + 2 * (long)ecc + 1);
      float es0 = sA.x, es1 = sA.y, es2 = sA.z, es3 = sA.w;
      float es4 = sB.x, es5 = sB.y, es6 = sB.z, es7 = sB.w;

      short8_t a0, a1;
      #pragma unroll
      for (int jj = 0; jj < 8; ++jj) {
        float4 wA = w1f[q * 18 + jj * 2 + 0];
        float4 wB = w1f[q * 18 + jj * 2 + 1];
        float x = es0 * wA.x + es1 * wA.y + es2 * wA.z + es3 * wA.w
                + es4 * wB.x + es5 * wB.y + es6 * wB.z + es7 * wB.w;
        float hv = (x * H_SCALE) / (1.f + __expf(-x));
        a0[jj] = (short)bf16r(hv);
        float4 wC = w1f[(4 + q) * 18 + jj * 2 + 0];
        float4 wD = w1f[(4 + q) * 18 + jj * 2 + 1];
        float x2 = es0 * wC.x + es1 * wC.y + es2 * wC.z + es3 * wC.w
                 + es4 * wD.x + es5 * wD.y + es6 * wD.z + es7 * wD.w;
        float hv2 = (x2 * H_SCALE) / (1.f + __expf(-x2));
        a1[jj] = (short)bf16r(hv2);
      }

      int sl0 = q * 4, sl1 = sl0 + 1, sl2 = sl0 + 2, sl3 = sl0 + 3;
      int src0 = __shfl(srcm, sl0, 64), src1 = __shfl(srcm, sl1, 64);
      int src2 = __shfl(srcm, sl2, 64), src3 = __shfl(srcm, sl3, 64);
      float ea0x = __shfl(eam.x, sl0, 64), ea0y = __shfl(eam.y, sl0, 64),
            ea0z = __shfl(eam.z, sl0, 64), ea0w = __shfl(eam.w, sl0, 64);
      float ea1x = __shfl(eam.x, sl1, 64), ea1y = __shfl(eam.y, sl1, 64),
            ea1z = __shfl(eam.z, sl1, 64), ea1w = __shfl(eam.w, sl1, 64);
      float ea2x = __shfl(eam.x, sl2, 64), ea2y = __shfl(eam.y, sl2, 64),
            ea2z = __shfl(eam.z, sl2, 64), ea2w = __shfl(eam.w, sl2, 64);
      float ea3x = __shfl(eam.x, sl3, 64), ea3y = __shfl(eam.y, sl3, 64),
            ea3z = __shfl(eam.z, sl3, 64), ea3w = __shfl(eam.w, sl3, 64);

      RowData d0 = load_row(A + (long)src0 * 128, m);
      RowData d1 = load_row(A + (long)src1 * 128, m);
      RowData d2 = load_row(A + (long)src2 * 128, m);
      RowData d3 = load_row(A + (long)src3 * 128, m);

      float4_t acL[2], acH[2];
      #pragma unroll
      for (int uo = 0; uo < 2; ++uo) {
        int tl = ch * 2 + uo;
        short8_t bl0 = w2frag[(tl * 2 + 0) * 64 + l];
        short8_t bl1 = w2frag[(tl * 2 + 1) * 64 + l];
        float4_t zl = (float4_t){0.f, 0.f, 0.f, 0.f};
        zl = __builtin_amdgcn_mfma_f32_16x16x32_bf16(a0, bl0, zl, 0, 0, 0);
        zl = __builtin_amdgcn_mfma_f32_16x16x32_bf16(a1, bl1, zl, 0, 0, 0);
        acL[uo] = zl;
        int th = 4 + ch * 2 + uo;
        short8_t bh0 = w2frag[(th * 2 + 0) * 64 + l];
        short8_t bh1 = w2frag[(th * 2 + 1) * 64 + l];
        float4_t zh = (float4_t){0.f, 0.f, 0.f, 0.f};
        zh = __builtin_amdgcn_mfma_f32_16x16x32_bf16(a0, bh0, zh, 0, 0, 0);
        zh = __builtin_amdgcn_mfma_f32_16x16x32_bf16(a1, bh1, zh, 0, 0, 0);
        acH[uo] = zh;
      }

#define EPI(R, D, EAX, EAY, EAZ, EAW) do {                                       \
        float* mrow = mid + (et * 16 + q * 4 + (R)) * MROW;                      \
        { float wAa = acL[0][R], wBb = acH[0][R];                                \
          if (ch == 0) {                                                         \
            mrow[m] = wAa * D.se0 * EAX;                                         \
            float b = wBb * EAX;                                                 \
            mrow[160 + 3 * m + 0] = b * D.vx0;                                   \
            mrow[160 + 3 * m + 1] = b * D.vy0;                                   \
            mrow[160 + 3 * m + 2] = b * D.vz0;                                   \
          } else {                                                               \
            float dv = D.vx0 * EAY + D.vy0 * EAZ + D.vz0 * EAW;                  \
            mrow[32 + m] = wBb * dv * INV_SQRT3_C;                               \
            float b = wAa * D.se0;                                               \
            mrow[64 + 3 * m + 0] = b * EAY;                                      \
            mrow[64 + 3 * m + 1] = b * EAZ;                                      \
            mrow[64 + 3 * m + 2] = b * EAW;                                      \
          } }                                                                    \
        { float wAa = acL[1][R], wBb = acH[1][R];                                \
          int uu = 16 + m;                                                       \
          if (ch == 0) {                                                         \
            mrow[uu] = wAa * D.se1 * EAX;                                        \
            float b = wBb * EAX;                                                 \
            mrow[160 + 3 * uu + 0] = b * D.vx1;                                  \
            mrow[160 + 3 * uu + 1] = b * D.vy1;                                  \
            mrow[160 + 3 * uu + 2] = b * D.vz1;                                  \
          } else {                                                               \
            float dv = D.vx1 * EAY + D.vy1 * EAZ + D.vz1 * EAW;                  \
            mrow[32 + uu] = wBb * dv * INV_SQRT3_C;                              \
            float b = wAa * D.se1;                                               \
            mrow[64 + 3 * uu + 0] = b * EAY;                                     \
            mrow[64 + 3 * uu + 1] = b * EAZ;                                     \
            mrow[64 + 3 * uu + 2] = b * EAW;                                     \
          } }                                                                    \
      } while (0)

      EPI(0, d0, ea0x, ea0y, ea0z, ea0w);
      EPI(1, d1, ea1x, ea1y, ea1z, ea1w);
      EPI(2, d2, ea2x, ea2y, ea2z, ea2w);
      EPI(3, d3, ea3x, ea3y, ea3z, ea3w);
#undef EPI
    }
    __syncthreads();

    {
      int lo = (offA0 > k0) ? offA0 : k0;
      int hiA = offA1 < (k0 + CHUNK) ? offA1 : (k0 + CHUNK);
      for (int e = lo; e < hiA; ++e) {
        float4_t v = *(const float4_t*)(mid + (e - k0) * MROW + 4 * l);
        racA.x += v.x; racA.y += v.y; racA.z += v.z; racA.w += v.w;
      }
      int lo2 = (offA1 > k0) ? offA1 : k0;
      int hiB = offB1 < (k0 + CHUNK) ? offB1 : (k0 + CHUNK);
      for (int e = lo2; e < hiB; ++e) {
        float4_t v = *(const float4_t*)(mid + (e - k0) * MROW + 4 * l);
        racB.x += v.x; racB.y += v.y; racB.z += v.z; racB.w += v.w;
      }
    }
    __syncthreads();
  }

  *(float4_t*)(ACC + (long)(n0 + nA) * 256 + 4 * l)     = racA;
  *(float4_t*)(ACC + (long)(n0 + nA + 1) * 256 + 4 * l) = racB;
}

// ---------------- tier3: R4 k_edge kept verbatim -----------------------------
__global__ __launch_bounds__(256, 4) void k_edge_fb(
    const float* __restrict__ A,
    const int* __restrict__ edge_src,
    const int* __restrict__ edge_dst,
    const float* __restrict__ edge_attr,
    const float* __restrict__ edge_scalars,
    const float* __restrict__ fc_w1,
    const float* __restrict__ fc_w2,
    const int* __restrict__ offsets,
    const int* __restrict__ slots,
    float* __restrict__ ACC) {
  const float INV_SQRT8 = 0.35355339059327373f;
  const float H_SCALE   = 1.6791767923989418f / 8.0f;

  __shared__ float    lacc[NPB * LROW];
  __shared__ short8_t w2frag[16 * 64];
  __shared__ float4   w1f[144];

  int tid = threadIdx.x;
  int n0 = blockIdx.x * NPB;
  int ebase = offsets[n0];
  int eend  = offsets[n0 + NPB];

  for (int i = tid; i < NPB * LROW; i += 256) lacc[i] = 0.f;
  if (tid < 128) {
    int j = tid >> 1, hf = tid & 1;
    float4 wv4;
    wv4.x = fc_w1[(hf * 4 + 0) * 64 + j] * INV_SQRT8;
    wv4.y = fc_w1[(hf * 4 + 1) * 64 + j] * INV_SQRT8;
    wv4.z = fc_w1[(hf * 4 + 2) * 64 + j] * INV_SQRT8;
    wv4.w = fc_w1[(hf * 4 + 3) * 64 + j] * INV_SQRT8;
    w1f[(j >> 3) * 18 + (j & 7) * 2 + hf] = wv4;
  }
  for (int fi = tid; fi < 16 * 64; fi += 256) {
    int f = fi >> 6, ll = fi & 63;
    int ct = f >> 1, kh = f & 1, mm = ll & 15, qq = ll >> 4;
    short8_t v;
    #pragma unroll
    for (int j = 0; j < 8; ++j)
      v[j] = (short)bf16r(fc_w2[(kh * 32 + qq * 8 + j) * 128 + ct * 16 + mm]);
    w2frag[fi] = v;
  }
  __syncthreads();

  int wv = tid >> 6;
  int l  = tid & 63;
  int m  = l & 15;
  int q  = l >> 4;

  for (int k0 = ebase; k0 < eend; k0 += 64) {
    int ce = k0 + 4 * m + wv;
    bool vld = ce < eend;
    int e = slots[vld ? ce : (eend - 1)];
    int srcm = edge_src[e];
    int lnm  = edge_dst[e] - n0;
    float4 eam = ld4(edge_attr + (long)e * 4);
    float4 sA = ld4(edge_scalars + (long)e * 8);
    float4 sB = ld4(edge_scalars + (long)e * 8 + 4);
    float es0 = sA.x, es1 = sA.y, es2 = sA.z, es3 = sA.w;
    float es4 = sB.x, es5 = sB.y, es6 = sB.z, es7 = sB.w;

    short8_t a0, a1;
    #pragma unroll
    for (int jj = 0; jj < 8; ++jj) {
      float4 wA = w1f[q * 18 + jj * 2 + 0];
      float4 wB = w1f[q * 18 + jj * 2 + 1];
      float x = es0 * wA.x + es1 * wA.y + es2 * wA.z + es3 * wA.w
              + es4 * wB.x + es5 * wB.y + es6 * wB.z + es7 * wB.w;
      float hv = vld ? (x * H_SCALE) / (1.f + __expf(-x)) : 0.f;
      a0[jj] = (short)bf16r(hv);
      float4 wC = w1f[(4 + q) * 18 + jj * 2 + 0];
      float4 wD = w1f[(4 + q) * 18 + jj * 2 + 1];
      float x2 = es0 * wC.x + es1 * wC.y + es2 * wC.z + es3 * wC.w
               + es4 * wD.x + es5 * wD.y + es6 * wD.z + es7 * wD.w;
      float hv2 = vld ? (x2 * H_SCALE) / (1.f + __expf(-x2)) : 0.f;
      a1[jj] = (short)bf16r(hv2);
    }

    int sl0 = q * 4, sl1 = sl0 + 1, sl2 = sl0 + 2, sl3 = sl0 + 3;
    int src0 = __shfl(srcm, sl0, 64), src1 = __shfl(srcm, sl1, 64);
    int src2 = __shfl(srcm, sl2, 64), src3 = __shfl(srcm, sl3, 64);
    int ln0 = __shfl(lnm, sl0, 64), ln1 = __shfl(lnm, sl1, 64);
    int ln2 = __shfl(lnm, sl2, 64), ln3 = __shfl(lnm, sl3, 64);
    float ea0x = __shfl(eam.x, sl0, 64), ea0y = __shfl(eam.y, sl0, 64),
          ea0z = __shfl(eam.z, sl0, 64), ea0w = __shfl(eam.w, sl0, 64);
    float ea1x = __shfl(eam.x, sl1, 64), ea1y = __shfl(eam.y, sl1, 64),
          ea1z = __shfl(eam.z, sl1, 64), ea1w = __shfl(eam.w, sl1, 64);
    float ea2x = __shfl(eam.x, sl2, 64), ea2y = __shfl(eam.y, sl2, 64),
          ea2z = __shfl(eam.z, sl2, 64), ea2w = __shfl(eam.w, sl2, 64);
    float ea3x = __shfl(eam.x, sl3, 64), ea3y = __shfl(eam.y, sl3, 64),
          ea3z = __shfl(eam.z, sl3, 64), ea3w = __shfl(eam.w, sl3, 64);

    const float* abA = A + (long)src0 * 128;
    const float* abB = A + (long)src1 * 128;
    RowData dA = load_row(abA, m);
    RowData dB = load_row(abB, m);

    float4_t acc[8];
    #pragma unroll
    for (int t = 0; t < 8; ++t) {
      short8_t b0 = w2frag[(t * 2 + 0) * 64 + l];
      short8_t b1 = w2frag[(t * 2 + 1) * 64 + l];
      float4_t z = (float4_t){0.f, 0.f, 0.f, 0.f};
      z = __builtin_amdgcn_mfma_f32_16x16x32_bf16(a0, b0, z, 0, 0, 0);
      z = __builtin_amdgcn_mfma_f32_16x16x32_bf16(a1, b1, z, 0, 0, 0);
      acc[t] = z;
    }

    const float* abC = A + (long)src2 * 128;
    const float* abD = A + (long)src3 * 128;
    RowData dC = load_row(abC, m);
    RowData dD = load_row(abD, m);

    #define ACCUM_ROW(RR, LN, EAX, EAY, EAZ, EAW, D) do {                        \
        float* lrow = lacc + (LN) * LROW;                                        \
        accum_half(lrow, m,      acc[0][RR], acc[2][RR], acc[4][RR], acc[6][RR], \
                   D.se0, D.vx0, D.vy0, D.vz0, EAX, EAY, EAZ, EAW);              \
        accum_half(lrow, m + 16, acc[1][RR], acc[3][RR], acc[5][RR], acc[7][RR], \
                   D.se1, D.vx1, D.vy1, D.vz1, EAX, EAY, EAZ, EAW);              \
      } while (0)

    if (k0 + 64 <= eend) {
      ACCUM_ROW(0, ln0, ea0x, ea0y, ea0z, ea0w, dA);
      ACCUM_ROW(1, ln1, ea1x, ea1y, ea1z, ea1w, dB);
      ACCUM_ROW(2, ln2, ea2x, ea2y, ea2z, ea2w, dC);
      ACCUM_ROW(3, ln3, ea3x, ea3y, ea3z, ea3w, dD);
    } else {
      int cb = k0 + 16 * q + wv;
      if (cb + 0  < eend) ACCUM_ROW(0, ln0, ea0x, ea0y, ea0z, ea0w, dA);
      if (cb + 4  < eend) ACCUM_ROW(1, ln1, ea1x, ea1y, ea1z, ea1w, dB);
      if (cb + 8  < eend) ACCUM_ROW(2, ln2, ea2x, ea2y, ea2z, ea2w, dC);
      if (cb + 12 < eend) ACCUM_ROW(3, ln3, ea3x, ea3y, ea3z, ea3w, dD);
    }
    #undef ACCUM_ROW
  }
  __syncthreads();

  for (int i = tid; i < NPB * 256; i += 256) {
    int node = i >> 8;
    int c = i & 255;
    ACC[(long)(n0 + node) * 256 + c] = lacc[node * LROW + c];
  }
}

// ---------------- Stage 2 (old; tiers 2/3) ----------------
__global__ void k3_stage2(const float* __restrict__ ACC,
                          const float* __restrict__ w2s,
                          const float* __restrict__ w2v,
                          float* __restrict__ out) {
  const float scale = 0.03125f; // (1/sqrt(16)) / sqrt(64)
  int stride = gridDim.x * blockDim.x;
  for (int idx = blockIdx.x * blockDim.x + threadIdx.x; idx < NNODES * 128; idx += stride) {
    int n = idx >> 7;
    int c = idx & 127;
    const float* row = ACC + (long)n * 256;
    float acc = 0.f;
    if (c < 32) {
      #pragma unroll
      for (int qq = 0; qq < 64; ++qq)
        acc = fmaf(row[qq], w2s[qq * 32 + c], acc);
    } else {
      int cc = c - 32;
      int w = cc / 3;
      int i = cc - w * 3;
      #pragma unroll
      for (int qq = 0; qq < 64; ++qq)
        acc = fmaf(row[64 + qq * 3 + i], w2v[qq * 32 + w], acc);
    }
    out[idx] = acc * scale;
  }
}

// ---------------- Stage 2b — R8: divergence-free, LDS-staged -----------------
// Same defect/fix as k1: old version serialized both exec-masked branches and
// used scalar loads. Thread (g,j) computes node g's outputs {s[j], v[j][0..2]}
// from the LDS-staged ACC row; weights prescaled in LDS. Output layout
// unchanged (col j for s, cols 32+3j+{0,1,2} for v; contiguous across j).
__global__ __launch_bounds__(256) void k3_stage2b(
    const float* __restrict__ ACC,
    const float* __restrict__ w2s,
    const float* __restrict__ w2v,
    float* __restrict__ out) {
  __shared__ float rows[NB3 * 256];   // 8 KB
  __shared__ float ws[64 * 32];       // 8 KB (prescaled)
  __shared__ float wvv[64 * 32];      // 8 KB (prescaled)
  const float scale = 0.03125f; // (1/sqrt(16)) / sqrt(64)
  int tid = threadIdx.x;
  int n0 = blockIdx.x * NB3;

  #pragma unroll
  for (int k = 0; k < 2; ++k) {
    int i = tid + k * 256;
    float4 a = ((const float4*)w2s)[i];
    a.x *= scale; a.y *= scale; a.z *= scale; a.w *= scale;
    ((float4*)ws)[i] = a;
    float4 b = ((const float4*)w2v)[i];
    b.x *= scale; b.y *= scale; b.z *= scale; b.w *= scale;
    ((float4*)wvv)[i] = b;
    ((float4*)rows)[i] = ((const float4*)(ACC + (long)n0 * 256))[i];
  }
  __syncthreads();

  int j = tid & 31, g = tid >> 5;
  const float* lr = rows + g * 256;
  float ac0 = 0.f, ac1 = 0.f, ac2 = 0.f, ac3 = 0.f;
  #pragma unroll
  for (int t = 0; t < 64; ++t) {
    float wsj = ws[t * 32 + j];
    float wvj = wvv[t * 32 + j];
    ac0 = fmaf(lr[t],            wsj, ac0);
    ac1 = fmaf(lr[64 + 3 * t],     wvj, ac1);
    ac2 = fmaf(lr[64 + 3 * t + 1], wvj, ac2);
    ac3 = fmaf(lr[64 + 3 * t + 2], wvj, ac3);
  }
  float* po = out + (long)(n0 + g) * 128;
  po[j] = ac0;
  po[32 + 3 * j + 0] = ac1;
  po[32 + 3 * j + 1] = ac2;
  po[32 + 3 * j + 2] = ac3;
}

extern "C" void kernel_launch(void* const* d_in, const int* in_sizes, int n_in,
                              void* d_out, int out_size, void* d_ws, size_t ws_size,
                              hipStream_t stream) {
  const float* node_input   = (const float*)d_in[0];
  const int*   edge_src     = (const int*)d_in[2];
  const int*   edge_dst     = (const int*)d_in[3];
  const float* edge_attr    = (const float*)d_in[4];
  const float* edge_scalars = (const float*)d_in[5];
  const float* fc_w1        = (const float*)d_in[8];
  const float* fc_w2        = (const float*)d_in[9];
  const float* w_lin1_s     = (const float*)d_in[6];
  const float* w_lin1_v     = (const float*)d_in[7];
  const float* w_lin2_s     = (const float*)d_in[10];
  const float* w_lin2_v     = (const float*)d_in[11];

  float* out = (float*)d_out;
  float* Abuf = out;  // stage-1 output lives in d_out; stage-2 overwrites it later

  const size_t SZ_ACC = (size_t)NNODES * 256 * sizeof(float);   // 40.96 MB
  const size_t SZ_PE  = (size_t)NEDGES * 64;                    // 40.96 MB (tier1)
  const size_t SZ_PES = (size_t)NEDGES * 32;                    // 20.48 MB (tier2)
  const size_t SZ_PEA = (size_t)NEDGES * 16;                    // 10.24 MB (tier2)
  const size_t SZ_PSR = (size_t)NEDGES * 4;                     //  2.56 MB (tier2)
  const size_t SZ_CNT = (size_t)NNODES * sizeof(int);
  const size_t SZ_OFF = (size_t)(NNODES + 4) * sizeof(int);
  const size_t SZ_SLT = (size_t)NEDGES * sizeof(int);
  const size_t need1 = SZ_ACC + SZ_PE + 3 * SZ_CNT + SZ_OFF + 2048;
  const size_t need2 = SZ_ACC + SZ_PES + SZ_PEA + SZ_PSR + 3 * SZ_CNT + SZ_OFF + 2048;

  if (ws_size >= need1) {
    // ---- tier1: R8 (AoS A2 + vectorized stage kernels + proven edge kernel)
    char* p = (char*)d_ws;
    float*    ACC = (float*)p;    p += SZ_ACC;
    float4_t* PE  = (float4_t*)p; p += SZ_PE;
    int* counts   = (int*)p;      p += SZ_CNT;
    int* offsets  = (int*)p;      p += SZ_OFF;
    int* cursor   = (int*)p;      p += SZ_CNT;
    int* bsum     = (int*)p;      p += 160 * sizeof(int);
    int* boff     = (int*)p;      p += 160 * sizeof(int);

    hipMemsetAsync(counts, 0, SZ_CNT, stream);
    k1_stage1b<<<NNODES / NB1, 256, 0, stream>>>(node_input, w_lin1_s, w_lin1_v, Abuf);
    k_hist<<<NEDGES / 256, 256, 0, stream>>>(edge_dst, counts);
    k_scanA<<<157, 256, 0, stream>>>(counts, bsum);
    k_scanB<<<1, 256, 0, stream>>>(bsum, boff, offsets);
    k_scanC<<<157, 256, 0, stream>>>(counts, boff, offsets, cursor);
    k_scatter_pack3<<<NEDGES / 256, 256, 0, stream>>>(edge_src, edge_dst, edge_attr,
                                                      edge_scalars, cursor, PE);
    k_edge4b<<<NNODES / NPB, 256, 0, stream>>>(Abuf, PE, fc_w1, fc_w2, offsets, ACC);
    k3_stage2b<<<NNODES / NB3, 256, 0, stream>>>(ACC, w_lin2_s, w_lin2_v, out);
  } else if (ws_size >= need2) {
    // ---- tier2: proven R6 path
    char* p = (char*)d_ws;
    float*    ACC = (float*)p;    p += SZ_ACC;
    float4_t* PES = (float4_t*)p; p += SZ_PES;
    float4_t* PEA = (float4_t*)p; p += SZ_PEA;
    int*      PSRC = (int*)p;     p += SZ_PSR;
    int* counts   = (int*)p;      p += SZ_CNT;
    int* offsets  = (int*)p;      p += SZ_OFF;
    int* cursor   = (int*)p;      p += SZ_CNT;
    int* bsum     = (int*)p;      p += 160 * sizeof(int);
    int* boff     = (int*)p;      p += 160 * sizeof(int);

    hipMemsetAsync(counts, 0, SZ_CNT, stream);
    k1_stage1<<<2048, 256, 0, stream>>>(node_input, w_lin1_s, w_lin1_v, Abuf);
    k_hist<<<NEDGES / 256, 256, 0, stream>>>(edge_dst, counts);
    k_scanA<<<157, 256, 0, stream>>>(counts, bsum);
    k_scanB<<<1, 256, 0, stream>>>(bsum, boff, offsets);
    k_scanC<<<157, 256, 0, stream>>>(counts, boff, offsets, cursor);
    k_scatter_pack2<<<NEDGES / 256, 256, 0, stream>>>(edge_src, edge_dst, edge_attr,
                                                      edge_scalars, cursor, PSRC, PEA, PES);
    k_edge3<<<NNODES / NPB, 256, 0, stream>>>(Abuf, PSRC, PEA, PES, fc_w1, fc_w2,
                                              offsets, ACC);
    k3_stage2<<<2048, 256, 0, stream>>>(ACC, w_lin2_s, w_lin2_v, out);
  } else {
    // ---- tier3: proven R4 fallback
    char* p = (char*)d_ws;
    float* ACC    = (float*)p;  p += SZ_ACC;
    int* counts   = (int*)p;    p += SZ_CNT;
    int* offsets  = (int*)p;    p += SZ_OFF;
    int* cursor   = (int*)p;    p += SZ_CNT;
    int* slots    = (int*)p;    p += SZ_SLT;
    int* bsum     = (int*)p;    p += 160 * sizeof(int);
    int* boff     = (int*)p;    p += 160 * sizeof(int);

    hipMemsetAsync(counts, 0, SZ_CNT, stream);
    k1_stage1<<<2048, 256, 0, stream>>>(node_input, w_lin1_s, w_lin1_v, Abuf);
    k_hist<<<NEDGES / 256, 256, 0, stream>>>(edge_dst, counts);
    k_scanA<<<157, 256, 0, stream>>>(counts, bsum);
    k_scanB<<<1, 256, 0, stream>>>(bsum, boff, offsets);
    k_scanC<<<157, 256, 0, stream>>>(counts, boff, offsets, cursor);
    k_scatter<<<NEDGES / 256, 256, 0, stream>>>(edge_dst, cursor, slots);
    k_edge_fb<<<NNODES / NPB, 256, 0, stream>>>(Abuf, edge_src, edge_dst, edge_attr,
                                                edge_scalars, fc_w1, fc_w2,
                                                offsets, slots, ACC);
    k3_stage2<<<2048, 256, 0, stream>>>(ACC, w_lin2_s, w_lin2_v, out);
  }
}

// Round 6
// 322.709 us; speedup vs baseline: 3.8921x; 1.0446x over previous
//
#include <hip/hip_runtime.h>
#include <math.h>

#define NNODES 40000
#define NEDGES 640000
#define NPB 8             // nodes per edge-block
#define LROW 257          // fallback kernels: padded LDS accumulator row stride
#define CHUNK 32          // edges per chunk in k_edge3 (tier2)
#define CHUNK4 16         // edges per chunk in k_edge5 (tier1)
#define MROW 260          // mid row stride (floats): 16B-aligned, 4-bank row shift
#define NB1 8             // nodes per block, k1_stage1b
#define NB3 8             // nodes per block, k3_stage2b

typedef __attribute__((ext_vector_type(8))) short short8_t;
typedef __attribute__((ext_vector_type(4))) short short4_t;
typedef __attribute__((ext_vector_type(4))) float float4_t;

__device__ __forceinline__ float4 ld4(const float* p) { return *(const float4*)p; }

__device__ __forceinline__ unsigned short bf16r(float x) {
  union { float f; unsigned u; } v; v.f = x;
  unsigned u = v.u;
  u += 0x7FFFu + ((u >> 16) & 1u);   // RNE
  return (unsigned short)(u >> 16);
}

__device__ __forceinline__ void lds_fadd(float* p, float v) {
  __hip_atomic_fetch_add(p, v, __ATOMIC_RELAXED, __HIP_MEMORY_SCOPE_WORKGROUP);
}

#define INV_SQRT3_C 0.57735026918962576f

// tier3-kernel helper (R4, proven)
__device__ __forceinline__ void accum_half(float* lrow, int u,
    float w0, float w1, float w2, float w3,
    float se, float vx, float vy, float vz,
    float esc, float ev0, float ev1, float ev2) {
  lds_fadd(lrow + u, w0 * se * esc);
  float dv = vx * ev0 + vy * ev1 + vz * ev2;
  lds_fadd(lrow + 32 + u, w3 * dv * INV_SQRT3_C);
  float b1v = w1 * se;
  lds_fadd(lrow + 64 + u * 3 + 0, b1v * ev0);
  lds_fadd(lrow + 64 + u * 3 + 1, b1v * ev1);
  lds_fadd(lrow + 64 + u * 3 + 2, b1v * ev2);
  float b2v = w2 * esc;
  lds_fadd(lrow + 160 + u * 3 + 0, b2v * vx);
  lds_fadd(lrow + 160 + u * 3 + 1, b2v * vy);
  lds_fadd(lrow + 160 + u * 3 + 2, b2v * vz);
}

struct RowData { float se0, se1, vx0, vy0, vz0, vx1, vy1, vz1; };

__device__ __forceinline__ RowData load_row(const float* ab, int m) {
  RowData d;
  d.se0 = ab[m];            d.se1 = ab[m + 16];
  d.vx0 = ab[32 + 3 * m];   d.vy0 = ab[33 + 3 * m];   d.vz0 = ab[34 + 3 * m];
  d.vx1 = ab[80 + 3 * m];   d.vy1 = ab[81 + 3 * m];   d.vz1 = ab[82 + 3 * m];
  return d;
}

// ---------------- Stage 1 (old SoA layout; tiers 2/3) ----------------
__global__ void k1_stage1(const float* __restrict__ node_input,
                          const float* __restrict__ w1s,
                          const float* __restrict__ w1v,
                          float* __restrict__ A) {
  const float scale = 0.17677669529663687f; // 1/sqrt(32)
  int stride = gridDim.x * blockDim.x;
  for (int idx = blockIdx.x * blockDim.x + threadIdx.x; idx < NNODES * 128; idx += stride) {
    int n = idx >> 7;
    int c = idx & 127;
    const float* row = node_input + n * 128;
    float acc = 0.f;
    if (c < 32) {
      #pragma unroll
      for (int u = 0; u < 32; ++u)
        acc = fmaf(row[u], w1s[u * 32 + c], acc);
    } else {
      int cc = c - 32;
      int w = cc / 3;
      int i = cc - w * 3;
      #pragma unroll
      for (int u = 0; u < 32; ++u)
        acc = fmaf(row[32 + u * 3 + i], w1v[u * 32 + w], acc);
    }
    A[idx] = acc * scale;
  }
}

// ---------------- Stage 1b (R8, proven): divergence-free, AoS output ---------
__global__ __launch_bounds__(256) void k1_stage1b(
    const float* __restrict__ node_input,
    const float* __restrict__ w1s,
    const float* __restrict__ w1v,
    float* __restrict__ A2) {
  __shared__ float rows[NB1 * 128];   // 4 KB
  __shared__ float ws[32 * 32];       // 4 KB (prescaled)
  __shared__ float wvv[32 * 32];      // 4 KB (prescaled)
  const float scale = 0.17677669529663687f; // 1/sqrt(32)
  int tid = threadIdx.x;
  int n0 = blockIdx.x * NB1;

  float4 a = ((const float4*)w1s)[tid];          // 256 float4 = full 32x32
  a.x *= scale; a.y *= scale; a.z *= scale; a.w *= scale;
  ((float4*)ws)[tid] = a;
  float4 b = ((const float4*)w1v)[tid];
  b.x *= scale; b.y *= scale; b.z *= scale; b.w *= scale;
  ((float4*)wvv)[tid] = b;
  ((float4*)rows)[tid] = ((const float4*)(node_input + (long)n0 * 128))[tid];
  __syncthreads();

  int j = tid & 31, g = tid >> 5;
  const float* lr = rows + g * 128;
  float ac0 = 0.f, ac1 = 0.f, ac2 = 0.f, ac3 = 0.f;
  #pragma unroll
  for (int t = 0; t < 32; ++t) {
    float wsj = ws[t * 32 + j];
    float wvj = wvv[t * 32 + j];
    ac0 = fmaf(lr[t],            wsj, ac0);
    ac1 = fmaf(lr[32 + 3 * t],     wvj, ac1);
    ac2 = fmaf(lr[32 + 3 * t + 1], wvj, ac2);
    ac3 = fmaf(lr[32 + 3 * t + 2], wvj, ac3);
  }
  float4 o; o.x = ac0; o.y = ac1; o.z = ac2; o.w = ac3;
  ((float4*)(A2 + (long)n0 * 128))[tid] = o;   // tid = g*32+j -> n0+g, u=j
}

// ---------------- CSR build ----------------
__global__ void k_hist(const int* __restrict__ edge_dst, int* __restrict__ counts) {
  int e = blockIdx.x * blockDim.x + threadIdx.x;
  if (e < NEDGES) atomicAdd(&counts[edge_dst[e]], 1);
}

__global__ void k_scanA(const int* __restrict__ counts, int* __restrict__ bsum) {
  __shared__ int ws[4];
  int t = blockIdx.x * 256 + threadIdx.x;
  int v = (t < NNODES) ? counts[t] : 0;
  for (int d = 32; d; d >>= 1) v += __shfl_down(v, d, 64);
  if ((threadIdx.x & 63) == 0) ws[threadIdx.x >> 6] = v;
  __syncthreads();
  if (threadIdx.x == 0) bsum[blockIdx.x] = ws[0] + ws[1] + ws[2] + ws[3];
}

__global__ __launch_bounds__(256) void k_scanB(const int* __restrict__ bsum,
                                               int* __restrict__ boff,
                                               int* __restrict__ offsets) {
  __shared__ int s[256];
  int tid = threadIdx.x;
  int v = (tid < 157) ? bsum[tid] : 0;
  s[tid] = v;
  __syncthreads();
  for (int d = 1; d < 256; d <<= 1) {
    int x = (tid >= d) ? s[tid - d] : 0;
    __syncthreads();
    s[tid] += x;
    __syncthreads();
  }
  if (tid < 157) boff[tid] = s[tid] - v;
  if (tid == 0) offsets[NNODES] = NEDGES;
}

__global__ __launch_bounds__(256) void k_scanC(const int* __restrict__ counts,
                                               const int* __restrict__ boff,
                                               int* __restrict__ offsets,
                                               int* __restrict__ cursor) {
  __shared__ int s[256];
  int tid = threadIdx.x;
  int t = blockIdx.x * 256 + tid;
  int v = (t < NNODES) ? counts[t] : 0;
  s[tid] = v;
  __syncthreads();
  for (int d = 1; d < 256; d <<= 1) {
    int x = (tid >= d) ? s[tid - d] : 0;
    __syncthreads();
    s[tid] += x;
    __syncthreads();
  }
  int off = boff[blockIdx.x] + s[tid] - v;
  if (t < NNODES) { offsets[t] = off; cursor[t] = off; }
}

// R9: scanB+scanC merged — each block redundantly prefix-sums the 157 block
// sums (157 adds in LDS) instead of waiting for a separate scanB launch.
__global__ __launch_bounds__(256) void k_scanBC(
    const int* __restrict__ counts,
    const int* __restrict__ bsum,
    int* __restrict__ offsets,
    int* __restrict__ cursor) {
  __shared__ int sb[256];
  __shared__ int s[256];
  int tid = threadIdx.x;
  int vb = (tid < 157) ? bsum[tid] : 0;
  sb[tid] = vb;
  __syncthreads();
  for (int d = 1; d < 256; d <<= 1) {
    int x = (tid >= d) ? sb[tid - d] : 0;
    __syncthreads();
    sb[tid] += x;
    __syncthreads();
  }
  int myboff = (blockIdx.x == 0) ? 0 : sb[blockIdx.x - 1];
  int t = blockIdx.x * 256 + tid;
  int v = (t < NNODES) ? counts[t] : 0;
  s[tid] = v;
  __syncthreads();
  for (int d = 1; d < 256; d <<= 1) {
    int x = (tid >= d) ? s[tid - d] : 0;
    __syncthreads();
    s[tid] += x;
    __syncthreads();
  }
  int off = myboff + s[tid] - v;
  if (t < NNODES) { offsets[t] = off; cursor[t] = off; }
  if (blockIdx.x == 0 && tid == 0) offsets[NNODES] = NEDGES;
}

// tier3 scatter (slots only)
__global__ void k_scatter(const int* __restrict__ edge_dst,
                          int* __restrict__ cursor, int* __restrict__ slots) {
  int e = blockIdx.x * blockDim.x + threadIdx.x;
  if (e < NEDGES) {
    int d = edge_dst[e];
    int p = atomicAdd(&cursor[d], 1);
    slots[p] = e;
  }
}

// tier2 scatter (R6, proven)
__global__ void k_scatter_pack2(const int* __restrict__ edge_src,
                                const int* __restrict__ edge_dst,
                                const float* __restrict__ edge_attr,
                                const float* __restrict__ edge_scalars,
                                int* __restrict__ cursor,
                                int* __restrict__ PSRC,
                                float4_t* __restrict__ PEA,
                                float4_t* __restrict__ PES) {
  int e = blockIdx.x * blockDim.x + threadIdx.x;
  if (e < NEDGES) {
    int d = edge_dst[e];
    int p = atomicAdd(&cursor[d], 1);
    PSRC[p] = edge_src[e];
    PEA[p] = *(const float4_t*)(edge_attr + (long)e * 4);
    PES[2 * p]     = *(const float4_t*)(edge_scalars + (long)e * 8);
    PES[2 * p + 1] = *(const float4_t*)(edge_scalars + (long)e * 8 + 4);
  }
}

// tier1 scatter (R7, proven): one aligned 64B record per edge
__global__ void k_scatter_pack3(const int* __restrict__ edge_src,
                                const int* __restrict__ edge_dst,
                                const float* __restrict__ edge_attr,
                                const float* __restrict__ edge_scalars,
                                int* __restrict__ cursor,
                                float4_t* __restrict__ PE) {
  int e = blockIdx.x * blockDim.x + threadIdx.x;
  if (e < NEDGES) {
    int d = edge_dst[e];
    int p = atomicAdd(&cursor[d], 1);
    float4_t* b = PE + (long)p * 4;
    b[0] = *(const float4_t*)(edge_attr + (long)e * 4);
    b[1] = *(const float4_t*)(edge_scalars + (long)e * 8);
    b[2] = *(const float4_t*)(edge_scalars + (long)e * 8 + 4);
    float4_t s;
    s.x = __int_as_float(edge_src[e]); s.y = 0.f; s.z = 0.f; s.w = 0.f;
    b[3] = s;
  }
}

// ---------------- Fused edge kernel — R9: stage-2 fused, shfl-free meta ------
// R8 post-mortem: AoS gather neutral (VMEM count was not the bound); k1/k3
// rewrite -130us. Remaining structural waste: the ACC round-trip (k_edge
// writes 41MB, k3 reads 41MB + writes 20MB) exists only because stage-2 lives
// outside. Each block's rac registers already hold the full segment-sum for
// its 8 nodes at loop end -> fuse the 256->128 stage-2 matmul here:
//   (1) stage w_lin2_s/w_lin2_v prescaled into 16KB LDS (total 37.6KB; still
//       4 blocks/CU under launch_bounds(256,4): 4x37.6 = 150KB < 160KB).
//   (2) epilogue: rac -> mid rows (reused as node rows) -> k3_stage2b-pattern
//       compute -> write final out. ACC buffer + k3 launch deleted.
//   A2 moves to ws (d_out is now written by this kernel -> aliasing A2 in
//   d_out would corrupt gathers of not-yet-processed blocks).
// Also: EPI metadata via DIRECT uniform PE loads (lane (q,m) loads edges
// q*4+r itself, same clamp as the shfl source lane computed) -> removes 20
// ds_bpermute/lane/chunk from the LDS pipe (shared with h_lds/mid/reader).
__global__ __launch_bounds__(256, 4) void k_edge5(
    const float* __restrict__ A2,
    const float4_t* __restrict__ PE,
    const float* __restrict__ fc_w1,
    const float* __restrict__ fc_w2,
    const float* __restrict__ w2s,
    const float* __restrict__ w2v,
    const int* __restrict__ offsets,
    float* __restrict__ out) {
  const float INV_SQRT8 = 0.35355339059327373f;
  const float H_SCALE   = 1.6791767923989418f / 8.0f; // SILU_NORM / sqrt(64)
  const float S2SCALE   = 0.03125f;                   // (1/sqrt(16))/sqrt(64)

  __shared__ float  mid[CHUNK4 * MROW];   // 16,640 B; reused as node rows at end
  __shared__ short  h_lds[CHUNK4 * 72];   //  2,304 B (144B row stride)
  __shared__ float4 w1f[144];             //  2,304 B
  __shared__ float  ws2[64 * 32];         //  8,192 B (prescaled w_lin2_s)
  __shared__ float  wv2[64 * 32];         //  8,192 B (prescaled w_lin2_v)

  int tid = threadIdx.x;
  int n0 = blockIdx.x * NPB;
  int ebase = offsets[n0];
  int eend  = offsets[n0 + NPB];

  if (tid < 128) {
    int j = tid >> 1, hf = tid & 1;
    float4 wv4;
    wv4.x = fc_w1[(hf * 4 + 0) * 64 + j] * INV_SQRT8;
    wv4.y = fc_w1[(hf * 4 + 1) * 64 + j] * INV_SQRT8;
    wv4.z = fc_w1[(hf * 4 + 2) * 64 + j] * INV_SQRT8;
    wv4.w = fc_w1[(hf * 4 + 3) * 64 + j] * INV_SQRT8;
    w1f[(j >> 3) * 18 + (j & 7) * 2 + hf] = wv4;
  }
  // stage-2 weights, prescaled (512 float4 per matrix, 2 per thread)
  #pragma unroll
  for (int k = 0; k < 2; ++k) {
    int i = tid + k * 256;
    float4 a = ((const float4*)w2s)[i];
    a.x *= S2SCALE; a.y *= S2SCALE; a.z *= S2SCALE; a.w *= S2SCALE;
    ((float4*)ws2)[i] = a;
    float4 b = ((const float4*)w2v)[i];
    b.x *= S2SCALE; b.y *= S2SCALE; b.z *= S2SCALE; b.w *= S2SCALE;
    ((float4*)wv2)[i] = b;
  }

  int wv = tid >> 6;       // wave id 0..3
  int l  = tid & 63;
  int m  = l & 15;
  int q  = l >> 4;
  int uh = wv & 1;         // u-half: u in [uh*16, uh*16+16)
  int cl = wv >> 1;        // column class
  int tL = cl * 2 + uh;    // w-tile for {w0|w1}
  int tH = 4 + cl * 2 + uh;// w-tile for {w2|w3}
  int u  = uh * 16 + m;

  // B-frags direct from global (fc_w2 is 32KB, L2-resident)
  short8_t bL0, bL1, bH0, bH1;
  #pragma unroll
  for (int j = 0; j < 8; ++j) {
    bL0[j] = (short)bf16r(fc_w2[(q * 8 + j) * 128      + tL * 16 + m]);
    bL1[j] = (short)bf16r(fc_w2[(32 + q * 8 + j) * 128 + tL * 16 + m]);
    bH0[j] = (short)bf16r(fc_w2[(q * 8 + j) * 128      + tH * 16 + m]);
    bH1[j] = (short)bf16r(fc_w2[(32 + q * 8 + j) * 128 + tH * 16 + m]);
  }

  int nA = 2 * wv;
  int offA0 = offsets[n0 + nA];
  int offA1 = offsets[n0 + nA + 1];
  int offB1 = offsets[n0 + nA + 2];
  float4_t racA = {0.f, 0.f, 0.f, 0.f};
  float4_t racB = {0.f, 0.f, 0.f, 0.f};

  float ea0x, ea0y, ea0z, ea0w, ea1x, ea1y, ea1z, ea1w,
        ea2x, ea2y, ea2z, ea2w, ea3x, ea3y, ea3z, ea3w;
  float se0, se1, se2, se3, vx0, vx1, vx2, vx3,
        vy0, vy1, vy2, vy3, vz0, vz1, vz2, vz3;

  auto loadmeta = [&](int kb) {
    // own edge: h quarter compute + publish (unchanged from R7/R8)
    int ecs = kb + m;
    int ecc = (ecs < eend) ? ecs : (eend - 1);
    const float4_t* pb = PE + (long)ecc * 4;
    float4_t sA  = pb[1];
    float4_t sB  = pb[2];
    int g  = wv * 2 + (q >> 1);
    int ob = (q & 1) * 4;
    short4_t hq;
    #pragma unroll
    for (int j = 0; j < 4; ++j) {
      float4 wA = w1f[g * 18 + (ob + j) * 2 + 0];
      float4 wB = w1f[g * 18 + (ob + j) * 2 + 1];
      float x = sA.x * wA.x + sA.y * wA.y + sA.z * wA.z + sA.w * wA.w
              + sB.x * wB.x + sB.y * wB.y + sB.z * wB.z + sB.w * wB.w;
      float hv = (x * H_SCALE) / (1.f + __expf(-x));
      hq[j] = (short)bf16r(hv);
    }
    *(short4_t*)((char*)h_lds + m * 144 + wv * 32 + q * 8) = hq;
    // EPI metadata: direct loads (uniform per 16-lane q-group; clamp matches
    // what the shfl source lane computed in R7/R8)
    int eb = kb + q * 4;
    int e0 = (eb     < eend) ? eb     : (eend - 1);
    int e1 = (eb + 1 < eend) ? eb + 1 : (eend - 1);
    int e2 = (eb + 2 < eend) ? eb + 2 : (eend - 1);
    int e3 = (eb + 3 < eend) ? eb + 3 : (eend - 1);
    const float4_t* p0 = PE + (long)e0 * 4;
    const float4_t* p1 = PE + (long)e1 * 4;
    const float4_t* p2 = PE + (long)e2 * 4;
    const float4_t* p3 = PE + (long)e3 * 4;
    float4_t a0v = p0[0]; int s0i = __float_as_int(p0[3].x);
    float4_t a1v = p1[0]; int s1i = __float_as_int(p1[3].x);
    float4_t a2v = p2[0]; int s2i = __float_as_int(p2[3].x);
    float4_t a3v = p3[0]; int s3i = __float_as_int(p3[3].x);
    ea0x = a0v.x; ea0y = a0v.y; ea0z = a0v.z; ea0w = a0v.w;
    ea1x = a1v.x; ea1y = a1v.y; ea1z = a1v.z; ea1w = a1v.w;
    ea2x = a2v.x; ea2y = a2v.y; ea2z = a2v.z; ea2w = a2v.w;
    ea3x = a3v.x; ea3y = a3v.y; ea3z = a3v.z; ea3w = a3v.w;
    // AoS A2 gathers: one aligned dwordx4 per row
    float4 g0 = *(const float4*)(A2 + (long)s0i * 128 + 4 * u);
    float4 g1 = *(const float4*)(A2 + (long)s1i * 128 + 4 * u);
    float4 g2 = *(const float4*)(A2 + (long)s2i * 128 + 4 * u);
    float4 g3 = *(const float4*)(A2 + (long)s3i * 128 + 4 * u);
    se0 = g0.x; vx0 = g0.y; vy0 = g0.z; vz0 = g0.w;
    se1 = g1.x; vx1 = g1.y; vy1 = g1.z; vz1 = g1.w;
    se2 = g2.x; vx2 = g2.y; vy2 = g2.z; vz2 = g2.w;
    se3 = g3.x; vx3 = g3.y; vy3 = g3.z; vz3 = g3.w;
  };

  __syncthreads();    // w1f/ws2/wv2 ready

  if (ebase < eend) {
    loadmeta(ebase);
    for (int k0 = ebase; k0 < eend; k0 += CHUNK4) {
      __syncthreads();  // h_lds published; prev-chunk mid reads done
      short8_t a0 = *(const short8_t*)((const char*)h_lds + m * 144 + q * 16);
      short8_t a1 = *(const short8_t*)((const char*)h_lds + m * 144 + 64 + q * 16);
      float4_t acL = {0.f, 0.f, 0.f, 0.f};
      float4_t acH = {0.f, 0.f, 0.f, 0.f};
      acL = __builtin_amdgcn_mfma_f32_16x16x32_bf16(a0, bL0, acL, 0, 0, 0);
      acL = __builtin_amdgcn_mfma_f32_16x16x32_bf16(a1, bL1, acL, 0, 0, 0);
      acH = __builtin_amdgcn_mfma_f32_16x16x32_bf16(a0, bH0, acH, 0, 0, 0);
      acH = __builtin_amdgcn_mfma_f32_16x16x32_bf16(a1, bH1, acH, 0, 0, 0);
#define EPI4(R, SE, VX, VY, VZ, EAX, EAY, EAZ, EAW) do {            \
        float* mrow = mid + (q * 4 + (R)) * MROW;                   \
        if (cl == 0) {                                              \
          mrow[u] = acL[R] * (SE) * (EAX);                          \
          float b = acH[R] * (EAX);                                 \
          mrow[160 + 3 * u + 0] = b * (VX);                         \
          mrow[160 + 3 * u + 1] = b * (VY);                         \
          mrow[160 + 3 * u + 2] = b * (VZ);                         \
        } else {                                                    \
          float dv = (VX) * (EAY) + (VY) * (EAZ) + (VZ) * (EAW);    \
          mrow[32 + u] = acH[R] * dv * INV_SQRT3_C;                 \
          float b = acL[R] * (SE);                                  \
          mrow[64 + 3 * u + 0] = b * (EAY);                         \
          mrow[64 + 3 * u + 1] = b * (EAZ);                         \
          mrow[64 + 3 * u + 2] = b * (EAW);                         \
        }                                                           \
      } while (0)
      EPI4(0, se0, vx0, vy0, vz0, ea0x, ea0y, ea0z, ea0w);
      EPI4(1, se1, vx1, vy1, vz1, ea1x, ea1y, ea1z, ea1w);
      EPI4(2, se2, vx2, vy2, vz2, ea2x, ea2y, ea2z, ea2w);
      EPI4(3, se3, vx3, vy3, vz3, ea3x, ea3y, ea3z, ea3w);
#undef EPI4
      __syncthreads();  // mid ready
      {
        int lo = (offA0 > k0) ? offA0 : k0;
        int hi = offA1 < (k0 + CHUNK4) ? offA1 : (k0 + CHUNK4);
        for (int e = lo; e < hi; ++e) {
          float4_t v = *(const float4_t*)(mid + (e - k0) * MROW + 4 * l);
          racA.x += v.x; racA.y += v.y; racA.z += v.z; racA.w += v.w;
        }
        int lo2 = (offA1 > k0) ? offA1 : k0;
        int hi2 = offB1 < (k0 + CHUNK4) ? offB1 : (k0 + CHUNK4);
        for (int e = lo2; e < hi2; ++e) {
          float4_t v = *(const float4_t*)(mid + (e - k0) * MROW + 4 * l);
          racB.x += v.x; racB.y += v.y; racB.z += v.z; racB.w += v.w;
        }
      }
      if (k0 + CHUNK4 < eend) loadmeta(k0 + CHUNK4);
    }
  }

  // ---- fused stage-2 epilogue ----
  __syncthreads();   // all waves done with mid (last chunk readers)
  // publish node sums into mid rows 0..7 (b128, conflict-free)
  *(float4_t*)(mid + (2 * wv) * MROW + 4 * l)     = racA;
  *(float4_t*)(mid + (2 * wv + 1) * MROW + 4 * l) = racB;
  __syncthreads();
  {
    // thread (g=tid>>5, j=tid&31): node n0+g, outputs {s[j], v[j][0..2]}
    // (k3_stage2b pattern; nr reads are 32-lane broadcasts, ws2/wv2 reads
    // conflict-free)
    int j = tid & 31, g = tid >> 5;
    const float* nr = mid + g * MROW;
    float ac0 = 0.f, ac1 = 0.f, ac2 = 0.f, ac3 = 0.f;
    #pragma unroll
    for (int t = 0; t < 64; ++t) {
      float wsj = ws2[t * 32 + j];
      float wvj = wv2[t * 32 + j];
      ac0 = fmaf(nr[t],              wsj, ac0);
      ac1 = fmaf(nr[64 + 3 * t],     wvj, ac1);
      ac2 = fmaf(nr[64 + 3 * t + 1], wvj, ac2);
      ac3 = fmaf(nr[64 + 3 * t + 2], wvj, ac3);
    }
    float* po = out + (long)(n0 + g) * 128;
    po[j] = ac0;
    po[32 + 3 * j + 0] = ac1;
    po[32 + 3 * j + 1] = ac2;
    po[32 + 3 * j + 2] = ac3;
  }
}

// ---------------- tier2: R6 k_edge3 kept verbatim ----------------------------
__global__ __launch_bounds__(256, 3) void k_edge3(
    const float* __restrict__ A,
    const int* __restrict__ PSRC,
    const float4_t* __restrict__ PEA,
    const float4_t* __restrict__ PES,
    const float* __restrict__ fc_w1,
    const float* __restrict__ fc_w2,
    const int* __restrict__ offsets,
    float* __restrict__ ACC) {
  const float INV_SQRT8 = 0.35355339059327373f;
  const float H_SCALE   = 1.6791767923989418f / 8.0f;

  __shared__ float    mid[CHUNK * MROW];
  __shared__ short8_t w2frag[16 * 64];
  __shared__ float4   w1f[144];

  int tid = threadIdx.x;
  int n0 = blockIdx.x * NPB;
  int ebase = offsets[n0];
  int eend  = offsets[n0 + NPB];

  if (tid < 128) {
    int j = tid >> 1, hf = tid & 1;
    float4 wv4;
    wv4.x = fc_w1[(hf * 4 + 0) * 64 + j] * INV_SQRT8;
    wv4.y = fc_w1[(hf * 4 + 1) * 64 + j] * INV_SQRT8;
    wv4.z = fc_w1[(hf * 4 + 2) * 64 + j] * INV_SQRT8;
    wv4.w = fc_w1[(hf * 4 + 3) * 64 + j] * INV_SQRT8;
    w1f[(j >> 3) * 18 + (j & 7) * 2 + hf] = wv4;
  }
  for (int fi = tid; fi < 16 * 64; fi += 256) {
    int f = fi >> 6, ll = fi & 63;
    int ct = f >> 1, kh = f & 1, mm = ll & 15, qq = ll >> 4;
    short8_t v;
    #pragma unroll
    for (int j = 0; j < 8; ++j)
      v[j] = (short)bf16r(fc_w2[(kh * 32 + qq * 8 + j) * 128 + ct * 16 + mm]);
    w2frag[fi] = v;
  }
  __syncthreads();

  int wv = tid >> 6;
  int l  = tid & 63;
  int m  = l & 15;
  int q  = l >> 4;
  int et = wv & 1;
  int ch = wv >> 1;

  int nA = 2 * wv;
  int offA0 = offsets[n0 + nA];
  int offA1 = offsets[n0 + nA + 1];
  int offB1 = offsets[n0 + nA + 2];
  float4_t racA = {0.f, 0.f, 0.f, 0.f};
  float4_t racB = {0.f, 0.f, 0.f, 0.f};

  for (int k0 = ebase; k0 < eend; k0 += CHUNK) {
    {
      int ecs = k0 + et * 16 + m;
      int ecc = (ecs < eend) ? ecs : (eend - 1);
      int srcm = PSRC[ecc];
      float4 eam = *(const float4*)(PEA + ecc);
      float4 sA  = *(const float4*)(PES + 2 * (long)ecc);
      float4 sB  = *(const float4*)(PES + 2 * (long)ecc + 1);
      float es0 = sA.x, es1 = sA.y, es2 = sA.z, es3 = sA.w;
      float es4 = sB.x, es5 = sB.y, es6 = sB.z, es7 = sB.w;

      short8_t a0, a1;
      #pragma unroll
      for (int jj = 0; jj < 8; ++jj) {
        float4 wA = w1f[q * 18 + jj * 2 + 0];
        float4 wB = w1f[q * 18 + jj * 2 + 1];
        float x = es0 * wA.x + es1 * wA.y + es2 * wA.z + es3 * wA.w
                + es4 * wB.x + es5 * wB.y + es6 * wB.z + es7 * wB.w;
        float hv = (x * H_SCALE) / (1.f + __expf(-x));
        a0[jj] = (short)bf16r(hv);
        float4 wC = w1f[(4 + q) * 18 + jj * 2 + 0];
        float4 wD = w1f[(4 + q) * 18 + jj * 2 + 1];
        float x2 = es0 * wC.x + es1 * wC.y + es2 * wC.z + es3 * wC.w
                 + es4 * wD.x + es5 * wD.y + es6 * wD.z + es7 * wD.w;
        float hv2 = (x2 * H_SCALE) / (1.f + __expf(-x2));
        a1[jj] = (short)bf16r(hv2);
      }

      int sl0 = q * 4, sl1 = sl0 + 1, sl2 = sl0 + 2, sl3 = sl0 + 3;
      int src0 = __shfl(srcm, sl0, 64), src1 = __shfl(srcm, sl1, 64);
      int src2 = __shfl(srcm, sl2, 64), src3 = __shfl(srcm, sl3, 64);
      float ea0x = __shfl(eam.x, sl0, 64), ea0y = __shfl(eam.y, sl0, 64),
            ea0z = __shfl(eam.z, sl0, 64), ea0w = __shfl(eam.w, sl0, 64);
      float ea1x = __shfl(eam.x, sl1, 64), ea1y = __shfl(eam.y, sl1, 64),
            ea1z = __shfl(eam.z, sl1, 64), ea1w = __shfl(eam.w, sl1, 64);
      float ea2x = __shfl(eam.x, sl2, 64), ea2y = __shfl(eam.y, sl2, 64),
            ea2z = __shfl(eam.z, sl2, 64), ea2w = __shfl(eam.w, sl2, 64);
      float ea3x = __shfl(eam.x, sl3, 64), ea3y = __shfl(eam.y, sl3, 64),
            ea3z = __shfl(eam.z, sl3, 64), ea3w = __shfl(eam.w, sl3, 64);

      RowData d0 = load_row(A + (long)src0 * 128, m);
      RowData d1 = load_row(A + (long)src1 * 128, m);
      RowData d2 = load_row(A + (long)src2 * 128, m);
      RowData d3 = load_row(A + (long)src3 * 128, m);

      float4_t acL[2], acH[2];
      #pragma unroll
      for (int uo = 0; uo < 2; ++uo) {
        int tl = ch * 2 + uo;
        short8_t bl0 = w2frag[(tl * 2 + 0) * 64 + l];
        short8_t bl1 = w2frag[(tl * 2 + 1) * 64 + l];
        float4_t zl = (float4_t){0.f, 0.f, 0.f, 0.f};
        zl = __builtin_amdgcn_mfma_f32_16x16x32_bf16(a0, bl0, zl, 0, 0, 0);
        zl = __builtin_amdgcn_mfma_f32_16x16x32_bf16(a1, bl1, zl, 0, 0, 0);
        acL[uo] = zl;
        int th = 4 + ch * 2 + uo;
        short8_t bh0 = w2frag[(th * 2 + 0) * 64 + l];
        short8_t bh1 = w2frag[(th * 2 + 1) * 64 + l];
        float4_t zh = (float4_t){0.f, 0.f, 0.f, 0.f};
        zh = __builtin_amdgcn_mfma_f32_16x16x32_bf16(a0, bh0, zh, 0, 0, 0);
        zh = __builtin_amdgcn_mfma_f32_16x16x32_bf16(a1, bh1, zh, 0, 0, 0);
        acH[uo] = zh;
      }

#define EPI(R, D, EAX, EAY, EAZ, EAW) do {                                       \
        float* mrow = mid + (et * 16 + q * 4 + (R)) * MROW;                      \
        { float wAa = acL[0][R], wBb = acH[0][R];                                \
          if (ch == 0) {                                                         \
            mrow[m] = wAa * D.se0 * EAX;                                         \
            float b = wBb * EAX;                                                 \
            mrow[160 + 3 * m + 0] = b * D.vx0;                                   \
            mrow[160 + 3 * m + 1] = b * D.vy0;                                   \
            mrow[160 + 3 * m + 2] = b * D.vz0;                                   \
          } else {                                                               \
            float dv = D.vx0 * EAY + D.vy0 * EAZ + D.vz0 * EAW;                  \
            mrow[32 + m] = wBb * dv * INV_SQRT3_C;                               \
            float b = wAa * D.se0;                                               \
            mrow[64 + 3 * m + 0] = b * EAY;                                      \
            mrow[64 + 3 * m + 1] = b * EAZ;                                      \
            mrow[64 + 3 * m + 2] = b * EAW;                                      \
          } }                                                                    \
        { float wAa = acL[1][R], wBb = acH[1][R];                                \
          int uu = 16 + m;                                                       \
          if (ch == 0) {                                                         \
            mrow[uu] = wAa * D.se1 * EAX;                                        \
            float b = wBb * EAX;                                                 \
            mrow[160 + 3 * uu + 0] = b * D.vx1;                                  \
            mrow[160 + 3 * uu + 1] = b * D.vy1;                                  \
            mrow[160 + 3 * uu + 2] = b * D.vz1;                                  \
          } else {                                                               \
            float dv = D.vx1 * EAY + D.vy1 * EAZ + D.vz1 * EAW;                  \
            mrow[32 + uu] = wBb * dv * INV_SQRT3_C;                              \
            float b = wAa * D.se1;                                               \
            mrow[64 + 3 * uu + 0] = b * EAY;                                     \
            mrow[64 + 3 * uu + 1] = b * EAZ;                                     \
            mrow[64 + 3 * uu + 2] = b * EAW;                                     \
          } }                                                                    \
      } while (0)

      EPI(0, d0, ea0x, ea0y, ea0z, ea0w);
      EPI(1, d1, ea1x, ea1y, ea1z, ea1w);
      EPI(2, d2, ea2x, ea2y, ea2z, ea2w);
      EPI(3, d3, ea3x, ea3y, ea3z, ea3w);
#undef EPI
    }
    __syncthreads();

    {
      int lo = (offA0 > k0) ? offA0 : k0;
      int hiA = offA1 < (k0 + CHUNK) ? offA1 : (k0 + CHUNK);
      for (int e = lo; e < hiA; ++e) {
        float4_t v = *(const float4_t*)(mid + (e - k0) * MROW + 4 * l);
        racA.x += v.x; racA.y += v.y; racA.z += v.z; racA.w += v.w;
      }
      int lo2 = (offA1 > k0) ? offA1 : k0;
      int hiB = offB1 < (k0 + CHUNK) ? offB1 : (k0 + CHUNK);
      for (int e = lo2; e < hiB; ++e) {
        float4_t v = *(const float4_t*)(mid + (e - k0) * MROW + 4 * l);
        racB.x += v.x; racB.y += v.y; racB.z += v.z; racB.w += v.w;
      }
    }
    __syncthreads();
  }

  *(float4_t*)(ACC + (long)(n0 + nA) * 256 + 4 * l)     = racA;
  *(float4_t*)(ACC + (long)(n0 + nA + 1) * 256 + 4 * l) = racB;
}

// ---------------- tier3: R4 k_edge kept verbatim -----------------------------
__global__ __launch_bounds__(256, 4) void k_edge_fb(
    const float* __restrict__ A,
    const int* __restrict__ edge_src,
    const int* __restrict__ edge_dst,
    const float* __restrict__ edge_attr,
    const float* __restrict__ edge_scalars,
    const float* __restrict__ fc_w1,
    const float* __restrict__ fc_w2,
    const int* __restrict__ offsets,
    const int* __restrict__ slots,
    float* __restrict__ ACC) {
  const float INV_SQRT8 = 0.35355339059327373f;
  const float H_SCALE   = 1.6791767923989418f / 8.0f;

  __shared__ float    lacc[NPB * LROW];
  __shared__ short8_t w2frag[16 * 64];
  __shared__ float4   w1f[144];

  int tid = threadIdx.x;
  int n0 = blockIdx.x * NPB;
  int ebase = offsets[n0];
  int eend  = offsets[n0 + NPB];

  for (int i = tid; i < NPB * LROW; i += 256) lacc[i] = 0.f;
  if (tid < 128) {
    int j = tid >> 1, hf = tid & 1;
    float4 wv4;
    wv4.x = fc_w1[(hf * 4 + 0) * 64 + j] * INV_SQRT8;
    wv4.y = fc_w1[(hf * 4 + 1) * 64 + j] * INV_SQRT8;
    wv4.z = fc_w1[(hf * 4 + 2) * 64 + j] * INV_SQRT8;
    wv4.w = fc_w1[(hf * 4 + 3) * 64 + j] * INV_SQRT8;
    w1f[(j >> 3) * 18 + (j & 7) * 2 + hf] = wv4;
  }
  for (int fi = tid; fi < 16 * 64; fi += 256) {
    int f = fi >> 6, ll = fi & 63;
    int ct = f >> 1, kh = f & 1, mm = ll & 15, qq = ll >> 4;
    short8_t v;
    #pragma unroll
    for (int j = 0; j < 8; ++j)
      v[j] = (short)bf16r(fc_w2[(kh * 32 + qq * 8 + j) * 128 + ct * 16 + mm]);
    w2frag[fi] = v;
  }
  __syncthreads();

  int wv = tid >> 6;
  int l  = tid & 63;
  int m  = l & 15;
  int q  = l >> 4;

  for (int k0 = ebase; k0 < eend; k0 += 64) {
    int ce = k0 + 4 * m + wv;
    bool vld = ce < eend;
    int e = slots[vld ? ce : (eend - 1)];
    int srcm = edge_src[e];
    int lnm  = edge_dst[e] - n0;
    float4 eam = ld4(edge_attr + (long)e * 4);
    float4 sA = ld4(edge_scalars + (long)e * 8);
    float4 sB = ld4(edge_scalars + (long)e * 8 + 4);
    float es0 = sA.x, es1 = sA.y, es2 = sA.z, es3 = sA.w;
    float es4 = sB.x, es5 = sB.y, es6 = sB.z, es7 = sB.w;

    short8_t a0, a1;
    #pragma unroll
    for (int jj = 0; jj < 8; ++jj) {
      float4 wA = w1f[q * 18 + jj * 2 + 0];
      float4 wB = w1f[q * 18 + jj * 2 + 1];
      float x = es0 * wA.x + es1 * wA.y + es2 * wA.z + es3 * wA.w
              + es4 * wB.x + es5 * wB.y + es6 * wB.z + es7 * wB.w;
      float hv = vld ? (x * H_SCALE) / (1.f + __expf(-x)) : 0.f;
      a0[jj] = (short)bf16r(hv);
      float4 wC = w1f[(4 + q) * 18 + jj * 2 + 0];
      float4 wD = w1f[(4 + q) * 18 + jj * 2 + 1];
      float x2 = es0 * wC.x + es1 * wC.y + es2 * wC.z + es3 * wC.w
               + es4 * wD.x + es5 * wD.y + es6 * wD.z + es7 * wD.w;
      float hv2 = vld ? (x2 * H_SCALE) / (1.f + __expf(-x2)) : 0.f;
      a1[jj] = (short)bf16r(hv2);
    }

    int sl0 = q * 4, sl1 = sl0 + 1, sl2 = sl0 + 2, sl3 = sl0 + 3;
    int src0 = __shfl(srcm, sl0, 64), src1 = __shfl(srcm, sl1, 64);
    int src2 = __shfl(srcm, sl2, 64), src3 = __shfl(srcm, sl3, 64);
    int ln0 = __shfl(lnm, sl0, 64), ln1 = __shfl(lnm, sl1, 64);
    int ln2 = __shfl(lnm, sl2, 64), ln3 = __shfl(lnm, sl3, 64);
    float ea0x = __shfl(eam.x, sl0, 64), ea0y = __shfl(eam.y, sl0, 64),
          ea0z = __shfl(eam.z, sl0, 64), ea0w = __shfl(eam.w, sl0, 64);
    float ea1x = __shfl(eam.x, sl1, 64), ea1y = __shfl(eam.y, sl1, 64),
          ea1z = __shfl(eam.z, sl1, 64), ea1w = __shfl(eam.w, sl1, 64);
    float ea2x = __shfl(eam.x, sl2, 64), ea2y = __shfl(eam.y, sl2, 64),
          ea2z = __shfl(eam.z, sl2, 64), ea2w = __shfl(eam.w, sl2, 64);
    float ea3x = __shfl(eam.x, sl3, 64), ea3y = __shfl(eam.y, sl3, 64),
          ea3z = __shfl(eam.z, sl3, 64), ea3w = __shfl(eam.w, sl3, 64);

    const float* abA = A + (long)src0 * 128;
    const float* abB = A + (long)src1 * 128;
    RowData dA = load_row(abA, m);
    RowData dB = load_row(abB, m);

    float4_t acc[8];
    #pragma unroll
    for (int t = 0; t < 8; ++t) {
      short8_t b0 = w2frag[(t * 2 + 0) * 64 + l];
      short8_t b1 = w2frag[(t * 2 + 1) * 64 + l];
      float4_t z = (float4_t){0.f, 0.f, 0.f, 0.f};
      z = __builtin_amdgcn_mfma_f32_16x16x32_bf16(a0, b0, z, 0, 0, 0);
      z = __builtin_amdgcn_mfma_f32_16x16x32_bf16(a1, b1, z, 0, 0, 0);
      acc[t] = z;
    }

    const float* abC = A + (long)src2 * 128;
    const float* abD = A + (long)src3 * 128;
    RowData dC = load_row(abC, m);
    RowData dD = load_row(abD, m);

    #define ACCUM_ROW(RR, LN, EAX, EAY, EAZ, EAW, D) do {                        \
        float* lrow = lacc + (LN) * LROW;                                        \
        accum_half(lrow, m,      acc[0][RR], acc[2][RR], acc[4][RR], acc[6][RR], \
                   D.se0, D.vx0, D.vy0, D.vz0, EAX, EAY, EAZ, EAW);              \
        accum_half(lrow, m + 16, acc[1][RR], acc[3][RR], acc[5][RR], acc[7][RR], \
                   D.se1, D.vx1, D.vy1, D.vz1, EAX, EAY, EAZ, EAW);              \
      } while (0)

    if (k0 + 64 <= eend) {
      ACCUM_ROW(0, ln0, ea0x, ea0y, ea0z, ea0w, dA);
      ACCUM_ROW(1, ln1, ea1x, ea1y, ea1z, ea1w, dB);
      ACCUM_ROW(2, ln2, ea2x, ea2y, ea2z, ea2w, dC);
      ACCUM_ROW(3, ln3, ea3x, ea3y, ea3z, ea3w, dD);
    } else {
      int cb = k0 + 16 * q + wv;
      if (cb + 0  < eend) ACCUM_ROW(0, ln0, ea0x, ea0y, ea0z, ea0w, dA);
      if (cb + 4  < eend) ACCUM_ROW(1, ln1, ea1x, ea1y, ea1z, ea1w, dB);
      if (cb + 8  < eend) ACCUM_ROW(2, ln2, ea2x, ea2y, ea2z, ea2w, dC);
      if (cb + 12 < eend) ACCUM_ROW(3, ln3, ea3x, ea3y, ea3z, ea3w, dD);
    }
    #undef ACCUM_ROW
  }
  __syncthreads();

  for (int i = tid; i < NPB * 256; i += 256) {
    int node = i >> 8;
    int c = i & 255;
    ACC[(long)(n0 + node) * 256 + c] = lacc[node * LROW + c];
  }
}

// ---------------- Stage 2 (old; tiers 2/3) ----------------
__global__ void k3_stage2(const float* __restrict__ ACC,
                          const float* __restrict__ w2s,
                          const float* __restrict__ w2v,
                          float* __restrict__ out) {
  const float scale = 0.03125f; // (1/sqrt(16)) / sqrt(64)
  int stride = gridDim.x * blockDim.x;
  for (int idx = blockIdx.x * blockDim.x + threadIdx.x; idx < NNODES * 128; idx += stride) {
    int n = idx >> 7;
    int c = idx & 127;
    const float* row = ACC + (long)n * 256;
    float acc = 0.f;
    if (c < 32) {
      #pragma unroll
      for (int qq = 0; qq < 64; ++qq)
        acc = fmaf(row[qq], w2s[qq * 32 + c], acc);
    } else {
      int cc = c - 32;
      int w = cc / 3;
      int i = cc - w * 3;
      #pragma unroll
      for (int qq = 0; qq < 64; ++qq)
        acc = fmaf(row[64 + qq * 3 + i], w2v[qq * 32 + w], acc);
    }
    out[idx] = acc * scale;
  }
}

extern "C" void kernel_launch(void* const* d_in, const int* in_sizes, int n_in,
                              void* d_out, int out_size, void* d_ws, size_t ws_size,
                              hipStream_t stream) {
  const float* node_input   = (const float*)d_in[0];
  const int*   edge_src     = (const int*)d_in[2];
  const int*   edge_dst     = (const int*)d_in[3];
  const float* edge_attr    = (const float*)d_in[4];
  const float* edge_scalars = (const float*)d_in[5];
  const float* fc_w1        = (const float*)d_in[8];
  const float* fc_w2        = (const float*)d_in[9];
  const float* w_lin1_s     = (const float*)d_in[6];
  const float* w_lin1_v     = (const float*)d_in[7];
  const float* w_lin2_s     = (const float*)d_in[10];
  const float* w_lin2_v     = (const float*)d_in[11];

  float* out = (float*)d_out;

  const size_t SZ_ACC = (size_t)NNODES * 256 * sizeof(float);   // 40.96 MB
  const size_t SZ_A2  = (size_t)NNODES * 128 * sizeof(float);   // 20.48 MB (tier1)
  const size_t SZ_PE  = (size_t)NEDGES * 64;                    // 40.96 MB (tier1)
  const size_t SZ_PES = (size_t)NEDGES * 32;                    // 20.48 MB (tier2)
  const size_t SZ_PEA = (size_t)NEDGES * 16;                    // 10.24 MB (tier2)
  const size_t SZ_PSR = (size_t)NEDGES * 4;                     //  2.56 MB (tier2)
  const size_t SZ_CNT = (size_t)NNODES * sizeof(int);
  const size_t SZ_OFF = (size_t)(NNODES + 4) * sizeof(int);
  const size_t SZ_SLT = (size_t)NEDGES * sizeof(int);
  const size_t need1 = SZ_A2 + SZ_PE + 3 * SZ_CNT + SZ_OFF + 2048;
  const size_t need2 = SZ_ACC + SZ_PES + SZ_PEA + SZ_PSR + 3 * SZ_CNT + SZ_OFF + 2048;

  if (ws_size >= need1) {
    // ---- tier1: R9 — stage-2 fused into edge kernel; A2 lives in ws
    char* p = (char*)d_ws;
    float*    A2  = (float*)p;    p += SZ_A2;
    float4_t* PE  = (float4_t*)p; p += SZ_PE;
    int* counts   = (int*)p;      p += SZ_CNT;
    int* offsets  = (int*)p;      p += SZ_OFF;
    int* cursor   = (int*)p;      p += SZ_CNT;
    int* bsum     = (int*)p;      p += 160 * sizeof(int);
    int* boff     = (int*)p;      p += 160 * sizeof(int);
    (void)boff;

    hipMemsetAsync(counts, 0, SZ_CNT, stream);
    k1_stage1b<<<NNODES / NB1, 256, 0, stream>>>(node_input, w_lin1_s, w_lin1_v, A2);
    k_hist<<<NEDGES / 256, 256, 0, stream>>>(edge_dst, counts);
    k_scanA<<<157, 256, 0, stream>>>(counts, bsum);
    k_scanBC<<<157, 256, 0, stream>>>(counts, bsum, offsets, cursor);
    k_scatter_pack3<<<NEDGES / 256, 256, 0, stream>>>(edge_src, edge_dst, edge_attr,
                                                      edge_scalars, cursor, PE);
    k_edge5<<<NNODES / NPB, 256, 0, stream>>>(A2, PE, fc_w1, fc_w2,
                                              w_lin2_s, w_lin2_v, offsets, out);
  } else if (ws_size >= need2) {
    // ---- tier2: proven R6 path
    float* Abuf = out;
    char* p = (char*)d_ws;
    float*    ACC = (float*)p;    p += SZ_ACC;
    float4_t* PES = (float4_t*)p; p += SZ_PES;
    float4_t* PEA = (float4_t*)p; p += SZ_PEA;
    int*      PSRC = (int*)p;     p += SZ_PSR;
    int* counts   = (int*)p;      p += SZ_CNT;
    int* offsets  = (int*)p;      p += SZ_OFF;
    int* cursor   = (int*)p;      p += SZ_CNT;
    int* bsum     = (int*)p;      p += 160 * sizeof(int);
    int* boff     = (int*)p;      p += 160 * sizeof(int);

    hipMemsetAsync(counts, 0, SZ_CNT, stream);
    k1_stage1<<<2048, 256, 0, stream>>>(node_input, w_lin1_s, w_lin1_v, Abuf);
    k_hist<<<NEDGES / 256, 256, 0, stream>>>(edge_dst, counts);
    k_scanA<<<157, 256, 0, stream>>>(counts, bsum);
    k_scanB<<<1, 256, 0, stream>>>(bsum, boff, offsets);
    k_scanC<<<157, 256, 0, stream>>>(counts, boff, offsets, cursor);
    k_scatter_pack2<<<NEDGES / 256, 256, 0, stream>>>(edge_src, edge_dst, edge_attr,
                                                      edge_scalars, cursor, PSRC, PEA, PES);
    k_edge3<<<NNODES / NPB, 256, 0, stream>>>(Abuf, PSRC, PEA, PES, fc_w1, fc_w2,
                                              offsets, ACC);
    k3_stage2<<<2048, 256, 0, stream>>>(ACC, w_lin2_s, w_lin2_v, out);
  } else {
    // ---- tier3: proven R4 fallback
    float* Abuf = out;
    char* p = (char*)d_ws;
    float* ACC    = (float*)p;  p += SZ_ACC;
    int* counts   = (int*)p;    p += SZ_CNT;
    int* offsets  = (int*)p;    p += SZ_OFF;
    int* cursor   = (int*)p;    p += SZ_CNT;
    int* slots    = (int*)p;    p += SZ_SLT;
    int* bsum     = (int*)p;    p += 160 * sizeof(int);
    int* boff     = (int*)p;    p += 160 * sizeof(int);

    hipMemsetAsync(counts, 0, SZ_CNT, stream);
    k1_stage1<<<2048, 256, 0, stream>>>(node_input, w_lin1_s, w_lin1_v, Abuf);
    k_hist<<<NEDGES / 256, 256, 0, stream>>>(edge_dst, counts);
    k_scanA<<<157, 256, 0, stream>>>(counts, bsum);
    k_scanB<<<1, 256, 0, stream>>>(bsum, boff, offsets);
    k_scanC<<<157, 256, 0, stream>>>(counts, boff, offsets, cursor);
    k_scatter<<<NEDGES / 256, 256, 0, stream>>>(edge_dst, cursor, slots);
    k_edge_fb<<<NNODES / NPB, 256, 0, stream>>>(Abuf, edge_src, edge_dst, edge_attr,
                                                edge_scalars, fc_w1, fc_w2,
                                                offsets, slots, ACC);
    k3_stage2<<<2048, 256, 0, stream>>>(ACC, w_lin2_s, w_lin2_v, out);
  }
}